// Round 7
// baseline (518.332 us; speedup 1.0000x reference)
//
#include <hip/hip_runtime.h>
#include <math.h>

// ---- problem constants ----
#define BB 16
#define CIN 256
#define MM 4096      // H*W
#define HIDC 256
#define NQ 300
#define NHH 4
#define HDD 16

// ---- output offsets (floats) ----
#define OFF_BOXES  0
#define OFF_SCORES 19200
#define OFF_CLS    24000
#define OFF_MAPS   408000
#define OFF_DIV    20068800
#define OFF_SF     20068801

// ---- workspace offsets (in floats) ----
#define WS_COMB16  0            // 16*256*4096 ushort  (comb, c-major: [c][m])
#define WS_KEYS16  8388608      // keysT: (b, m=4096, d=64) bf16
#define WS_ATTN16  10485760     // 16*300*4096 ushort
#define WS_T16     21544960     // 16*300*256 ushort
#define WS_VALW16  22159360     // 65536 ushort
#define WS_SUMS    22192128     // 16*4*300 fp32 (exp-sum; atomically accumulated)
#define WS_NORM    22211328     // 4800 floats: SUM OF SQUARES per (b,n)
#define WS_ACC     22216128     // 1 float (+pad) -- contiguous after norms (one zero pass)
#define WS_P       22216192     // head scratch base

// head scratch
#define HP_SF16   (WS_P + 0)         // 4800x256 bf16  (614400 fl)
#define HP_Z2BB   (WS_P + 2457600)   // 4800x128 bf16  (307200 fl)
#define HP_Z2CH   (WS_P + 2764800)   // 4800x128 bf16  (307200 fl) -- contiguous after Z2BB
#define HP_HW     (WS_P + 3072000)   // head weights bf16 (~108.6k fl)
#define WS_B2     (WS_P + 3180544)   // 256 fp32: [bb2_b | ch2_b] contiguous
#define WS_Q16    (WS_P + 3200000)   // 320x64 bf16 q (0.25-scaled, rows 300..319 zero)
// MFMA-path buffers
#define WS_XT     25426432      // xT16: (b,4096,256) bf16 = 8388608 fl (dead after comb_mfma)
#define WS_COMBT  33815040      // combT: (b, m=4096, c=256) bf16 = 8388608 fl
#define WS_FPW16  42203648      // fp_w rows 0..127 bf16
#define WS_KEYW16 42220032      // key_w bf16
#define WS_Z1PRE2 42228224      // 2 x 4800x256 fp32 = 2457600 fl (boxes|scores z1 pre-LN)
#define WS_Z1B16  44685824      // 2 x 4800x256 bf16 = 1228800 fl
// total ≈ 45914624 fl ≈ 184 MB (harness provides ≥246 MB)

// ushort offsets within HP_HW:
#define HW_BB1 0
#define HW_CH1 65536
#define HW_BB2 131072
#define HW_CH2 163840
#define HW_CTP 196608

typedef short short8 __attribute__((ext_vector_type(8)));
typedef float floatx4 __attribute__((ext_vector_type(4)));

__device__ __forceinline__ unsigned short f2bf(float f){
  unsigned int u = __float_as_uint(f);
  u = (u + 0x7FFFu + ((u >> 16) & 1u)) >> 16;
  return (unsigned short)u;
}
__device__ __forceinline__ float bf1(unsigned short u){
  return __uint_as_float((unsigned int)u << 16);
}

__global__ __launch_bounds__(256) void zero4_kernel(float4* __restrict__ p, int n4){
  int i = blockIdx.x * 256 + threadIdx.x;
  if (i < n4) p[i] = make_float4(0.f, 0.f, 0.f, 0.f);
}

// fused init: q16 (0.25-scaled, 320-row pad), fp_w rows 0..127 bf16, key_w bf16
__global__ __launch_bounds__(256) void init_kernel(const float* __restrict__ ss,
    const float* __restrict__ fp_w, const float* __restrict__ key_w,
    unsigned short* __restrict__ q16, unsigned short* __restrict__ fpw16,
    unsigned short* __restrict__ keyw16){
  int i = blockIdx.x * 256 + threadIdx.x;
  int T = gridDim.x * 256;
  for (int j = i; j < 320*64; j += T)
    q16[j] = (j < NQ*64) ? f2bf(ss[j] * 0.25f) : (unsigned short)0;
  for (int j = i; j < 128*256; j += T) fpw16[j] = f2bf(fp_w[j]);
  for (int j = i; j < 64*256; j += T)  keyw16[j] = f2bf(key_w[j]);
}

// one fused cast of all bf16 weight copies + contiguous gemm2 biases
__global__ __launch_bounds__(256) void cast_heads_kernel(
    const float* __restrict__ val_w, const float* __restrict__ bb1_w,
    const float* __restrict__ ch1_w, const float* __restrict__ bb2_w,
    const float* __restrict__ ch2_w, const float* __restrict__ ctp_w,
    const float* __restrict__ bb2_b, const float* __restrict__ ch2_b,
    unsigned short* __restrict__ valw16, unsigned short* __restrict__ hw16,
    float* __restrict__ b2){
  int i = blockIdx.x * 256 + threadIdx.x;
  int T = gridDim.x * 256;
  for (int j = i; j < 65536; j += T) valw16[j] = f2bf(val_w[j]);
  for (int j = i; j < 65536; j += T) hw16[HW_BB1 + j] = f2bf(bb1_w[j]);
  for (int j = i; j < 65536; j += T) hw16[HW_CH1 + j] = f2bf(ch1_w[j]);
  for (int j = i; j < 32768; j += T) hw16[HW_BB2 + j] = f2bf(bb2_w[j]);
  for (int j = i; j < 32768; j += T) hw16[HW_CH2 + j] = f2bf(ch2_w[j]);
  for (int j = i; j < 20480; j += T) hw16[HW_CTP + j] = f2bf(ctp_w[j]);
  for (int j = i; j < 128; j += T){ b2[j] = bb2_b[j]; b2[128 + j] = ch2_b[j]; }
}

// pos encoding into BOTH layouts: comb16[c][m] rows 128..255 (ushort4 over m)
// and combT[m][128+c] (ushort4 over c). One kernel, linear id split.
__global__ __launch_bounds__(256) void pos_kernel(const float* __restrict__ pos_w,
                                                  const float* __restrict__ pos_b,
                                                  unsigned short* __restrict__ comb16,
                                                  unsigned short* __restrict__ combT){
  int lin = blockIdx.x * 256 + threadIdx.x;
  if (lin < 2097152){                     // part A: comb16, thread -> (b, c, m4)
    int m  = (lin & 1023) * 4;
    int c  = (lin >> 10) & 127;
    int b  = lin >> 17;
    int row = m >> 6, col = m & 63;
    float y  = -1.f + 2.f * (float)row / 63.f;
    float wy = pos_w[c*2], wx = pos_w[c*2+1], pb = pos_b[c];
    float base = wy * y + pb;
    ushort4 u;
    u.x = f2bf(base + wx * (-1.f + 2.f * (float)(col+0) / 63.f));
    u.y = f2bf(base + wx * (-1.f + 2.f * (float)(col+1) / 63.f));
    u.z = f2bf(base + wx * (-1.f + 2.f * (float)(col+2) / 63.f));
    u.w = f2bf(base + wx * (-1.f + 2.f * (float)(col+3) / 63.f));
    *(ushort4*)&comb16[((size_t)(b*HIDC + 128 + c))*MM + m] = u;
  } else if (lin < 2097152 + 131072){     // part B: combT, thread -> (m, c4)
    int l2 = lin - 2097152;
    int c4 = (l2 & 31) * 4;
    int m  = l2 >> 5;
    int row = m >> 6, col = m & 63;
    float y = -1.f + 2.f * (float)row / 63.f;
    float x = -1.f + 2.f * (float)col / 63.f;
    ushort4 u;
    u.x = f2bf(pos_w[(c4+0)*2] * y + pos_w[(c4+0)*2+1] * x + pos_b[c4+0]);
    u.y = f2bf(pos_w[(c4+1)*2] * y + pos_w[(c4+1)*2+1] * x + pos_b[c4+1]);
    u.z = f2bf(pos_w[(c4+2)*2] * y + pos_w[(c4+2)*2+1] * x + pos_b[c4+2]);
    u.w = f2bf(pos_w[(c4+3)*2] * y + pos_w[(c4+3)*2+1] * x + pos_b[c4+3]);
    #pragma unroll
    for (int b = 0; b < BB; b++)
      *(ushort4*)&combT[((size_t)b*MM + m)*CIN + 128 + c4] = u;
  }
}

// x (b, 256, 4096) fp32 -> xT16 (b, 4096, 256) bf16; one 64x64 tile per block.
__global__ __launch_bounds__(256) void transpose_x_kernel(
    const float* __restrict__ in, unsigned short* __restrict__ outp){
  int b = blockIdx.z;
  int m0 = blockIdx.x * 64;
  int r0 = blockIdx.y * 64;
  __shared__ unsigned short lds[64][68];
  int t = threadIdx.x;
  const float* ib = in + (size_t)b * CIN * MM;
  #pragma unroll
  for (int j = 0; j < 4; j++){
    int lin = j*256 + t;
    int rr = lin >> 4;
    int m4 = (lin & 15) * 4;
    float4 v = *(const float4*)&ib[(size_t)(r0 + rr)*MM + m0 + m4];
    lds[m4+0][rr] = f2bf(v.x);
    lds[m4+1][rr] = f2bf(v.y);
    lds[m4+2][rr] = f2bf(v.z);
    lds[m4+3][rr] = f2bf(v.w);
  }
  __syncthreads();
  unsigned short* ob = outp + (size_t)b * MM * CIN;
  #pragma unroll
  for (int j = 0; j < 4; j++){
    int lin = j*256 + t;
    int mm = lin >> 4;
    int c4 = (lin & 15) * 4;
    ushort4 u;
    u.x = lds[mm][c4+0]; u.y = lds[mm][c4+1];
    u.z = lds[mm][c4+2]; u.w = lds[mm][c4+3];
    *(ushort4*)&ob[(size_t)(m0 + mm)*CIN + r0 + c4] = u;
  }
}

// comb rows 0..127 via MFMA with DUAL-layout store:
//   comb16[c][m] (scalar, c-major) AND combT[m][c] (ushort4: reg axis = 4 consecutive c).
__global__ __launch_bounds__(64) void comb_mfma_kernel(
    const unsigned short* __restrict__ fpw16, const unsigned short* __restrict__ xT16,
    const float* __restrict__ fp_b, const float* __restrict__ bn_g,
    const float* __restrict__ bn_b, const float* __restrict__ bn_m,
    const float* __restrict__ bn_v, unsigned short* __restrict__ comb16,
    unsigned short* __restrict__ combT){
  int b = blockIdx.z;
  const unsigned short* Bb = xT16 + (size_t)b * MM * CIN;
  unsigned short* cb  = comb16 + (size_t)b * HIDC * MM;
  unsigned short* cTb = combT + (size_t)b * MM * CIN;
  int lane = threadIdx.x;
  int r16 = lane & 15;
  int ko  = (lane >> 4) * 8;
  const unsigned short* arow[4];
  const unsigned short* brow[4];
  #pragma unroll
  for (int i = 0; i < 4; i++){
    arow[i] = fpw16 + (size_t)(blockIdx.y*64 + i*16 + r16) * CIN + ko;
    brow[i] = Bb + (size_t)(blockIdx.x*64 + i*16 + r16) * CIN + ko;
  }
  floatx4 acc[4][4];
  #pragma unroll
  for (int i = 0; i < 4; i++)
    #pragma unroll
    for (int j = 0; j < 4; j++)
      acc[i][j] = (floatx4){0.f, 0.f, 0.f, 0.f};
  short8 a[4], bv[4], a2[4], b2[4];
  #pragma unroll
  for (int i = 0; i < 4; i++){
    a[i]  = *(const short8*)(arow[i]);
    bv[i] = *(const short8*)(brow[i]);
  }
  for (int k = 32; k < CIN; k += 32){
    #pragma unroll
    for (int i = 0; i < 4; i++){
      a2[i] = *(const short8*)(arow[i] + k);
      b2[i] = *(const short8*)(brow[i] + k);
    }
    #pragma unroll
    for (int i = 0; i < 4; i++)
      #pragma unroll
      for (int j = 0; j < 4; j++)
        acc[i][j] = __builtin_amdgcn_mfma_f32_16x16x32_bf16(a[i], bv[j], acc[i][j], 0, 0, 0);
    #pragma unroll
    for (int i = 0; i < 4; i++){ a[i] = a2[i]; bv[i] = b2[i]; }
  }
  #pragma unroll
  for (int i = 0; i < 4; i++)
    #pragma unroll
    for (int j = 0; j < 4; j++)
      acc[i][j] = __builtin_amdgcn_mfma_f32_16x16x32_bf16(a[i], bv[j], acc[i][j], 0, 0, 0);
  int cq = lane & 15, rq = (lane >> 4) * 4;
  #pragma unroll
  for (int i = 0; i < 4; i++){
    int rbase = blockIdx.y*64 + i*16 + rq;
    float mul[4], ofs[4];
    #pragma unroll
    for (int reg = 0; reg < 4; reg++){
      int rr = rbase + reg;
      float sc = rsqrtf(bn_v[rr] + 1e-5f);
      mul[reg] = sc * bn_g[rr];
      ofs[reg] = (fp_b[rr] - bn_m[rr]) * mul[reg] + bn_b[rr];
    }
    #pragma unroll
    for (int j = 0; j < 4; j++){
      int cc = blockIdx.x*64 + j*16 + cq;
      ushort4 u;
      float v0 = fmaxf(acc[i][j][0] * mul[0] + ofs[0], 0.f); u.x = f2bf(v0);
      float v1 = fmaxf(acc[i][j][1] * mul[1] + ofs[1], 0.f); u.y = f2bf(v1);
      float v2 = fmaxf(acc[i][j][2] * mul[2] + ofs[2], 0.f); u.z = f2bf(v2);
      float v3 = fmaxf(acc[i][j][3] * mul[3] + ofs[3], 0.f); u.w = f2bf(v3);
      cb[(size_t)(rbase+0) * MM + cc] = u.x;
      cb[(size_t)(rbase+1) * MM + cc] = u.y;
      cb[(size_t)(rbase+2) * MM + cc] = u.z;
      cb[(size_t)(rbase+3) * MM + cc] = u.w;
      *(ushort4*)&cTb[(size_t)cc * CIN + rbase] = u;
    }
  }
}

// ======== fused no-P attention: SWAPPED-operand MFMA logits, 2 passes ========
// mfma(a=k, b=q): D col = n (lane&15), D row = m ((lane>>4)*4 + reg).

// pass 1: sums[b][h][n] = sum_m exp(q.k/4). grid (32 m-chunks, 5 n-tiles, 16 b), 256 thr.
__global__ __launch_bounds__(256) void attn_sums_kernel(
    const unsigned short* __restrict__ q16, const unsigned short* __restrict__ keysT,
    float* __restrict__ sums){
  int b = blockIdx.z, ny = blockIdx.y, mx = blockIdx.x;
  int tid = threadIdx.x, w = tid >> 6, lane = tid & 63;
  int n0 = ny * 64;
  int l15 = lane & 15, qh = lane >> 4;
  int ko = (qh & 1) * 8;
  bool lo = lane < 32;
  const unsigned short* kT = keysT + (size_t)b * MM * 64;
  int mwb = mx*128 + w*32;
  __shared__ unsigned short qlds[64][72];
  __shared__ float spart[4][NHH][64];
  for (int c = tid; c < 512; c += 256){
    int r = c >> 3, d8 = (c & 7) * 8;
    *(short8*)&qlds[r][d8] = *(const short8*)&q16[(size_t)(n0 + r)*64 + d8];
  }
  __syncthreads();
  short8 zz = {0,0,0,0,0,0,0,0};
  #pragma unroll 1
  for (int h = 0; h < NHH; h++){
    short8 bq[4];
    #pragma unroll
    for (int ni = 0; ni < 4; ni++)
      bq[ni] = lo ? *(const short8*)&qlds[ni*16 + l15][h*16 + ko] : zz;
    float sacc[4] = {0.f, 0.f, 0.f, 0.f};
    #pragma unroll
    for (int ms = 0; ms < 2; ms++){
      int m = mwb + ms*16 + l15;
      short8 a = lo ? *(const short8*)&kT[(size_t)m*64 + h*16 + ko] : zz;
      #pragma unroll
      for (int ni = 0; ni < 4; ni++){
        floatx4 l = __builtin_amdgcn_mfma_f32_16x16x32_bf16(a, bq[ni],
                        (floatx4){0.f,0.f,0.f,0.f}, 0, 0, 0);
        sacc[ni] += __expf(l[0]) + __expf(l[1]) + __expf(l[2]) + __expf(l[3]);
      }
    }
    #pragma unroll
    for (int ni = 0; ni < 4; ni++){
      float v = sacc[ni];
      v += __shfl_xor(v, 16); v += __shfl_xor(v, 32);
      if (lane < 16) spart[w][h][ni*16 + lane] = v;
    }
  }
  __syncthreads();
  if (tid < NHH*64){
    int h = tid >> 6, r = tid & 63, n = n0 + r;
    if (n < NQ){
      float v = spart[0][h][r] + spart[1][h][r] + spart[2][h][r] + spart[3][h][r];
      atomicAdd(&sums[((size_t)b*NHH + h)*NQ + n], v);
    }
  }
}

// pass 2: attn[b][n][m] = sum_h exp(q.k/4) * (0.25/S_bhn); vectorized float4/ushort4 stores.
__global__ __launch_bounds__(256) void attn_emit_kernel(
    const unsigned short* __restrict__ q16, const unsigned short* __restrict__ keysT,
    const float* __restrict__ sums, float* __restrict__ maps,
    unsigned short* __restrict__ attn16, float* __restrict__ norms){
  int b = blockIdx.z, ny = blockIdx.y, mx = blockIdx.x;
  int tid = threadIdx.x, w = tid >> 6, lane = tid & 63;
  int n0 = ny * 64;
  int l15 = lane & 15, qh = lane >> 4;
  int ko = (qh & 1) * 8;
  bool lo = lane < 32;
  __shared__ unsigned short qlds[64][72];
  __shared__ float inv_s[NHH][64];
  __shared__ float npart[4][64];
  for (int c = tid; c < 512; c += 256){
    int r = c >> 3, d8 = (c & 7) * 8;
    *(short8*)&qlds[r][d8] = *(const short8*)&q16[(size_t)(n0 + r)*64 + d8];
  }
  if (tid < NHH*64){
    int h = tid >> 6, r = tid & 63, n = n0 + r;
    inv_s[h][r] = (n < NQ) ? 0.25f / sums[((size_t)b*NHH + h)*NQ + n] : 0.f;
  }
  __syncthreads();
  const unsigned short* kT = keysT + (size_t)b * MM * 64;
  int mwb = mx*128 + w*32;
  short8 zz = {0,0,0,0,0,0,0,0};
  float nacc[4] = {0.f, 0.f, 0.f, 0.f};
  float* mb = maps + (size_t)b * NQ * MM;
  unsigned short* ab = attn16 + (size_t)b * NQ * MM;
  #pragma unroll 1
  for (int ms = 0; ms < 2; ms++){
    asm volatile("" ::: "memory");   // defeat LICM: q frags re-read from LDS each iter
    int mbase = mwb + ms*16;
    int mk = mbase + l15;
    floatx4 o[4];
    #pragma unroll
    for (int ni = 0; ni < 4; ni++) o[ni] = (floatx4){0.f,0.f,0.f,0.f};
    #pragma unroll
    for (int h = 0; h < NHH; h++){
      short8 a = lo ? *(const short8*)&kT[(size_t)mk*64 + h*16 + ko] : zz;
      #pragma unroll
      for (int ni = 0; ni < 4; ni++){
        short8 bq = lo ? *(const short8*)&qlds[ni*16 + l15][h*16 + ko] : zz;
        floatx4 l = __builtin_amdgcn_mfma_f32_16x16x32_bf16(a, bq,
                        (floatx4){0.f,0.f,0.f,0.f}, 0, 0, 0);
        float iv = inv_s[h][ni*16 + l15];
        o[ni][0] += __expf(l[0]) * iv;
        o[ni][1] += __expf(l[1]) * iv;
        o[ni][2] += __expf(l[2]) * iv;
        o[ni][3] += __expf(l[3]) * iv;
      }
    }
    #pragma unroll
    for (int ni = 0; ni < 4; ni++){
      nacc[ni] += o[ni][0]*o[ni][0] + o[ni][1]*o[ni][1]
                + o[ni][2]*o[ni][2] + o[ni][3]*o[ni][3];
      int n = n0 + ni*16 + l15;
      if (n < NQ){
        size_t off = (size_t)n*MM + mbase + qh*4;
        float4 v; v.x = o[ni][0]; v.y = o[ni][1]; v.z = o[ni][2]; v.w = o[ni][3];
        *(float4*)&mb[off] = v;
        ushort4 u;
        u.x = f2bf(v.x); u.y = f2bf(v.y); u.z = f2bf(v.z); u.w = f2bf(v.w);
        *(ushort4*)&ab[off] = u;
      }
    }
  }
  #pragma unroll
  for (int ni = 0; ni < 4; ni++){
    float v = nacc[ni];
    v += __shfl_xor(v, 16); v += __shfl_xor(v, 32);
    if (lane < 16) npart[w][ni*16 + lane] = v;
  }
  __syncthreads();
  if (tid < 64){
    int n = n0 + tid;
    if (n < NQ){
      float v = npart[0][tid] + npart[1][tid] + npart[2][tid] + npart[3][tid];
      atomicAdd(&norms[(size_t)b*NQ + n], v);
    }
  }
}

// C = A @ B^T (+bias). bf16 NT MFMA, wave per 64x64 tile. Row clamp Mr, col clamp Nc.
// bias index = bz*bstride + cc (bstride=0 -> shared bias across batch/z).
template<bool RELU>
__global__ __launch_bounds__(64) void mfma_nt_kernel(
    const unsigned short* __restrict__ A, size_t sA,
    const unsigned short* __restrict__ B, size_t sB,
    const float* __restrict__ bias, int bstride,
    float* __restrict__ C, unsigned short* __restrict__ C16,
    size_t sC, int ldc, int Mr, int Nc, int K){
  int bz = blockIdx.z;
  const unsigned short* Ab = A + (size_t)bz * sA;
  const unsigned short* Bb = B + (size_t)bz * sB;
  int lane = threadIdx.x;
  int r16 = lane & 15;
  int ko  = (lane >> 4) * 8;
  const unsigned short* arow[4];
  const unsigned short* brow[4];
  #pragma unroll
  for (int i = 0; i < 4; i++){
    int m = blockIdx.y*64 + i*16 + r16;
    if (m > Mr - 1) m = Mr - 1;
    arow[i] = Ab + (size_t)m * K + ko;
    int n = blockIdx.x*64 + i*16 + r16;
    if (n > Nc - 1) n = Nc - 1;
    brow[i] = Bb + (size_t)n * K + ko;
  }
  floatx4 acc[4][4];
  #pragma unroll
  for (int i = 0; i < 4; i++)
    #pragma unroll
    for (int j = 0; j < 4; j++)
      acc[i][j] = (floatx4){0.f, 0.f, 0.f, 0.f};
  short8 a[4], bv[4], a2[4], b2[4];
  #pragma unroll
  for (int i = 0; i < 4; i++){
    a[i]  = *(const short8*)(arow[i]);
    bv[i] = *(const short8*)(brow[i]);
  }
  for (int k = 32; k < K; k += 32){
    #pragma unroll
    for (int i = 0; i < 4; i++){
      a2[i] = *(const short8*)(arow[i] + k);
      b2[i] = *(const short8*)(brow[i] + k);
    }
    #pragma unroll
    for (int i = 0; i < 4; i++)
      #pragma unroll
      for (int j = 0; j < 4; j++)
        acc[i][j] = __builtin_amdgcn_mfma_f32_16x16x32_bf16(a[i], bv[j], acc[i][j], 0, 0, 0);
    #pragma unroll
    for (int i = 0; i < 4; i++){ a[i] = a2[i]; bv[i] = b2[i]; }
  }
  #pragma unroll
  for (int i = 0; i < 4; i++)
    #pragma unroll
    for (int j = 0; j < 4; j++)
      acc[i][j] = __builtin_amdgcn_mfma_f32_16x16x32_bf16(a[i], bv[j], acc[i][j], 0, 0, 0);
  int cq = lane & 15, rq = (lane >> 4) * 4;
  #pragma unroll
  for (int j = 0; j < 4; j++){
    int cc = blockIdx.x*64 + j*16 + cq;
    if (cc >= Nc) continue;
    float bv_ = bias ? bias[bz*bstride + cc] : 0.f;
    #pragma unroll
    for (int i = 0; i < 4; i++){
      int rbase = blockIdx.y*64 + i*16 + rq;
      #pragma unroll
      for (int reg = 0; reg < 4; reg++){
        int rr = rbase + reg;
        if (rr < Mr){
          float v = acc[i][j][reg] + bv_;
          if (RELU) v = fmaxf(v, 0.f);
          size_t o = (size_t)bz * sC + (size_t)rr * ldc + cc;
          if (C)   C[o] = v;
          if (C16) C16[o] = f2bf(v);
        }
      }
    }
  }
}

// 8-wave K-split GEMM (512 thr) with dual-buffer LDS reduction; writes bf16 C16 directly.
// Block = one 64x64 tile; wave w handles K-chunk [w*K/8, (w+1)*K/8).
// Waves 0..3 reduce into red[0], waves 4..7 into red[1] (concurrent groups, 4 phases each);
// final add red[0]+red[1] fused into the bf16 epilogue.
__global__ __launch_bounds__(512) void mfma_red8_kernel(
    const unsigned short* __restrict__ A, size_t sA,
    const unsigned short* __restrict__ B, size_t sB,
    unsigned short* __restrict__ C16, size_t sC, int ldc, int Mr, int K){
  int bz = blockIdx.z;
  int tid = threadIdx.x, w = tid >> 6, lane = tid & 63;
  int kchunk = K >> 3;
  const unsigned short* Ab = A + (size_t)bz * sA + (size_t)w * kchunk;
  const unsigned short* Bb = B + (size_t)bz * sB + (size_t)w * kchunk;
  int r16 = lane & 15;
  int ko  = (lane >> 4) * 8;
  const unsigned short* arow[4];
  const unsigned short* brow[4];
  #pragma unroll
  for (int i = 0; i < 4; i++){
    int m = blockIdx.y*64 + i*16 + r16;
    if (m > Mr - 1) m = Mr - 1;
    arow[i] = Ab + (size_t)m * K + ko;
    int n = blockIdx.x*64 + i*16 + r16;
    brow[i] = Bb + (size_t)n * K + ko;
  }
  floatx4 acc[4][4];
  #pragma unroll
  for (int i = 0; i < 4; i++)
    #pragma unroll
    for (int j = 0; j < 4; j++)
      acc[i][j] = (floatx4){0.f, 0.f, 0.f, 0.f};
  short8 a[4], bv[4], a2[4], b2[4];
  #pragma unroll
  for (int i = 0; i < 4; i++){
    a[i]  = *(const short8*)(arow[i]);
    bv[i] = *(const short8*)(brow[i]);
  }
  for (int k = 32; k < kchunk; k += 32){
    #pragma unroll
    for (int i = 0; i < 4; i++){
      a2[i] = *(const short8*)(arow[i] + k);
      b2[i] = *(const short8*)(brow[i] + k);
    }
    #pragma unroll
    for (int i = 0; i < 4; i++)
      #pragma unroll
      for (int j = 0; j < 4; j++)
        acc[i][j] = __builtin_amdgcn_mfma_f32_16x16x32_bf16(a[i], bv[j], acc[i][j], 0, 0, 0);
    #pragma unroll
    for (int i = 0; i < 4; i++){ a[i] = a2[i]; bv[i] = b2[i]; }
  }
  #pragma unroll
  for (int i = 0; i < 4; i++)
    #pragma unroll
    for (int j = 0; j < 4; j++)
      acc[i][j] = __builtin_amdgcn_mfma_f32_16x16x32_bf16(a[i], bv[j], acc[i][j], 0, 0, 0);
  // dual-group LDS reduction: group g = w>>2 has its own buffer; 4 phases per group
  __shared__ float red[2][64][65];
  int g = w >> 2, ph = w & 3;
  int cq = lane & 15, rq = (lane >> 4) * 4;
  #pragma unroll 1
  for (int p = 0; p < 4; p++){
    if (ph == p){
      #pragma unroll
      for (int i = 0; i < 4; i++)
        #pragma unroll
        for (int reg = 0; reg < 4; reg++){
          int r = i*16 + rq + reg;
          #pragma unroll
          for (int j = 0; j < 4; j++){
            int c = j*16 + cq;
            if (p == 0) red[g][r][c] = acc[i][j][reg];
            else        red[g][r][c] += acc[i][j][reg];
          }
        }
    }
    __syncthreads();
  }
  // fused bf16 epilogue: 1024 ushort4 quads, 2 per thread; adds the two group buffers
  unsigned short* Cb = C16 + (size_t)bz * sC;
  for (int idx = tid; idx < 1024; idx += 512){
    int r = idx >> 4, c4 = (idx & 15) * 4;
    int gr = blockIdx.y*64 + r;
    if (gr < Mr){
      ushort4 u;
      u.x = f2bf(red[0][r][c4+0] + red[1][r][c4+0]);
      u.y = f2bf(red[0][r][c4+1] + red[1][r][c4+1]);
      u.z = f2bf(red[0][r][c4+2] + red[1][r][c4+2]);
      u.w = f2bf(red[0][r][c4+3] + red[1][r][c4+3]);
      *(ushort4*)&Cb[(size_t)gr * ldc + blockIdx.x*64 + c4] = u;
    }
  }
}

// LayerNorm(x + bias) + ReLU over 256-wide rows for BOTH heads (z = blockIdx.y).
__global__ __launch_bounds__(256) void ln_relu2_kernel(const float* __restrict__ zin,
    const float* __restrict__ bias_b, const float* __restrict__ bias_c,
    const float* __restrict__ g_b, const float* __restrict__ be_b,
    const float* __restrict__ g_c, const float* __restrict__ be_c,
    unsigned short* __restrict__ zout){
  int z = blockIdx.y;
  const float* bias = z ? bias_c : bias_b;
  const float* g    = z ? g_c : g_b;
  const float* be   = z ? be_c : be_b;
  const float* zi = zin + (size_t)z * 1228800;
  unsigned short* zo = zout + (size_t)z * 1228800;
  int row = blockIdx.x * 4 + (threadIdx.x >> 6);
  int lane = threadIdx.x & 63;
  float4 v = *(const float4*)&zi[(size_t)row * 256 + lane * 4];
  float4 bi = *(const float4*)&bias[lane * 4];
  v.x += bi.x; v.y += bi.y; v.z += bi.z; v.w += bi.w;
  float s = v.x + v.y + v.z + v.w;
  #pragma unroll
  for (int off = 32; off >= 1; off >>= 1) s += __shfl_xor(s, off);
  float mean = s * (1.f/256.f);
  float dx = v.x - mean, dy = v.y - mean, dz = v.z - mean, dw = v.w - mean;
  float sq = dx*dx + dy*dy + dz*dz + dw*dw;
  #pragma unroll
  for (int off = 32; off >= 1; off >>= 1) sq += __shfl_xor(sq, off);
  float inv = rsqrtf(sq * (1.f/256.f) + 1e-5f);
  float4 gv = *(const float4*)&g[lane * 4];
  float4 bb = *(const float4*)&be[lane * 4];
  ushort4 u;
  u.x = f2bf(fmaxf(dx*inv*gv.x + bb.x, 0.f));
  u.y = f2bf(fmaxf(dy*inv*gv.y + bb.y, 0.f));
  u.z = f2bf(fmaxf(dz*inv*gv.z + bb.z, 0.f));
  u.w = f2bf(fmaxf(dw*inv*gv.w + bb.w, 0.f));
  *(ushort4*)&zo[(size_t)row * 256 + lane * 4] = u;
}

// final tiny projections: boxes = z2bb @ bb3^T + b; scores = sigmoid(z2ch @ ch3^T + b)
__global__ __launch_bounds__(256) void head3_kernel(
    const unsigned short* __restrict__ z2bb, const unsigned short* __restrict__ z2ch,
    const float* __restrict__ bb3_w, const float* __restrict__ bb3_b,
    const float* __restrict__ ch3_w, const float* __restrict__ ch3_b,
    float* __restrict__ boxes, float* __restrict__ scores){
  int row = blockIdx.x * 4 + (threadIdx.x >> 6);
  int lane = threadIdx.x & 63;
  float zb0 = bf1(z2bb[(size_t)row*128 + 2*lane]);
  float zb1 = bf1(z2bb[(size_t)row*128 + 2*lane + 1]);
  float zc0 = bf1(z2ch[(size_t)row*128 + 2*lane]);
  float zc1 = bf1(z2ch[(size_t)row*128 + 2*lane + 1]);
  float acc[5];
  #pragma unroll
  for (int o = 0; o < 4; o++)
    acc[o] = bb3_w[o*128 + 2*lane]*zb0 + bb3_w[o*128 + 2*lane + 1]*zb1;
  acc[4] = ch3_w[2*lane]*zc0 + ch3_w[2*lane + 1]*zc1;
  #pragma unroll
  for (int o = 0; o < 5; o++){
    float v = acc[o];
    #pragma unroll
    for (int off = 32; off >= 1; off >>= 1) v += __shfl_xor(v, off);
    acc[o] = v;
  }
  if (lane == 0){
    #pragma unroll
    for (int o = 0; o < 4; o++)
      boxes[(size_t)row*4 + o] = acc[o] + bb3_b[o];
    float sv = acc[4] + ch3_b[0];
    scores[row] = 1.f / (1.f + __expf(-sv));
  }
}

// diversity: sum_m (sum_n attn[n,m]/||attn_n||)^2  (norms holds SUM OF SQUARES)
__global__ __launch_bounds__(256) void simdiv_kernel(const unsigned short* __restrict__ attn16,
    const float* __restrict__ norms, float* __restrict__ acc){
  int b = blockIdx.y;
  int m = blockIdx.x * 256 + threadIdx.x;
  __shared__ float inv_s[NQ];
  __shared__ float red[4];
  for (int i = threadIdx.x; i < NQ; i += 256)
    inv_s[i] = 1.f / fmaxf(sqrtf(norms[(size_t)b * NQ + i]), 1e-12f);
  __syncthreads();
  const unsigned short* ab = attn16 + (size_t)b * NQ * MM;
  float S = 0.f;
  for (int n = 0; n < NQ; n++)
    S += bf1(ab[(size_t)n * MM + m]) * inv_s[n];
  float p = S * S;
  #pragma unroll
  for (int off = 32; off >= 1; off >>= 1) p += __shfl_xor(p, off);
  int w = threadIdx.x >> 6, lane = threadIdx.x & 63;
  if (lane == 0) red[w] = p;
  __syncthreads();
  if (threadIdx.x == 0) atomicAdd(acc, red[0] + red[1] + red[2] + red[3]);
}

__global__ void finalize_kernel(const float* __restrict__ acc, float* __restrict__ out_div){
  out_div[0] = (acc[0] - (float)(BB * NQ)) / (float)(NQ * (NQ - 1)) * 0.1f;
}

extern "C" void kernel_launch(void* const* d_in, const int* in_sizes, int n_in,
                              void* d_out, int out_size, void* d_ws, size_t ws_size,
                              hipStream_t stream){
  const float* x      = (const float*)d_in[0];
  const float* ss     = (const float*)d_in[1];
  const float* pos_w  = (const float*)d_in[2];
  const float* pos_b  = (const float*)d_in[3];
  const float* fp_w   = (const float*)d_in[4];
  const float* fp_b   = (const float*)d_in[5];
  const float* bn_g   = (const float*)d_in[6];
  const float* bn_b   = (const float*)d_in[7];
  const float* bn_m   = (const float*)d_in[8];
  const float* bn_v   = (const float*)d_in[9];
  const float* key_w  = (const float*)d_in[10];
  const float* key_b  = (const float*)d_in[11];
  const float* val_w  = (const float*)d_in[12];
  const float* val_b  = (const float*)d_in[13];
  const float* ctp_w  = (const float*)d_in[14];
  const float* ctp_b  = (const float*)d_in[15];
  const float* bb1_w  = (const float*)d_in[16];
  const float* bb1_b  = (const float*)d_in[17];
  const float* bbln_g = (const float*)d_in[18];
  const float* bbln_b = (const float*)d_in[19];
  const float* bb2_w  = (const float*)d_in[20];
  const float* bb2_b  = (const float*)d_in[21];
  const float* bb3_w  = (const float*)d_in[22];
  const float* bb3_b  = (const float*)d_in[23];
  const float* ch1_w  = (const float*)d_in[24];
  const float* ch1_b  = (const float*)d_in[25];
  const float* chln_g = (const float*)d_in[26];
  const float* chln_b = (const float*)d_in[27];
  const float* ch2_w  = (const float*)d_in[28];
  const float* ch2_b  = (const float*)d_in[29];
  const float* ch3_w  = (const float*)d_in[30];
  const float* ch3_b  = (const float*)d_in[31];

  float* out    = (float*)d_out;
  float* boxes  = out + OFF_BOXES;
  float* scores = out + OFF_SCORES;
  float* cls    = out + OFF_CLS;
  float* maps   = out + OFF_MAPS;
  float* divp   = out + OFF_DIV;
  float* sfout  = out + OFF_SF;

  float* ws = (float*)d_ws;
  unsigned short* comb16 = (unsigned short*)(ws + WS_COMB16);
  unsigned short* keysT  = (unsigned short*)(ws + WS_KEYS16);
  unsigned short* attn16 = (unsigned short*)(ws + WS_ATTN16);
  unsigned short* t16    = (unsigned short*)(ws + WS_T16);
  unsigned short* valw16 = (unsigned short*)(ws + WS_VALW16);
  float* sums  = ws + WS_SUMS;
  float* norms = ws + WS_NORM;
  float* dacc  = ws + WS_ACC;
  unsigned short* sf16   = (unsigned short*)(ws + HP_SF16);
  unsigned short* z2bb16 = (unsigned short*)(ws + HP_Z2BB);
  unsigned short* z2ch16 = (unsigned short*)(ws + HP_Z2CH);
  unsigned short* hw16   = (unsigned short*)(ws + HP_HW);
  float*          b2ws   = ws + WS_B2;
  unsigned short* q16    = (unsigned short*)(ws + WS_Q16);
  unsigned short* xT16   = (unsigned short*)(ws + WS_XT);
  unsigned short* combT  = (unsigned short*)(ws + WS_COMBT);
  unsigned short* fpw16  = (unsigned short*)(ws + WS_FPW16);
  unsigned short* keyw16 = (unsigned short*)(ws + WS_KEYW16);
  float*          z1pre2 = ws + WS_Z1PRE2;
  unsigned short* z1b16  = (unsigned short*)(ws + WS_Z1B16);

  // sums + norms + dacc are contiguous -> one zeroing pass (covers dacc)
  zero4_kernel<<<24, 256, 0, stream>>>((float4*)sums, 6002);
  init_kernel<<<128, 256, 0, stream>>>(ss, fp_w, key_w, q16, fpw16, keyw16);

  // x (b,256,4096) fp32 -> xT16 (b,4096,256) bf16
  transpose_x_kernel<<<dim3(64,4,16), 256, 0, stream>>>(x, xT16);
  // pos encoding into comb16 rows 128..255 AND combT cols 128..255
  pos_kernel<<<8704, 256, 0, stream>>>(pos_w, pos_b, comb16, combT);
  // comb rows 0..127 = relu(bn(fp_w @ x)) via MFMA, dual-layout store
  comb_mfma_kernel<<<dim3(64,2,16), 64, 0, stream>>>(
      fpw16, xT16, fp_b, bn_g, bn_b, bn_m, bn_v, comb16, combT);
  // keysT[m][d] = combT @ key_w^T + key_b (D-layout = m-major)
  mfma_nt_kernel<false><<<dim3(1,64,16), 64, 0, stream>>>(
      combT, (size_t)MM*CIN, keyw16, 0, key_b, 0,
      nullptr, keysT, (size_t)MM*64, 64, MM, 64, CIN);

  // fused no-P attention: swapped-operand MFMA logits, 2 passes
  attn_sums_kernel<<<dim3(32,5,16), 256, 0, stream>>>(q16, keysT, sums);
  attn_emit_kernel<<<dim3(32,5,16), 256, 0, stream>>>(q16, keysT, sums, maps, attn16, norms);

  // t16 = bf16(attn @ comb^T)  (8-wave K-split, dual-buffer in-block reduce, no partials)
  mfma_red8_kernel<<<dim3(4,5,BB), 512, 0, stream>>>(
      attn16, (size_t)NQ*MM, comb16, (size_t)HIDC*MM,
      t16, (size_t)NQ*HIDC, HIDC, NQ, MM);
  cast_heads_kernel<<<256, 256, 0, stream>>>(val_w, bb1_w, ch1_w, bb2_w, ch2_w, ctp_w,
                                             bb2_b, ch2_b, valw16, hw16, b2ws);
  // sf = t @ val_w^T + val_b  (fp32 into d_out, bf16 into sf16)
  mfma_nt_kernel<false><<<dim3(4,5,BB), 64, 0, stream>>>(
      t16, (size_t)NQ*HIDC, valw16, 0, val_b, 0,
      sfout, sf16, (size_t)NQ*HIDC, HIDC, NQ, HIDC, HIDC);

  // ---- both heads, merged (z=0 boxes, z=1 scores) ----
  mfma_nt_kernel<false><<<dim3(4,75,2), 64, 0, stream>>>(
      sf16, 0, hw16 + HW_BB1, (size_t)(HW_CH1 - HW_BB1), nullptr, 0,
      z1pre2, nullptr, (size_t)4800*256, 256, 4800, 256, 256);
  ln_relu2_kernel<<<dim3(1200,2), 256, 0, stream>>>(
      z1pre2, bb1_b, ch1_b, bbln_g, bbln_b, chln_g, chln_b, z1b16);
  mfma_nt_kernel<true><<<dim3(2,75,2), 64, 0, stream>>>(
      z1b16, (size_t)4800*256, hw16 + HW_BB2, (size_t)(HW_CH2 - HW_BB2), b2ws, 128,
      nullptr, z2bb16, (size_t)4800*128, 128, 4800, 128, 256);
  // ---- finals + cls ----
  head3_kernel<<<1200, 256, 0, stream>>>(z2bb16, z2ch16, bb3_w, bb3_b, ch3_w, ch3_b, boxes, scores);
  mfma_nt_kernel<false><<<dim3(2,75,1), 64, 0, stream>>>(
      sf16, 0, hw16 + HW_CTP, 0, ctp_b, 0, cls, nullptr, 0, 80, 4800, 80, 256);

  simdiv_kernel<<<dim3(16,16), 256, 0, stream>>>(attn16, norms, dacc);
  finalize_kernel<<<1, 1, 0, stream>>>(dacc, divp);
}

// Round 8
// 500.883 us; speedup vs baseline: 1.0348x; 1.0348x over previous
//
#include <hip/hip_runtime.h>
#include <math.h>

// ---- problem constants ----
#define BB 16
#define CIN 256
#define MM 4096      // H*W
#define HIDC 256
#define NQ 300
#define NHH 4
#define HDD 16

// ---- output offsets (floats) ----
#define OFF_BOXES  0
#define OFF_SCORES 19200
#define OFF_CLS    24000
#define OFF_MAPS   408000
#define OFF_DIV    20068800
#define OFF_SF     20068801

// ---- workspace offsets (in floats) ----
#define WS_COMB16  0            // 16*256*4096 ushort  (comb, c-major: [c][m])
#define WS_KEYS16  8388608      // keysT: (b, m=4096, d=64) bf16
#define WS_ATTN16  10485760     // 16*300*4096 ushort
#define WS_T16     21544960     // 16*300*256 ushort
#define WS_VALW16  22159360     // 65536 ushort
#define WS_SUMS    22192128     // 16*4*300 fp32 (exp-sum; atomically accumulated)
#define WS_NORM    22211328     // 4800 floats: SUM OF SQUARES per (b,n)
#define WS_ACC     22216128     // 1 float (+pad) -- contiguous after norms (one zero pass)
#define WS_P       22216192     // head scratch base

// head scratch
#define HP_SF16   (WS_P + 0)         // 4800x256 bf16  (614400 fl)
#define HP_Z2BB   (WS_P + 2457600)   // 4800x128 bf16  (307200 fl)
#define HP_Z2CH   (WS_P + 2764800)   // 4800x128 bf16  (307200 fl) -- contiguous after Z2BB
#define HP_HW     (WS_P + 3072000)   // head weights bf16 (~108.6k fl)
#define WS_B2     (WS_P + 3180544)   // 256 fp32: [bb2_b | ch2_b] contiguous
#define WS_Q16    (WS_P + 3200000)   // 320x64 bf16 q (0.25-scaled, rows 300..319 zero)
// MFMA-path buffers
#define WS_XT     25426432      // xT16: (b,4096,256) bf16 = 8388608 fl (dead after comb_mfma)
#define WS_COMBT  33815040      // combT: (b, m=4096, c=256) bf16 = 8388608 fl
#define WS_FPW16  42203648      // fp_w rows 0..127 bf16
#define WS_KEYW16 42220032      // key_w bf16
#define WS_Z1PRE2 42228224      // 2 x 4800x256 fp32 = 2457600 fl (boxes|scores z1 pre-LN)
#define WS_Z1B16  44685824      // 2 x 4800x256 bf16 = 1228800 fl
// total ≈ 45914624 fl ≈ 184 MB (harness provides ≥246 MB)

// ushort offsets within HP_HW:
#define HW_BB1 0
#define HW_CH1 65536
#define HW_BB2 131072
#define HW_CH2 163840
#define HW_CTP 196608

typedef short short8 __attribute__((ext_vector_type(8)));
typedef float floatx4 __attribute__((ext_vector_type(4)));

__device__ __forceinline__ unsigned short f2bf(float f){
  unsigned int u = __float_as_uint(f);
  u = (u + 0x7FFFu + ((u >> 16) & 1u)) >> 16;
  return (unsigned short)u;
}
__device__ __forceinline__ float bf1(unsigned short u){
  return __uint_as_float((unsigned int)u << 16);
}

__global__ __launch_bounds__(256) void zero4_kernel(float4* __restrict__ p, int n4){
  int i = blockIdx.x * 256 + threadIdx.x;
  if (i < n4) p[i] = make_float4(0.f, 0.f, 0.f, 0.f);
}

// fused init: q16 (0.25-scaled, 320-row pad), fp_w rows 0..127 bf16, key_w bf16
__global__ __launch_bounds__(256) void init_kernel(const float* __restrict__ ss,
    const float* __restrict__ fp_w, const float* __restrict__ key_w,
    unsigned short* __restrict__ q16, unsigned short* __restrict__ fpw16,
    unsigned short* __restrict__ keyw16){
  int i = blockIdx.x * 256 + threadIdx.x;
  int T = gridDim.x * 256;
  for (int j = i; j < 320*64; j += T)
    q16[j] = (j < NQ*64) ? f2bf(ss[j] * 0.25f) : (unsigned short)0;
  for (int j = i; j < 128*256; j += T) fpw16[j] = f2bf(fp_w[j]);
  for (int j = i; j < 64*256; j += T)  keyw16[j] = f2bf(key_w[j]);
}

// one fused cast of all bf16 weight copies + contiguous gemm2 biases
__global__ __launch_bounds__(256) void cast_heads_kernel(
    const float* __restrict__ val_w, const float* __restrict__ bb1_w,
    const float* __restrict__ ch1_w, const float* __restrict__ bb2_w,
    const float* __restrict__ ch2_w, const float* __restrict__ ctp_w,
    const float* __restrict__ bb2_b, const float* __restrict__ ch2_b,
    unsigned short* __restrict__ valw16, unsigned short* __restrict__ hw16,
    float* __restrict__ b2){
  int i = blockIdx.x * 256 + threadIdx.x;
  int T = gridDim.x * 256;
  for (int j = i; j < 65536; j += T) valw16[j] = f2bf(val_w[j]);
  for (int j = i; j < 65536; j += T) hw16[HW_BB1 + j] = f2bf(bb1_w[j]);
  for (int j = i; j < 65536; j += T) hw16[HW_CH1 + j] = f2bf(ch1_w[j]);
  for (int j = i; j < 32768; j += T) hw16[HW_BB2 + j] = f2bf(bb2_w[j]);
  for (int j = i; j < 32768; j += T) hw16[HW_CH2 + j] = f2bf(ch2_w[j]);
  for (int j = i; j < 20480; j += T) hw16[HW_CTP + j] = f2bf(ctp_w[j]);
  for (int j = i; j < 128; j += T){ b2[j] = bb2_b[j]; b2[128 + j] = ch2_b[j]; }
}

// pos encoding into BOTH layouts: comb16[c][m] rows 128..255 (ushort4 over m)
// and combT[m][128+c] (ushort4 over c). One kernel, linear id split.
__global__ __launch_bounds__(256) void pos_kernel(const float* __restrict__ pos_w,
                                                  const float* __restrict__ pos_b,
                                                  unsigned short* __restrict__ comb16,
                                                  unsigned short* __restrict__ combT){
  int lin = blockIdx.x * 256 + threadIdx.x;
  if (lin < 2097152){                     // part A: comb16, thread -> (b, c, m4)
    int m  = (lin & 1023) * 4;
    int c  = (lin >> 10) & 127;
    int b  = lin >> 17;
    int row = m >> 6, col = m & 63;
    float y  = -1.f + 2.f * (float)row / 63.f;
    float wy = pos_w[c*2], wx = pos_w[c*2+1], pb = pos_b[c];
    float base = wy * y + pb;
    ushort4 u;
    u.x = f2bf(base + wx * (-1.f + 2.f * (float)(col+0) / 63.f));
    u.y = f2bf(base + wx * (-1.f + 2.f * (float)(col+1) / 63.f));
    u.z = f2bf(base + wx * (-1.f + 2.f * (float)(col+2) / 63.f));
    u.w = f2bf(base + wx * (-1.f + 2.f * (float)(col+3) / 63.f));
    *(ushort4*)&comb16[((size_t)(b*HIDC + 128 + c))*MM + m] = u;
  } else if (lin < 2097152 + 131072){     // part B: combT, thread -> (m, c4)
    int l2 = lin - 2097152;
    int c4 = (l2 & 31) * 4;
    int m  = l2 >> 5;
    int row = m >> 6, col = m & 63;
    float y = -1.f + 2.f * (float)row / 63.f;
    float x = -1.f + 2.f * (float)col / 63.f;
    ushort4 u;
    u.x = f2bf(pos_w[(c4+0)*2] * y + pos_w[(c4+0)*2+1] * x + pos_b[c4+0]);
    u.y = f2bf(pos_w[(c4+1)*2] * y + pos_w[(c4+1)*2+1] * x + pos_b[c4+1]);
    u.z = f2bf(pos_w[(c4+2)*2] * y + pos_w[(c4+2)*2+1] * x + pos_b[c4+2]);
    u.w = f2bf(pos_w[(c4+3)*2] * y + pos_w[(c4+3)*2+1] * x + pos_b[c4+3]);
    #pragma unroll
    for (int b = 0; b < BB; b++)
      *(ushort4*)&combT[((size_t)b*MM + m)*CIN + 128 + c4] = u;
  }
}

// x (b, 256, 4096) fp32 -> xT16 (b, 4096, 256) bf16; one 64x64 tile per block.
__global__ __launch_bounds__(256) void transpose_x_kernel(
    const float* __restrict__ in, unsigned short* __restrict__ outp){
  int b = blockIdx.z;
  int m0 = blockIdx.x * 64;
  int r0 = blockIdx.y * 64;
  __shared__ unsigned short lds[64][68];
  int t = threadIdx.x;
  const float* ib = in + (size_t)b * CIN * MM;
  #pragma unroll
  for (int j = 0; j < 4; j++){
    int lin = j*256 + t;
    int rr = lin >> 4;
    int m4 = (lin & 15) * 4;
    float4 v = *(const float4*)&ib[(size_t)(r0 + rr)*MM + m0 + m4];
    lds[m4+0][rr] = f2bf(v.x);
    lds[m4+1][rr] = f2bf(v.y);
    lds[m4+2][rr] = f2bf(v.z);
    lds[m4+3][rr] = f2bf(v.w);
  }
  __syncthreads();
  unsigned short* ob = outp + (size_t)b * MM * CIN;
  #pragma unroll
  for (int j = 0; j < 4; j++){
    int lin = j*256 + t;
    int mm = lin >> 4;
    int c4 = (lin & 15) * 4;
    ushort4 u;
    u.x = lds[mm][c4+0]; u.y = lds[mm][c4+1];
    u.z = lds[mm][c4+2]; u.w = lds[mm][c4+3];
    *(ushort4*)&ob[(size_t)(m0 + mm)*CIN + r0 + c4] = u;
  }
}

// comb rows 0..127 via MFMA with DUAL-layout store:
//   comb16[c][m] (scalar, c-major) AND combT[m][c] (ushort4: reg axis = 4 consecutive c).
__global__ __launch_bounds__(64) void comb_mfma_kernel(
    const unsigned short* __restrict__ fpw16, const unsigned short* __restrict__ xT16,
    const float* __restrict__ fp_b, const float* __restrict__ bn_g,
    const float* __restrict__ bn_b, const float* __restrict__ bn_m,
    const float* __restrict__ bn_v, unsigned short* __restrict__ comb16,
    unsigned short* __restrict__ combT){
  int b = blockIdx.z;
  const unsigned short* Bb = xT16 + (size_t)b * MM * CIN;
  unsigned short* cb  = comb16 + (size_t)b * HIDC * MM;
  unsigned short* cTb = combT + (size_t)b * MM * CIN;
  int lane = threadIdx.x;
  int r16 = lane & 15;
  int ko  = (lane >> 4) * 8;
  const unsigned short* arow[4];
  const unsigned short* brow[4];
  #pragma unroll
  for (int i = 0; i < 4; i++){
    arow[i] = fpw16 + (size_t)(blockIdx.y*64 + i*16 + r16) * CIN + ko;
    brow[i] = Bb + (size_t)(blockIdx.x*64 + i*16 + r16) * CIN + ko;
  }
  floatx4 acc[4][4];
  #pragma unroll
  for (int i = 0; i < 4; i++)
    #pragma unroll
    for (int j = 0; j < 4; j++)
      acc[i][j] = (floatx4){0.f, 0.f, 0.f, 0.f};
  short8 a[4], bv[4], a2[4], b2[4];
  #pragma unroll
  for (int i = 0; i < 4; i++){
    a[i]  = *(const short8*)(arow[i]);
    bv[i] = *(const short8*)(brow[i]);
  }
  for (int k = 32; k < CIN; k += 32){
    #pragma unroll
    for (int i = 0; i < 4; i++){
      a2[i] = *(const short8*)(arow[i] + k);
      b2[i] = *(const short8*)(brow[i] + k);
    }
    #pragma unroll
    for (int i = 0; i < 4; i++)
      #pragma unroll
      for (int j = 0; j < 4; j++)
        acc[i][j] = __builtin_amdgcn_mfma_f32_16x16x32_bf16(a[i], bv[j], acc[i][j], 0, 0, 0);
    #pragma unroll
    for (int i = 0; i < 4; i++){ a[i] = a2[i]; bv[i] = b2[i]; }
  }
  #pragma unroll
  for (int i = 0; i < 4; i++)
    #pragma unroll
    for (int j = 0; j < 4; j++)
      acc[i][j] = __builtin_amdgcn_mfma_f32_16x16x32_bf16(a[i], bv[j], acc[i][j], 0, 0, 0);
  int cq = lane & 15, rq = (lane >> 4) * 4;
  #pragma unroll
  for (int i = 0; i < 4; i++){
    int rbase = blockIdx.y*64 + i*16 + rq;
    float mul[4], ofs[4];
    #pragma unroll
    for (int reg = 0; reg < 4; reg++){
      int rr = rbase + reg;
      float sc = rsqrtf(bn_v[rr] + 1e-5f);
      mul[reg] = sc * bn_g[rr];
      ofs[reg] = (fp_b[rr] - bn_m[rr]) * mul[reg] + bn_b[rr];
    }
    #pragma unroll
    for (int j = 0; j < 4; j++){
      int cc = blockIdx.x*64 + j*16 + cq;
      ushort4 u;
      float v0 = fmaxf(acc[i][j][0] * mul[0] + ofs[0], 0.f); u.x = f2bf(v0);
      float v1 = fmaxf(acc[i][j][1] * mul[1] + ofs[1], 0.f); u.y = f2bf(v1);
      float v2 = fmaxf(acc[i][j][2] * mul[2] + ofs[2], 0.f); u.z = f2bf(v2);
      float v3 = fmaxf(acc[i][j][3] * mul[3] + ofs[3], 0.f); u.w = f2bf(v3);
      cb[(size_t)(rbase+0) * MM + cc] = u.x;
      cb[(size_t)(rbase+1) * MM + cc] = u.y;
      cb[(size_t)(rbase+2) * MM + cc] = u.z;
      cb[(size_t)(rbase+3) * MM + cc] = u.w;
      *(ushort4*)&cTb[(size_t)cc * CIN + rbase] = u;
    }
  }
}

// ======== fused no-P attention: SWAPPED-operand MFMA logits, 2 passes ========
// mfma(a=k, b=q): D col = n (lane&15), D row = m ((lane>>4)*4 + reg).

// pass 1: sums[b][h][n] = sum_m exp(q.k/4). grid (32 m-chunks, 5 n-tiles, 16 b), 256 thr.
__global__ __launch_bounds__(256) void attn_sums_kernel(
    const unsigned short* __restrict__ q16, const unsigned short* __restrict__ keysT,
    float* __restrict__ sums){
  int b = blockIdx.z, ny = blockIdx.y, mx = blockIdx.x;
  int tid = threadIdx.x, w = tid >> 6, lane = tid & 63;
  int n0 = ny * 64;
  int l15 = lane & 15, qh = lane >> 4;
  int ko = (qh & 1) * 8;
  bool lo = lane < 32;
  const unsigned short* kT = keysT + (size_t)b * MM * 64;
  int mwb = mx*128 + w*32;
  __shared__ unsigned short qlds[64][72];
  __shared__ float spart[4][NHH][64];
  for (int c = tid; c < 512; c += 256){
    int r = c >> 3, d8 = (c & 7) * 8;
    *(short8*)&qlds[r][d8] = *(const short8*)&q16[(size_t)(n0 + r)*64 + d8];
  }
  __syncthreads();
  short8 zz = {0,0,0,0,0,0,0,0};
  #pragma unroll 1
  for (int h = 0; h < NHH; h++){
    short8 bq[4];
    #pragma unroll
    for (int ni = 0; ni < 4; ni++)
      bq[ni] = lo ? *(const short8*)&qlds[ni*16 + l15][h*16 + ko] : zz;
    float sacc[4] = {0.f, 0.f, 0.f, 0.f};
    #pragma unroll
    for (int ms = 0; ms < 2; ms++){
      int m = mwb + ms*16 + l15;
      short8 a = lo ? *(const short8*)&kT[(size_t)m*64 + h*16 + ko] : zz;
      #pragma unroll
      for (int ni = 0; ni < 4; ni++){
        floatx4 l = __builtin_amdgcn_mfma_f32_16x16x32_bf16(a, bq[ni],
                        (floatx4){0.f,0.f,0.f,0.f}, 0, 0, 0);
        sacc[ni] += __expf(l[0]) + __expf(l[1]) + __expf(l[2]) + __expf(l[3]);
      }
    }
    #pragma unroll
    for (int ni = 0; ni < 4; ni++){
      float v = sacc[ni];
      v += __shfl_xor(v, 16); v += __shfl_xor(v, 32);
      if (lane < 16) spart[w][h][ni*16 + lane] = v;
    }
  }
  __syncthreads();
  if (tid < NHH*64){
    int h = tid >> 6, r = tid & 63, n = n0 + r;
    if (n < NQ){
      float v = spart[0][h][r] + spart[1][h][r] + spart[2][h][r] + spart[3][h][r];
      atomicAdd(&sums[((size_t)b*NHH + h)*NQ + n], v);
    }
  }
}

// pass 2: attn[b][n][m] = sum_h exp(q.k/4) * (0.25/S_bhn); vectorized float4/ushort4 stores.
__global__ __launch_bounds__(256) void attn_emit_kernel(
    const unsigned short* __restrict__ q16, const unsigned short* __restrict__ keysT,
    const float* __restrict__ sums, float* __restrict__ maps,
    unsigned short* __restrict__ attn16, float* __restrict__ norms){
  int b = blockIdx.z, ny = blockIdx.y, mx = blockIdx.x;
  int tid = threadIdx.x, w = tid >> 6, lane = tid & 63;
  int n0 = ny * 64;
  int l15 = lane & 15, qh = lane >> 4;
  int ko = (qh & 1) * 8;
  bool lo = lane < 32;
  __shared__ unsigned short qlds[64][72];
  __shared__ float inv_s[NHH][64];
  __shared__ float npart[4][64];
  for (int c = tid; c < 512; c += 256){
    int r = c >> 3, d8 = (c & 7) * 8;
    *(short8*)&qlds[r][d8] = *(const short8*)&q16[(size_t)(n0 + r)*64 + d8];
  }
  if (tid < NHH*64){
    int h = tid >> 6, r = tid & 63, n = n0 + r;
    inv_s[h][r] = (n < NQ) ? 0.25f / sums[((size_t)b*NHH + h)*NQ + n] : 0.f;
  }
  __syncthreads();
  const unsigned short* kT = keysT + (size_t)b * MM * 64;
  int mwb = mx*128 + w*32;
  short8 zz = {0,0,0,0,0,0,0,0};
  float nacc[4] = {0.f, 0.f, 0.f, 0.f};
  float* mb = maps + (size_t)b * NQ * MM;
  unsigned short* ab = attn16 + (size_t)b * NQ * MM;
  #pragma unroll 1
  for (int ms = 0; ms < 2; ms++){
    asm volatile("" ::: "memory");   // defeat LICM: q frags re-read from LDS each iter
    int mbase = mwb + ms*16;
    int mk = mbase + l15;
    floatx4 o[4];
    #pragma unroll
    for (int ni = 0; ni < 4; ni++) o[ni] = (floatx4){0.f,0.f,0.f,0.f};
    #pragma unroll
    for (int h = 0; h < NHH; h++){
      short8 a = lo ? *(const short8*)&kT[(size_t)mk*64 + h*16 + ko] : zz;
      #pragma unroll
      for (int ni = 0; ni < 4; ni++){
        short8 bq = lo ? *(const short8*)&qlds[ni*16 + l15][h*16 + ko] : zz;
        floatx4 l = __builtin_amdgcn_mfma_f32_16x16x32_bf16(a, bq,
                        (floatx4){0.f,0.f,0.f,0.f}, 0, 0, 0);
        float iv = inv_s[h][ni*16 + l15];
        o[ni][0] += __expf(l[0]) * iv;
        o[ni][1] += __expf(l[1]) * iv;
        o[ni][2] += __expf(l[2]) * iv;
        o[ni][3] += __expf(l[3]) * iv;
      }
    }
    #pragma unroll
    for (int ni = 0; ni < 4; ni++){
      nacc[ni] += o[ni][0]*o[ni][0] + o[ni][1]*o[ni][1]
                + o[ni][2]*o[ni][2] + o[ni][3]*o[ni][3];
      int n = n0 + ni*16 + l15;
      if (n < NQ){
        size_t off = (size_t)n*MM + mbase + qh*4;
        float4 v; v.x = o[ni][0]; v.y = o[ni][1]; v.z = o[ni][2]; v.w = o[ni][3];
        *(float4*)&mb[off] = v;
        ushort4 u;
        u.x = f2bf(v.x); u.y = f2bf(v.y); u.z = f2bf(v.z); u.w = f2bf(v.w);
        *(ushort4*)&ab[off] = u;
      }
    }
  }
  #pragma unroll
  for (int ni = 0; ni < 4; ni++){
    float v = nacc[ni];
    v += __shfl_xor(v, 16); v += __shfl_xor(v, 32);
    if (lane < 16) npart[w][ni*16 + lane] = v;
  }
  __syncthreads();
  if (tid < 64){
    int n = n0 + tid;
    if (n < NQ){
      float v = npart[0][tid] + npart[1][tid] + npart[2][tid] + npart[3][tid];
      atomicAdd(&norms[(size_t)b*NQ + n], v);
    }
  }
}

// C = A @ B^T (+bias). bf16 NT MFMA, wave per 64x64 tile. Row clamp Mr, col clamp Nc.
// bias index = bz*bstride + cc (bstride=0 -> shared bias across batch/z).
template<bool RELU>
__global__ __launch_bounds__(64) void mfma_nt_kernel(
    const unsigned short* __restrict__ A, size_t sA,
    const unsigned short* __restrict__ B, size_t sB,
    const float* __restrict__ bias, int bstride,
    float* __restrict__ C, unsigned short* __restrict__ C16,
    size_t sC, int ldc, int Mr, int Nc, int K){
  int bz = blockIdx.z;
  const unsigned short* Ab = A + (size_t)bz * sA;
  const unsigned short* Bb = B + (size_t)bz * sB;
  int lane = threadIdx.x;
  int r16 = lane & 15;
  int ko  = (lane >> 4) * 8;
  const unsigned short* arow[4];
  const unsigned short* brow[4];
  #pragma unroll
  for (int i = 0; i < 4; i++){
    int m = blockIdx.y*64 + i*16 + r16;
    if (m > Mr - 1) m = Mr - 1;
    arow[i] = Ab + (size_t)m * K + ko;
    int n = blockIdx.x*64 + i*16 + r16;
    if (n > Nc - 1) n = Nc - 1;
    brow[i] = Bb + (size_t)n * K + ko;
  }
  floatx4 acc[4][4];
  #pragma unroll
  for (int i = 0; i < 4; i++)
    #pragma unroll
    for (int j = 0; j < 4; j++)
      acc[i][j] = (floatx4){0.f, 0.f, 0.f, 0.f};
  short8 a[4], bv[4], a2[4], b2[4];
  #pragma unroll
  for (int i = 0; i < 4; i++){
    a[i]  = *(const short8*)(arow[i]);
    bv[i] = *(const short8*)(brow[i]);
  }
  for (int k = 32; k < K; k += 32){
    #pragma unroll
    for (int i = 0; i < 4; i++){
      a2[i] = *(const short8*)(arow[i] + k);
      b2[i] = *(const short8*)(brow[i] + k);
    }
    #pragma unroll
    for (int i = 0; i < 4; i++)
      #pragma unroll
      for (int j = 0; j < 4; j++)
        acc[i][j] = __builtin_amdgcn_mfma_f32_16x16x32_bf16(a[i], bv[j], acc[i][j], 0, 0, 0);
    #pragma unroll
    for (int i = 0; i < 4; i++){ a[i] = a2[i]; bv[i] = b2[i]; }
  }
  #pragma unroll
  for (int i = 0; i < 4; i++)
    #pragma unroll
    for (int j = 0; j < 4; j++)
      acc[i][j] = __builtin_amdgcn_mfma_f32_16x16x32_bf16(a[i], bv[j], acc[i][j], 0, 0, 0);
  int cq = lane & 15, rq = (lane >> 4) * 4;
  #pragma unroll
  for (int j = 0; j < 4; j++){
    int cc = blockIdx.x*64 + j*16 + cq;
    if (cc >= Nc) continue;
    float bv_ = bias ? bias[bz*bstride + cc] : 0.f;
    #pragma unroll
    for (int i = 0; i < 4; i++){
      int rbase = blockIdx.y*64 + i*16 + rq;
      #pragma unroll
      for (int reg = 0; reg < 4; reg++){
        int rr = rbase + reg;
        if (rr < Mr){
          float v = acc[i][j][reg] + bv_;
          if (RELU) v = fmaxf(v, 0.f);
          size_t o = (size_t)bz * sC + (size_t)rr * ldc + cc;
          if (C)   C[o] = v;
          if (C16) C16[o] = f2bf(v);
        }
      }
    }
  }
}

// ---- helpers for the deep-pipelined K-split GEMM ----
__device__ __forceinline__ void ld8(const unsigned short* const arow[4],
    const unsigned short* const brow[4], int kk, short8 as[4], short8 bs[4]){
  #pragma unroll
  for (int i = 0; i < 4; i++){
    as[i] = *(const short8*)(arow[i] + kk);
    bs[i] = *(const short8*)(brow[i] + kk);
  }
}
__device__ __forceinline__ void mm16(const short8 as[4], const short8 bs[4],
                                     floatx4 acc[4][4]){
  #pragma unroll
  for (int i = 0; i < 4; i++)
    #pragma unroll
    for (int j = 0; j < 4; j++)
      acc[i][j] = __builtin_amdgcn_mfma_f32_16x16x32_bf16(as[i], bs[j], acc[i][j], 0, 0, 0);
}

// 4-wave K-split GEMM, depth-2 software pipeline (3 register buffer-pairs = 24 loads
// in flight), in-block LDS reduction, bf16 epilogue (no partials).
// Linear grid (must be %8==0) with XCD-grouped swizzle: each XCD owns nb/8 consecutive
// work items -> A/B panels stay in that XCD's L2.
// Hard-coded for K=4096 (kchunk=1024, 32 k-iters per wave).
__global__ __launch_bounds__(256) void mfma_red4_kernel(
    const unsigned short* __restrict__ A, size_t sA,
    const unsigned short* __restrict__ B, size_t sB,
    unsigned short* __restrict__ C16, size_t sC, int ldc, int Mr, int K){
  int nb = gridDim.x;
  int chunk = nb >> 3;
  int lin = blockIdx.x;
  int swz = (lin & 7) * chunk + (lin >> 3);   // XCD-grouped work id
  int bz = swz / 20;                          // 20 tiles per batch (4 x-tiles * 5 y-tiles)
  int rem = swz - bz * 20;
  int tx = rem & 3;                           // N tile (HIDC/64 = 4)
  int ty = rem >> 2;                          // M tile (ceil(300/64) = 5)
  int tid = threadIdx.x, w = tid >> 6, lane = tid & 63;
  int kchunk = K >> 2;                        // 1024
  const unsigned short* Ab = A + (size_t)bz * sA + (size_t)w * kchunk;
  const unsigned short* Bb = B + (size_t)bz * sB + (size_t)w * kchunk;
  int r16 = lane & 15;
  int ko  = (lane >> 4) * 8;
  const unsigned short* arow[4];
  const unsigned short* brow[4];
  #pragma unroll
  for (int i = 0; i < 4; i++){
    int m = ty*64 + i*16 + r16;
    if (m > Mr - 1) m = Mr - 1;
    arow[i] = Ab + (size_t)m * K + ko;
    int n = tx*64 + i*16 + r16;
    brow[i] = Bb + (size_t)n * K + ko;
  }
  floatx4 acc[4][4];
  #pragma unroll
  for (int i = 0; i < 4; i++)
    #pragma unroll
    for (int j = 0; j < 4; j++)
      acc[i][j] = (floatx4){0.f, 0.f, 0.f, 0.f};
  short8 a0[4], b0[4], a1[4], b1[4], a2[4], b2[4];
  ld8(arow, brow, 0,  a0, b0);
  ld8(arow, brow, 32, a1, b1);
  ld8(arow, brow, 64, a2, b2);
  int k = 0;
  #pragma unroll 1
  for (int g = 0; g < 9; g++){              // 27 k-iters, depth-2 pipelined
    mm16(a0, b0, acc); ld8(arow, brow, k + 96,  a0, b0);
    mm16(a1, b1, acc); ld8(arow, brow, k + 128, a1, b1);
    mm16(a2, b2, acc); ld8(arow, brow, k + 160, a2, b2);
    k += 96;
  }
  // peeled tail: k == 864; consume 864/896/928, load 960/992, consume 960/992
  mm16(a0, b0, acc); ld8(arow, brow, k + 96,  a0, b0);
  mm16(a1, b1, acc); ld8(arow, brow, k + 128, a1, b1);
  mm16(a2, b2, acc);
  mm16(a0, b0, acc);
  mm16(a1, b1, acc);
  // cross-wave reduction in LDS (4 serialized phases; each is tiny)
  __shared__ float red[64][65];
  int cq = lane & 15, rq = (lane >> 4) * 4;
  #pragma unroll 1
  for (int ph = 0; ph < 4; ph++){
    if (w == ph){
      #pragma unroll
      for (int i = 0; i < 4; i++)
        #pragma unroll
        for (int reg = 0; reg < 4; reg++){
          int r = i*16 + rq + reg;
          #pragma unroll
          for (int j = 0; j < 4; j++){
            int c = j*16 + cq;
            if (ph == 0) red[r][c] = acc[i][j][reg];
            else         red[r][c] += acc[i][j][reg];
          }
        }
    }
    __syncthreads();
  }
  // fused bf16 epilogue: 1024 ushort4 quads, 4 per thread
  unsigned short* Cb = C16 + (size_t)bz * sC;
  for (int idx = tid; idx < 1024; idx += 256){
    int r = idx >> 4, c4 = (idx & 15) * 4;
    int gr = ty*64 + r;
    if (gr < Mr){
      ushort4 u;
      u.x = f2bf(red[r][c4+0]); u.y = f2bf(red[r][c4+1]);
      u.z = f2bf(red[r][c4+2]); u.w = f2bf(red[r][c4+3]);
      *(ushort4*)&Cb[(size_t)gr * ldc + tx*64 + c4] = u;
    }
  }
}

// LayerNorm(x + bias) + ReLU over 256-wide rows for BOTH heads (z = blockIdx.y).
__global__ __launch_bounds__(256) void ln_relu2_kernel(const float* __restrict__ zin,
    const float* __restrict__ bias_b, const float* __restrict__ bias_c,
    const float* __restrict__ g_b, const float* __restrict__ be_b,
    const float* __restrict__ g_c, const float* __restrict__ be_c,
    unsigned short* __restrict__ zout){
  int z = blockIdx.y;
  const float* bias = z ? bias_c : bias_b;
  const float* g    = z ? g_c : g_b;
  const float* be   = z ? be_c : be_b;
  const float* zi = zin + (size_t)z * 1228800;
  unsigned short* zo = zout + (size_t)z * 1228800;
  int row = blockIdx.x * 4 + (threadIdx.x >> 6);
  int lane = threadIdx.x & 63;
  float4 v = *(const float4*)&zi[(size_t)row * 256 + lane * 4];
  float4 bi = *(const float4*)&bias[lane * 4];
  v.x += bi.x; v.y += bi.y; v.z += bi.z; v.w += bi.w;
  float s = v.x + v.y + v.z + v.w;
  #pragma unroll
  for (int off = 32; off >= 1; off >>= 1) s += __shfl_xor(s, off);
  float mean = s * (1.f/256.f);
  float dx = v.x - mean, dy = v.y - mean, dz = v.z - mean, dw = v.w - mean;
  float sq = dx*dx + dy*dy + dz*dz + dw*dw;
  #pragma unroll
  for (int off = 32; off >= 1; off >>= 1) sq += __shfl_xor(sq, off);
  float inv = rsqrtf(sq * (1.f/256.f) + 1e-5f);
  float4 gv = *(const float4*)&g[lane * 4];
  float4 bb = *(const float4*)&be[lane * 4];
  ushort4 u;
  u.x = f2bf(fmaxf(dx*inv*gv.x + bb.x, 0.f));
  u.y = f2bf(fmaxf(dy*inv*gv.y + bb.y, 0.f));
  u.z = f2bf(fmaxf(dz*inv*gv.z + bb.z, 0.f));
  u.w = f2bf(fmaxf(dw*inv*gv.w + bb.w, 0.f));
  *(ushort4*)&zo[(size_t)row * 256 + lane * 4] = u;
}

// final tiny projections: boxes = z2bb @ bb3^T + b; scores = sigmoid(z2ch @ ch3^T + b)
__global__ __launch_bounds__(256) void head3_kernel(
    const unsigned short* __restrict__ z2bb, const unsigned short* __restrict__ z2ch,
    const float* __restrict__ bb3_w, const float* __restrict__ bb3_b,
    const float* __restrict__ ch3_w, const float* __restrict__ ch3_b,
    float* __restrict__ boxes, float* __restrict__ scores){
  int row = blockIdx.x * 4 + (threadIdx.x >> 6);
  int lane = threadIdx.x & 63;
  float zb0 = bf1(z2bb[(size_t)row*128 + 2*lane]);
  float zb1 = bf1(z2bb[(size_t)row*128 + 2*lane + 1]);
  float zc0 = bf1(z2ch[(size_t)row*128 + 2*lane]);
  float zc1 = bf1(z2ch[(size_t)row*128 + 2*lane + 1]);
  float acc[5];
  #pragma unroll
  for (int o = 0; o < 4; o++)
    acc[o] = bb3_w[o*128 + 2*lane]*zb0 + bb3_w[o*128 + 2*lane + 1]*zb1;
  acc[4] = ch3_w[2*lane]*zc0 + ch3_w[2*lane + 1]*zc1;
  #pragma unroll
  for (int o = 0; o < 5; o++){
    float v = acc[o];
    #pragma unroll
    for (int off = 32; off >= 1; off >>= 1) v += __shfl_xor(v, off);
    acc[o] = v;
  }
  if (lane == 0){
    #pragma unroll
    for (int o = 0; o < 4; o++)
      boxes[(size_t)row*4 + o] = acc[o] + bb3_b[o];
    float sv = acc[4] + ch3_b[0];
    scores[row] = 1.f / (1.f + __expf(-sv));
  }
}

// diversity: sum_m (sum_n attn[n,m]/||attn_n||)^2  (norms holds SUM OF SQUARES)
__global__ __launch_bounds__(256) void simdiv_kernel(const unsigned short* __restrict__ attn16,
    const float* __restrict__ norms, float* __restrict__ acc){
  int b = blockIdx.y;
  int m = blockIdx.x * 256 + threadIdx.x;
  __shared__ float inv_s[NQ];
  __shared__ float red[4];
  for (int i = threadIdx.x; i < NQ; i += 256)
    inv_s[i] = 1.f / fmaxf(sqrtf(norms[(size_t)b * NQ + i]), 1e-12f);
  __syncthreads();
  const unsigned short* ab = attn16 + (size_t)b * NQ * MM;
  float S = 0.f;
  for (int n = 0; n < NQ; n++)
    S += bf1(ab[(size_t)n * MM + m]) * inv_s[n];
  float p = S * S;
  #pragma unroll
  for (int off = 32; off >= 1; off >>= 1) p += __shfl_xor(p, off);
  int w = threadIdx.x >> 6, lane = threadIdx.x & 63;
  if (lane == 0) red[w] = p;
  __syncthreads();
  if (threadIdx.x == 0) atomicAdd(acc, red[0] + red[1] + red[2] + red[3]);
}

__global__ void finalize_kernel(const float* __restrict__ acc, float* __restrict__ out_div){
  out_div[0] = (acc[0] - (float)(BB * NQ)) / (float)(NQ * (NQ - 1)) * 0.1f;
}

extern "C" void kernel_launch(void* const* d_in, const int* in_sizes, int n_in,
                              void* d_out, int out_size, void* d_ws, size_t ws_size,
                              hipStream_t stream){
  const float* x      = (const float*)d_in[0];
  const float* ss     = (const float*)d_in[1];
  const float* pos_w  = (const float*)d_in[2];
  const float* pos_b  = (const float*)d_in[3];
  const float* fp_w   = (const float*)d_in[4];
  const float* fp_b   = (const float*)d_in[5];
  const float* bn_g   = (const float*)d_in[6];
  const float* bn_b   = (const float*)d_in[7];
  const float* bn_m   = (const float*)d_in[8];
  const float* bn_v   = (const float*)d_in[9];
  const float* key_w  = (const float*)d_in[10];
  const float* key_b  = (const float*)d_in[11];
  const float* val_w  = (const float*)d_in[12];
  const float* val_b  = (const float*)d_in[13];
  const float* ctp_w  = (const float*)d_in[14];
  const float* ctp_b  = (const float*)d_in[15];
  const float* bb1_w  = (const float*)d_in[16];
  const float* bb1_b  = (const float*)d_in[17];
  const float* bbln_g = (const float*)d_in[18];
  const float* bbln_b = (const float*)d_in[19];
  const float* bb2_w  = (const float*)d_in[20];
  const float* bb2_b  = (const float*)d_in[21];
  const float* bb3_w  = (const float*)d_in[22];
  const float* bb3_b  = (const float*)d_in[23];
  const float* ch1_w  = (const float*)d_in[24];
  const float* ch1_b  = (const float*)d_in[25];
  const float* chln_g = (const float*)d_in[26];
  const float* chln_b = (const float*)d_in[27];
  const float* ch2_w  = (const float*)d_in[28];
  const float* ch2_b  = (const float*)d_in[29];
  const float* ch3_w  = (const float*)d_in[30];
  const float* ch3_b  = (const float*)d_in[31];

  float* out    = (float*)d_out;
  float* boxes  = out + OFF_BOXES;
  float* scores = out + OFF_SCORES;
  float* cls    = out + OFF_CLS;
  float* maps   = out + OFF_MAPS;
  float* divp   = out + OFF_DIV;
  float* sfout  = out + OFF_SF;

  float* ws = (float*)d_ws;
  unsigned short* comb16 = (unsigned short*)(ws + WS_COMB16);
  unsigned short* keysT  = (unsigned short*)(ws + WS_KEYS16);
  unsigned short* attn16 = (unsigned short*)(ws + WS_ATTN16);
  unsigned short* t16    = (unsigned short*)(ws + WS_T16);
  unsigned short* valw16 = (unsigned short*)(ws + WS_VALW16);
  float* sums  = ws + WS_SUMS;
  float* norms = ws + WS_NORM;
  float* dacc  = ws + WS_ACC;
  unsigned short* sf16   = (unsigned short*)(ws + HP_SF16);
  unsigned short* z2bb16 = (unsigned short*)(ws + HP_Z2BB);
  unsigned short* z2ch16 = (unsigned short*)(ws + HP_Z2CH);
  unsigned short* hw16   = (unsigned short*)(ws + HP_HW);
  float*          b2ws   = ws + WS_B2;
  unsigned short* q16    = (unsigned short*)(ws + WS_Q16);
  unsigned short* xT16   = (unsigned short*)(ws + WS_XT);
  unsigned short* combT  = (unsigned short*)(ws + WS_COMBT);
  unsigned short* fpw16  = (unsigned short*)(ws + WS_FPW16);
  unsigned short* keyw16 = (unsigned short*)(ws + WS_KEYW16);
  float*          z1pre2 = ws + WS_Z1PRE2;
  unsigned short* z1b16  = (unsigned short*)(ws + WS_Z1B16);

  // sums + norms + dacc are contiguous -> one zeroing pass (covers dacc)
  zero4_kernel<<<24, 256, 0, stream>>>((float4*)sums, 6002);
  init_kernel<<<128, 256, 0, stream>>>(ss, fp_w, key_w, q16, fpw16, keyw16);

  // x (b,256,4096) fp32 -> xT16 (b,4096,256) bf16
  transpose_x_kernel<<<dim3(64,4,16), 256, 0, stream>>>(x, xT16);
  // pos encoding into comb16 rows 128..255 AND combT cols 128..255
  pos_kernel<<<8704, 256, 0, stream>>>(pos_w, pos_b, comb16, combT);
  // comb rows 0..127 = relu(bn(fp_w @ x)) via MFMA, dual-layout store
  comb_mfma_kernel<<<dim3(64,2,16), 64, 0, stream>>>(
      fpw16, xT16, fp_b, bn_g, bn_b, bn_m, bn_v, comb16, combT);
  // keysT[m][d] = combT @ key_w^T + key_b (D-layout = m-major)
  mfma_nt_kernel<false><<<dim3(1,64,16), 64, 0, stream>>>(
      combT, (size_t)MM*CIN, keyw16, 0, key_b, 0,
      nullptr, keysT, (size_t)MM*64, 64, MM, 64, CIN);

  // fused no-P attention: swapped-operand MFMA logits, 2 passes
  attn_sums_kernel<<<dim3(32,5,16), 256, 0, stream>>>(q16, keysT, sums);
  attn_emit_kernel<<<dim3(32,5,16), 256, 0, stream>>>(q16, keysT, sums, maps, attn16, norms);

  // t16 = bf16(attn @ comb^T)  (4-wave K-split, depth-2 pipeline, XCD-grouped swizzle)
  mfma_red4_kernel<<<320, 256, 0, stream>>>(
      attn16, (size_t)NQ*MM, comb16, (size_t)HIDC*MM,
      t16, (size_t)NQ*HIDC, HIDC, NQ, MM);
  cast_heads_kernel<<<256, 256, 0, stream>>>(val_w, bb1_w, ch1_w, bb2_w, ch2_w, ctp_w,
                                             bb2_b, ch2_b, valw16, hw16, b2ws);
  // sf = t @ val_w^T + val_b  (fp32 into d_out, bf16 into sf16)
  mfma_nt_kernel<false><<<dim3(4,5,BB), 64, 0, stream>>>(
      t16, (size_t)NQ*HIDC, valw16, 0, val_b, 0,
      sfout, sf16, (size_t)NQ*HIDC, HIDC, NQ, HIDC, HIDC);

  // ---- both heads, merged (z=0 boxes, z=1 scores) ----
  mfma_nt_kernel<false><<<dim3(4,75,2), 64, 0, stream>>>(
      sf16, 0, hw16 + HW_BB1, (size_t)(HW_CH1 - HW_BB1), nullptr, 0,
      z1pre2, nullptr, (size_t)4800*256, 256, 4800, 256, 256);
  ln_relu2_kernel<<<dim3(1200,2), 256, 0, stream>>>(
      z1pre2, bb1_b, ch1_b, bbln_g, bbln_b, chln_g, chln_b, z1b16);
  mfma_nt_kernel<true><<<dim3(2,75,2), 64, 0, stream>>>(
      z1b16, (size_t)4800*256, hw16 + HW_BB2, (size_t)(HW_CH2 - HW_BB2), b2ws, 128,
      nullptr, z2bb16, (size_t)4800*128, 128, 4800, 128, 256);
  // ---- finals + cls ----
  head3_kernel<<<1200, 256, 0, stream>>>(z2bb16, z2ch16, bb3_w, bb3_b, ch3_w, ch3_b, boxes, scores);
  mfma_nt_kernel<false><<<dim3(2,75,1), 64, 0, stream>>>(
      sf16, 0, hw16 + HW_CTP, 0, ctp_b, 0, cls, nullptr, 0, 80, 4800, 80, 256);

  simdiv_kernel<<<dim3(16,16), 256, 0, stream>>>(attn16, norms, dacc);
  finalize_kernel<<<1, 1, 0, stream>>>(dacc, divp);
}

// Round 9
// 481.266 us; speedup vs baseline: 1.0770x; 1.0408x over previous
//
#include <hip/hip_runtime.h>
#include <math.h>

// ---- problem constants ----
#define BB 16
#define CIN 256
#define MM 4096      // H*W
#define HIDC 256
#define NQ 300
#define NHH 4
#define HDD 16

// ---- output offsets (floats) ----
#define OFF_BOXES  0
#define OFF_SCORES 19200
#define OFF_CLS    24000
#define OFF_MAPS   408000
#define OFF_DIV    20068800
#define OFF_SF     20068801

// ---- workspace offsets (in floats) ----
#define WS_COMB16  0            // 16*256*4096 ushort  (comb, c-major: [c][m])
#define WS_KEYS16  8388608      // keysT: (b, m=4096, d=64) bf16
#define WS_ATTN16  10485760     // 16*300*4096 ushort
#define WS_T16     21544960     // 16*300*256 ushort
#define WS_VALW16  22159360     // 65536 ushort
#define WS_SUMS    22192128     // 16*4*300 fp32 (exp-sum; atomically accumulated)
#define WS_NORM    22211328     // 4800 floats: SUM OF SQUARES per (b,n)
#define WS_ACC     22216128     // 1 float (+pad) -- contiguous after norms (one zero pass)
#define WS_P       22216192     // head scratch base

// head scratch
#define HP_SF16   (WS_P + 0)         // 4800x256 bf16  (614400 fl)
#define HP_Z2BB   (WS_P + 2457600)   // 4800x128 bf16  (307200 fl)
#define HP_Z2CH   (WS_P + 2764800)   // 4800x128 bf16  (307200 fl) -- contiguous after Z2BB
#define HP_HW     (WS_P + 3072000)   // head weights bf16 (~108.6k fl)
#define WS_B2     (WS_P + 3180544)   // 256 fp32: [bb2_b | ch2_b] contiguous
#define WS_Q16    (WS_P + 3200000)   // 320x64 bf16 q (0.25-scaled, rows 300..319 zero)
// MFMA-path buffers
#define WS_XT     25426432      // xT16: (b,4096,256) bf16 (dead after comb_mfma)
                                // -> reused as splitk partials: 128 x 76800 fp32 = 9830400 fl
                                //    (spills into dead combT region; combT dead after keys)
#define WS_COMBT  33815040      // combT: (b, m=4096, c=256) bf16 = 8388608 fl
#define WS_FPW16  42203648      // fp_w rows 0..127 bf16
#define WS_KEYW16 42220032      // key_w bf16
#define WS_Z1PRE2 42228224      // 2 x 4800x256 fp32 = 2457600 fl (boxes|scores z1 pre-LN)
#define WS_Z1B16  44685824      // 2 x 4800x256 bf16 = 1228800 fl
// total ≈ 45914624 fl ≈ 184 MB (harness provides ≥246 MB)

// ushort offsets within HP_HW:
#define HW_BB1 0
#define HW_CH1 65536
#define HW_BB2 131072
#define HW_CH2 163840
#define HW_CTP 196608

typedef short short8 __attribute__((ext_vector_type(8)));
typedef float floatx4 __attribute__((ext_vector_type(4)));

__device__ __forceinline__ unsigned short f2bf(float f){
  unsigned int u = __float_as_uint(f);
  u = (u + 0x7FFFu + ((u >> 16) & 1u)) >> 16;
  return (unsigned short)u;
}
__device__ __forceinline__ float bf1(unsigned short u){
  return __uint_as_float((unsigned int)u << 16);
}

__global__ __launch_bounds__(256) void zero4_kernel(float4* __restrict__ p, int n4){
  int i = blockIdx.x * 256 + threadIdx.x;
  if (i < n4) p[i] = make_float4(0.f, 0.f, 0.f, 0.f);
}

// fused init: q16 (0.25-scaled, 320-row pad), fp_w rows 0..127 bf16, key_w bf16
__global__ __launch_bounds__(256) void init_kernel(const float* __restrict__ ss,
    const float* __restrict__ fp_w, const float* __restrict__ key_w,
    unsigned short* __restrict__ q16, unsigned short* __restrict__ fpw16,
    unsigned short* __restrict__ keyw16){
  int i = blockIdx.x * 256 + threadIdx.x;
  int T = gridDim.x * 256;
  for (int j = i; j < 320*64; j += T)
    q16[j] = (j < NQ*64) ? f2bf(ss[j] * 0.25f) : (unsigned short)0;
  for (int j = i; j < 128*256; j += T) fpw16[j] = f2bf(fp_w[j]);
  for (int j = i; j < 64*256; j += T)  keyw16[j] = f2bf(key_w[j]);
}

// one fused cast of all bf16 weight copies + contiguous gemm2 biases
__global__ __launch_bounds__(256) void cast_heads_kernel(
    const float* __restrict__ val_w, const float* __restrict__ bb1_w,
    const float* __restrict__ ch1_w, const float* __restrict__ bb2_w,
    const float* __restrict__ ch2_w, const float* __restrict__ ctp_w,
    const float* __restrict__ bb2_b, const float* __restrict__ ch2_b,
    unsigned short* __restrict__ valw16, unsigned short* __restrict__ hw16,
    float* __restrict__ b2){
  int i = blockIdx.x * 256 + threadIdx.x;
  int T = gridDim.x * 256;
  for (int j = i; j < 65536; j += T) valw16[j] = f2bf(val_w[j]);
  for (int j = i; j < 65536; j += T) hw16[HW_BB1 + j] = f2bf(bb1_w[j]);
  for (int j = i; j < 65536; j += T) hw16[HW_CH1 + j] = f2bf(ch1_w[j]);
  for (int j = i; j < 32768; j += T) hw16[HW_BB2 + j] = f2bf(bb2_w[j]);
  for (int j = i; j < 32768; j += T) hw16[HW_CH2 + j] = f2bf(ch2_w[j]);
  for (int j = i; j < 20480; j += T) hw16[HW_CTP + j] = f2bf(ctp_w[j]);
  for (int j = i; j < 128; j += T){ b2[j] = bb2_b[j]; b2[128 + j] = ch2_b[j]; }
}

// pos encoding into BOTH layouts: comb16[c][m] rows 128..255 (ushort4 over m)
// and combT[m][128+c] (ushort4 over c). One kernel, linear id split.
__global__ __launch_bounds__(256) void pos_kernel(const float* __restrict__ pos_w,
                                                  const float* __restrict__ pos_b,
                                                  unsigned short* __restrict__ comb16,
                                                  unsigned short* __restrict__ combT){
  int lin = blockIdx.x * 256 + threadIdx.x;
  if (lin < 2097152){                     // part A: comb16, thread -> (b, c, m4)
    int m  = (lin & 1023) * 4;
    int c  = (lin >> 10) & 127;
    int b  = lin >> 17;
    int row = m >> 6, col = m & 63;
    float y  = -1.f + 2.f * (float)row / 63.f;
    float wy = pos_w[c*2], wx = pos_w[c*2+1], pb = pos_b[c];
    float base = wy * y + pb;
    ushort4 u;
    u.x = f2bf(base + wx * (-1.f + 2.f * (float)(col+0) / 63.f));
    u.y = f2bf(base + wx * (-1.f + 2.f * (float)(col+1) / 63.f));
    u.z = f2bf(base + wx * (-1.f + 2.f * (float)(col+2) / 63.f));
    u.w = f2bf(base + wx * (-1.f + 2.f * (float)(col+3) / 63.f));
    *(ushort4*)&comb16[((size_t)(b*HIDC + 128 + c))*MM + m] = u;
  } else if (lin < 2097152 + 131072){     // part B: combT, thread -> (m, c4)
    int l2 = lin - 2097152;
    int c4 = (l2 & 31) * 4;
    int m  = l2 >> 5;
    int row = m >> 6, col = m & 63;
    float y = -1.f + 2.f * (float)row / 63.f;
    float x = -1.f + 2.f * (float)col / 63.f;
    ushort4 u;
    u.x = f2bf(pos_w[(c4+0)*2] * y + pos_w[(c4+0)*2+1] * x + pos_b[c4+0]);
    u.y = f2bf(pos_w[(c4+1)*2] * y + pos_w[(c4+1)*2+1] * x + pos_b[c4+1]);
    u.z = f2bf(pos_w[(c4+2)*2] * y + pos_w[(c4+2)*2+1] * x + pos_b[c4+2]);
    u.w = f2bf(pos_w[(c4+3)*2] * y + pos_w[(c4+3)*2+1] * x + pos_b[c4+3]);
    #pragma unroll
    for (int b = 0; b < BB; b++)
      *(ushort4*)&combT[((size_t)b*MM + m)*CIN + 128 + c4] = u;
  }
}

// x (b, 256, 4096) fp32 -> xT16 (b, 4096, 256) bf16; one 64x64 tile per block.
__global__ __launch_bounds__(256) void transpose_x_kernel(
    const float* __restrict__ in, unsigned short* __restrict__ outp){
  int b = blockIdx.z;
  int m0 = blockIdx.x * 64;
  int r0 = blockIdx.y * 64;
  __shared__ unsigned short lds[64][68];
  int t = threadIdx.x;
  const float* ib = in + (size_t)b * CIN * MM;
  #pragma unroll
  for (int j = 0; j < 4; j++){
    int lin = j*256 + t;
    int rr = lin >> 4;
    int m4 = (lin & 15) * 4;
    float4 v = *(const float4*)&ib[(size_t)(r0 + rr)*MM + m0 + m4];
    lds[m4+0][rr] = f2bf(v.x);
    lds[m4+1][rr] = f2bf(v.y);
    lds[m4+2][rr] = f2bf(v.z);
    lds[m4+3][rr] = f2bf(v.w);
  }
  __syncthreads();
  unsigned short* ob = outp + (size_t)b * MM * CIN;
  #pragma unroll
  for (int j = 0; j < 4; j++){
    int lin = j*256 + t;
    int mm = lin >> 4;
    int c4 = (lin & 15) * 4;
    ushort4 u;
    u.x = lds[mm][c4+0]; u.y = lds[mm][c4+1];
    u.z = lds[mm][c4+2]; u.w = lds[mm][c4+3];
    *(ushort4*)&ob[(size_t)(m0 + mm)*CIN + r0 + c4] = u;
  }
}

// comb rows 0..127 via MFMA with DUAL-layout store:
//   comb16[c][m] (scalar, c-major) AND combT[m][c] (ushort4: reg axis = 4 consecutive c).
__global__ __launch_bounds__(64) void comb_mfma_kernel(
    const unsigned short* __restrict__ fpw16, const unsigned short* __restrict__ xT16,
    const float* __restrict__ fp_b, const float* __restrict__ bn_g,
    const float* __restrict__ bn_b, const float* __restrict__ bn_m,
    const float* __restrict__ bn_v, unsigned short* __restrict__ comb16,
    unsigned short* __restrict__ combT){
  int b = blockIdx.z;
  const unsigned short* Bb = xT16 + (size_t)b * MM * CIN;
  unsigned short* cb  = comb16 + (size_t)b * HIDC * MM;
  unsigned short* cTb = combT + (size_t)b * MM * CIN;
  int lane = threadIdx.x;
  int r16 = lane & 15;
  int ko  = (lane >> 4) * 8;
  const unsigned short* arow[4];
  const unsigned short* brow[4];
  #pragma unroll
  for (int i = 0; i < 4; i++){
    arow[i] = fpw16 + (size_t)(blockIdx.y*64 + i*16 + r16) * CIN + ko;
    brow[i] = Bb + (size_t)(blockIdx.x*64 + i*16 + r16) * CIN + ko;
  }
  floatx4 acc[4][4];
  #pragma unroll
  for (int i = 0; i < 4; i++)
    #pragma unroll
    for (int j = 0; j < 4; j++)
      acc[i][j] = (floatx4){0.f, 0.f, 0.f, 0.f};
  short8 a[4], bv[4], a2[4], b2[4];
  #pragma unroll
  for (int i = 0; i < 4; i++){
    a[i]  = *(const short8*)(arow[i]);
    bv[i] = *(const short8*)(brow[i]);
  }
  for (int k = 32; k < CIN; k += 32){
    #pragma unroll
    for (int i = 0; i < 4; i++){
      a2[i] = *(const short8*)(arow[i] + k);
      b2[i] = *(const short8*)(brow[i] + k);
    }
    #pragma unroll
    for (int i = 0; i < 4; i++)
      #pragma unroll
      for (int j = 0; j < 4; j++)
        acc[i][j] = __builtin_amdgcn_mfma_f32_16x16x32_bf16(a[i], bv[j], acc[i][j], 0, 0, 0);
    #pragma unroll
    for (int i = 0; i < 4; i++){ a[i] = a2[i]; bv[i] = b2[i]; }
  }
  #pragma unroll
  for (int i = 0; i < 4; i++)
    #pragma unroll
    for (int j = 0; j < 4; j++)
      acc[i][j] = __builtin_amdgcn_mfma_f32_16x16x32_bf16(a[i], bv[j], acc[i][j], 0, 0, 0);
  int cq = lane & 15, rq = (lane >> 4) * 4;
  #pragma unroll
  for (int i = 0; i < 4; i++){
    int rbase = blockIdx.y*64 + i*16 + rq;
    float mul[4], ofs[4];
    #pragma unroll
    for (int reg = 0; reg < 4; reg++){
      int rr = rbase + reg;
      float sc = rsqrtf(bn_v[rr] + 1e-5f);
      mul[reg] = sc * bn_g[rr];
      ofs[reg] = (fp_b[rr] - bn_m[rr]) * mul[reg] + bn_b[rr];
    }
    #pragma unroll
    for (int j = 0; j < 4; j++){
      int cc = blockIdx.x*64 + j*16 + cq;
      ushort4 u;
      float v0 = fmaxf(acc[i][j][0] * mul[0] + ofs[0], 0.f); u.x = f2bf(v0);
      float v1 = fmaxf(acc[i][j][1] * mul[1] + ofs[1], 0.f); u.y = f2bf(v1);
      float v2 = fmaxf(acc[i][j][2] * mul[2] + ofs[2], 0.f); u.z = f2bf(v2);
      float v3 = fmaxf(acc[i][j][3] * mul[3] + ofs[3], 0.f); u.w = f2bf(v3);
      cb[(size_t)(rbase+0) * MM + cc] = u.x;
      cb[(size_t)(rbase+1) * MM + cc] = u.y;
      cb[(size_t)(rbase+2) * MM + cc] = u.z;
      cb[(size_t)(rbase+3) * MM + cc] = u.w;
      *(ushort4*)&cTb[(size_t)cc * CIN + rbase] = u;
    }
  }
}

// ======== fused no-P attention: SWAPPED-operand MFMA logits, 2 passes ========
// mfma(a=k, b=q): D col = n (lane&15), D row = m ((lane>>4)*4 + reg).

// pass 1: sums[b][h][n] = sum_m exp(q.k/4). grid (32 m-chunks, 5 n-tiles, 16 b), 256 thr.
__global__ __launch_bounds__(256) void attn_sums_kernel(
    const unsigned short* __restrict__ q16, const unsigned short* __restrict__ keysT,
    float* __restrict__ sums){
  int b = blockIdx.z, ny = blockIdx.y, mx = blockIdx.x;
  int tid = threadIdx.x, w = tid >> 6, lane = tid & 63;
  int n0 = ny * 64;
  int l15 = lane & 15, qh = lane >> 4;
  int ko = (qh & 1) * 8;
  bool lo = lane < 32;
  const unsigned short* kT = keysT + (size_t)b * MM * 64;
  int mwb = mx*128 + w*32;
  __shared__ unsigned short qlds[64][72];
  __shared__ float spart[4][NHH][64];
  for (int c = tid; c < 512; c += 256){
    int r = c >> 3, d8 = (c & 7) * 8;
    *(short8*)&qlds[r][d8] = *(const short8*)&q16[(size_t)(n0 + r)*64 + d8];
  }
  __syncthreads();
  short8 zz = {0,0,0,0,0,0,0,0};
  #pragma unroll 1
  for (int h = 0; h < NHH; h++){
    short8 bq[4];
    #pragma unroll
    for (int ni = 0; ni < 4; ni++)
      bq[ni] = lo ? *(const short8*)&qlds[ni*16 + l15][h*16 + ko] : zz;
    float sacc[4] = {0.f, 0.f, 0.f, 0.f};
    #pragma unroll
    for (int ms = 0; ms < 2; ms++){
      int m = mwb + ms*16 + l15;
      short8 a = lo ? *(const short8*)&kT[(size_t)m*64 + h*16 + ko] : zz;
      #pragma unroll
      for (int ni = 0; ni < 4; ni++){
        floatx4 l = __builtin_amdgcn_mfma_f32_16x16x32_bf16(a, bq[ni],
                        (floatx4){0.f,0.f,0.f,0.f}, 0, 0, 0);
        sacc[ni] += __expf(l[0]) + __expf(l[1]) + __expf(l[2]) + __expf(l[3]);
      }
    }
    #pragma unroll
    for (int ni = 0; ni < 4; ni++){
      float v = sacc[ni];
      v += __shfl_xor(v, 16); v += __shfl_xor(v, 32);
      if (lane < 16) spart[w][h][ni*16 + lane] = v;
    }
  }
  __syncthreads();
  if (tid < NHH*64){
    int h = tid >> 6, r = tid & 63, n = n0 + r;
    if (n < NQ){
      float v = spart[0][h][r] + spart[1][h][r] + spart[2][h][r] + spart[3][h][r];
      atomicAdd(&sums[((size_t)b*NHH + h)*NQ + n], v);
    }
  }
}

// pass 2: attn[b][n][m] = sum_h exp(q.k/4) * (0.25/S_bhn); vectorized float4/ushort4 stores.
__global__ __launch_bounds__(256) void attn_emit_kernel(
    const unsigned short* __restrict__ q16, const unsigned short* __restrict__ keysT,
    const float* __restrict__ sums, float* __restrict__ maps,
    unsigned short* __restrict__ attn16, float* __restrict__ norms){
  int b = blockIdx.z, ny = blockIdx.y, mx = blockIdx.x;
  int tid = threadIdx.x, w = tid >> 6, lane = tid & 63;
  int n0 = ny * 64;
  int l15 = lane & 15, qh = lane >> 4;
  int ko = (qh & 1) * 8;
  bool lo = lane < 32;
  __shared__ unsigned short qlds[64][72];
  __shared__ float inv_s[NHH][64];
  __shared__ float npart[4][64];
  for (int c = tid; c < 512; c += 256){
    int r = c >> 3, d8 = (c & 7) * 8;
    *(short8*)&qlds[r][d8] = *(const short8*)&q16[(size_t)(n0 + r)*64 + d8];
  }
  if (tid < NHH*64){
    int h = tid >> 6, r = tid & 63, n = n0 + r;
    inv_s[h][r] = (n < NQ) ? 0.25f / sums[((size_t)b*NHH + h)*NQ + n] : 0.f;
  }
  __syncthreads();
  const unsigned short* kT = keysT + (size_t)b * MM * 64;
  int mwb = mx*128 + w*32;
  short8 zz = {0,0,0,0,0,0,0,0};
  float nacc[4] = {0.f, 0.f, 0.f, 0.f};
  float* mb = maps + (size_t)b * NQ * MM;
  unsigned short* ab = attn16 + (size_t)b * NQ * MM;
  #pragma unroll 1
  for (int ms = 0; ms < 2; ms++){
    asm volatile("" ::: "memory");   // defeat LICM: q frags re-read from LDS each iter
    int mbase = mwb + ms*16;
    int mk = mbase + l15;
    floatx4 o[4];
    #pragma unroll
    for (int ni = 0; ni < 4; ni++) o[ni] = (floatx4){0.f,0.f,0.f,0.f};
    #pragma unroll
    for (int h = 0; h < NHH; h++){
      short8 a = lo ? *(const short8*)&kT[(size_t)mk*64 + h*16 + ko] : zz;
      #pragma unroll
      for (int ni = 0; ni < 4; ni++){
        short8 bq = lo ? *(const short8*)&qlds[ni*16 + l15][h*16 + ko] : zz;
        floatx4 l = __builtin_amdgcn_mfma_f32_16x16x32_bf16(a, bq,
                        (floatx4){0.f,0.f,0.f,0.f}, 0, 0, 0);
        float iv = inv_s[h][ni*16 + l15];
        o[ni][0] += __expf(l[0]) * iv;
        o[ni][1] += __expf(l[1]) * iv;
        o[ni][2] += __expf(l[2]) * iv;
        o[ni][3] += __expf(l[3]) * iv;
      }
    }
    #pragma unroll
    for (int ni = 0; ni < 4; ni++){
      nacc[ni] += o[ni][0]*o[ni][0] + o[ni][1]*o[ni][1]
                + o[ni][2]*o[ni][2] + o[ni][3]*o[ni][3];
      int n = n0 + ni*16 + l15;
      if (n < NQ){
        size_t off = (size_t)n*MM + mbase + qh*4;
        float4 v; v.x = o[ni][0]; v.y = o[ni][1]; v.z = o[ni][2]; v.w = o[ni][3];
        *(float4*)&mb[off] = v;
        ushort4 u;
        u.x = f2bf(v.x); u.y = f2bf(v.y); u.z = f2bf(v.z); u.w = f2bf(v.w);
        *(ushort4*)&ab[off] = u;
      }
    }
  }
  #pragma unroll
  for (int ni = 0; ni < 4; ni++){
    float v = nacc[ni];
    v += __shfl_xor(v, 16); v += __shfl_xor(v, 32);
    if (lane < 16) npart[w][ni*16 + lane] = v;
  }
  __syncthreads();
  if (tid < 64){
    int n = n0 + tid;
    if (n < NQ){
      float v = npart[0][tid] + npart[1][tid] + npart[2][tid] + npart[3][tid];
      atomicAdd(&norms[(size_t)b*NQ + n], v);
    }
  }
}

// C = A @ B^T (+bias). bf16 NT MFMA, wave per 64x64 tile. Row clamp Mr, col clamp Nc.
// bias index = bz*bstride + cc (bstride=0 -> shared bias across batch/z).
template<bool RELU>
__global__ __launch_bounds__(64) void mfma_nt_kernel(
    const unsigned short* __restrict__ A, size_t sA,
    const unsigned short* __restrict__ B, size_t sB,
    const float* __restrict__ bias, int bstride,
    float* __restrict__ C, unsigned short* __restrict__ C16,
    size_t sC, int ldc, int Mr, int Nc, int K){
  int bz = blockIdx.z;
  const unsigned short* Ab = A + (size_t)bz * sA;
  const unsigned short* Bb = B + (size_t)bz * sB;
  int lane = threadIdx.x;
  int r16 = lane & 15;
  int ko  = (lane >> 4) * 8;
  const unsigned short* arow[4];
  const unsigned short* brow[4];
  #pragma unroll
  for (int i = 0; i < 4; i++){
    int m = blockIdx.y*64 + i*16 + r16;
    if (m > Mr - 1) m = Mr - 1;
    arow[i] = Ab + (size_t)m * K + ko;
    int n = blockIdx.x*64 + i*16 + r16;
    if (n > Nc - 1) n = Nc - 1;
    brow[i] = Bb + (size_t)n * K + ko;
  }
  floatx4 acc[4][4];
  #pragma unroll
  for (int i = 0; i < 4; i++)
    #pragma unroll
    for (int j = 0; j < 4; j++)
      acc[i][j] = (floatx4){0.f, 0.f, 0.f, 0.f};
  short8 a[4], bv[4], a2[4], b2[4];
  #pragma unroll
  for (int i = 0; i < 4; i++){
    a[i]  = *(const short8*)(arow[i]);
    bv[i] = *(const short8*)(brow[i]);
  }
  for (int k = 32; k < K; k += 32){
    #pragma unroll
    for (int i = 0; i < 4; i++){
      a2[i] = *(const short8*)(arow[i] + k);
      b2[i] = *(const short8*)(brow[i] + k);
    }
    #pragma unroll
    for (int i = 0; i < 4; i++)
      #pragma unroll
      for (int j = 0; j < 4; j++)
        acc[i][j] = __builtin_amdgcn_mfma_f32_16x16x32_bf16(a[i], bv[j], acc[i][j], 0, 0, 0);
    #pragma unroll
    for (int i = 0; i < 4; i++){ a[i] = a2[i]; bv[i] = b2[i]; }
  }
  #pragma unroll
  for (int i = 0; i < 4; i++)
    #pragma unroll
    for (int j = 0; j < 4; j++)
      acc[i][j] = __builtin_amdgcn_mfma_f32_16x16x32_bf16(a[i], bv[j], acc[i][j], 0, 0, 0);
  int cq = lane & 15, rq = (lane >> 4) * 4;
  #pragma unroll
  for (int j = 0; j < 4; j++){
    int cc = blockIdx.x*64 + j*16 + cq;
    if (cc >= Nc) continue;
    float bv_ = bias ? bias[bz*bstride + cc] : 0.f;
    #pragma unroll
    for (int i = 0; i < 4; i++){
      int rbase = blockIdx.y*64 + i*16 + rq;
      #pragma unroll
      for (int reg = 0; reg < 4; reg++){
        int rr = rbase + reg;
        if (rr < Mr){
          float v = acc[i][j][reg] + bv_;
          if (RELU) v = fmaxf(v, 0.f);
          size_t o = (size_t)bz * sC + (size_t)rr * ldc + cc;
          if (C)   C[o] = v;
          if (C16) C16[o] = f2bf(v);
        }
      }
    }
  }
}

// split-K variant: 1-wave blocks, plain stores into per-(b,kchunk) fp32 partials.
// blockIdx.z = bz*nks + kz; C partial slab index = blockIdx.z.
__global__ __launch_bounds__(64) void mfma_nt_splitk_kernel(
    const unsigned short* __restrict__ A, size_t sA,
    const unsigned short* __restrict__ B, size_t sB,
    float* __restrict__ C, size_t sC, int ldc, int Mr, int K, int kchunk){
  int nks = K / kchunk;
  int bz = blockIdx.z / nks;
  int kz = blockIdx.z % nks;
  const unsigned short* Ab = A + (size_t)bz * sA + (size_t)kz * kchunk;
  const unsigned short* Bb = B + (size_t)bz * sB + (size_t)kz * kchunk;
  int lane = threadIdx.x;
  int r16 = lane & 15;
  int ko  = (lane >> 4) * 8;
  const unsigned short* arow[4];
  const unsigned short* brow[4];
  #pragma unroll
  for (int i = 0; i < 4; i++){
    int m = blockIdx.y*64 + i*16 + r16;
    if (m > Mr - 1) m = Mr - 1;
    arow[i] = Ab + (size_t)m * K + ko;
    int n = blockIdx.x*64 + i*16 + r16;
    brow[i] = Bb + (size_t)n * K + ko;
  }
  floatx4 acc[4][4];
  #pragma unroll
  for (int i = 0; i < 4; i++)
    #pragma unroll
    for (int j = 0; j < 4; j++)
      acc[i][j] = (floatx4){0.f, 0.f, 0.f, 0.f};
  short8 a[4], bv[4], a2[4], b2[4];
  #pragma unroll
  for (int i = 0; i < 4; i++){
    a[i]  = *(const short8*)(arow[i]);
    bv[i] = *(const short8*)(brow[i]);
  }
  for (int k = 32; k < kchunk; k += 32){
    #pragma unroll
    for (int i = 0; i < 4; i++){
      a2[i] = *(const short8*)(arow[i] + k);
      b2[i] = *(const short8*)(brow[i] + k);
    }
    #pragma unroll
    for (int i = 0; i < 4; i++)
      #pragma unroll
      for (int j = 0; j < 4; j++)
        acc[i][j] = __builtin_amdgcn_mfma_f32_16x16x32_bf16(a[i], bv[j], acc[i][j], 0, 0, 0);
    #pragma unroll
    for (int i = 0; i < 4; i++){ a[i] = a2[i]; bv[i] = b2[i]; }
  }
  #pragma unroll
  for (int i = 0; i < 4; i++)
    #pragma unroll
    for (int j = 0; j < 4; j++)
      acc[i][j] = __builtin_amdgcn_mfma_f32_16x16x32_bf16(a[i], bv[j], acc[i][j], 0, 0, 0);
  int cq = lane & 15, rq = (lane >> 4) * 4;
  #pragma unroll
  for (int j = 0; j < 4; j++){
    int cc = blockIdx.x*64 + j*16 + cq;
    #pragma unroll
    for (int i = 0; i < 4; i++){
      int rbase = blockIdx.y*64 + i*16 + rq;
      #pragma unroll
      for (int reg = 0; reg < 4; reg++){
        int rr = rbase + reg;
        if (rr < Mr)
          C[(size_t)blockIdx.z * sC + (size_t)rr * ldc + cc] = acc[i][j][reg];
      }
    }
  }
}

// t16 = bf16( sum over 8 split-K partials )
__global__ __launch_bounds__(256) void cast_sum8_kernel(const float* __restrict__ part,
                                                        unsigned short* __restrict__ dst, int n4){
  int i = blockIdx.x * 256 + threadIdx.x;   // float4 index within (b, n, c)
  if (i < n4){
    int b = i / 19200, r = i - b * 19200;   // 19200 = NQ*HIDC/4
    const float4* p = (const float4*)part + (size_t)b * 8 * 19200 + r;
    float4 s = p[0];
    #pragma unroll
    for (int k = 1; k < 8; k++){
      float4 v = p[(size_t)k * 19200];
      s.x += v.x; s.y += v.y; s.z += v.z; s.w += v.w;
    }
    ushort4 u;
    u.x = f2bf(s.x); u.y = f2bf(s.y); u.z = f2bf(s.z); u.w = f2bf(s.w);
    ((ushort4*)dst)[i] = u;
  }
}

// LayerNorm(x + bias) + ReLU over 256-wide rows for BOTH heads (z = blockIdx.y).
__global__ __launch_bounds__(256) void ln_relu2_kernel(const float* __restrict__ zin,
    const float* __restrict__ bias_b, const float* __restrict__ bias_c,
    const float* __restrict__ g_b, const float* __restrict__ be_b,
    const float* __restrict__ g_c, const float* __restrict__ be_c,
    unsigned short* __restrict__ zout){
  int z = blockIdx.y;
  const float* bias = z ? bias_c : bias_b;
  const float* g    = z ? g_c : g_b;
  const float* be   = z ? be_c : be_b;
  const float* zi = zin + (size_t)z * 1228800;
  unsigned short* zo = zout + (size_t)z * 1228800;
  int row = blockIdx.x * 4 + (threadIdx.x >> 6);
  int lane = threadIdx.x & 63;
  float4 v = *(const float4*)&zi[(size_t)row * 256 + lane * 4];
  float4 bi = *(const float4*)&bias[lane * 4];
  v.x += bi.x; v.y += bi.y; v.z += bi.z; v.w += bi.w;
  float s = v.x + v.y + v.z + v.w;
  #pragma unroll
  for (int off = 32; off >= 1; off >>= 1) s += __shfl_xor(s, off);
  float mean = s * (1.f/256.f);
  float dx = v.x - mean, dy = v.y - mean, dz = v.z - mean, dw = v.w - mean;
  float sq = dx*dx + dy*dy + dz*dz + dw*dw;
  #pragma unroll
  for (int off = 32; off >= 1; off >>= 1) sq += __shfl_xor(sq, off);
  float inv = rsqrtf(sq * (1.f/256.f) + 1e-5f);
  float4 gv = *(const float4*)&g[lane * 4];
  float4 bb = *(const float4*)&be[lane * 4];
  ushort4 u;
  u.x = f2bf(fmaxf(dx*inv*gv.x + bb.x, 0.f));
  u.y = f2bf(fmaxf(dy*inv*gv.y + bb.y, 0.f));
  u.z = f2bf(fmaxf(dz*inv*gv.z + bb.z, 0.f));
  u.w = f2bf(fmaxf(dw*inv*gv.w + bb.w, 0.f));
  *(ushort4*)&zo[(size_t)row * 256 + lane * 4] = u;
}

// final tiny projections: boxes = z2bb @ bb3^T + b; scores = sigmoid(z2ch @ ch3^T + b)
__global__ __launch_bounds__(256) void head3_kernel(
    const unsigned short* __restrict__ z2bb, const unsigned short* __restrict__ z2ch,
    const float* __restrict__ bb3_w, const float* __restrict__ bb3_b,
    const float* __restrict__ ch3_w, const float* __restrict__ ch3_b,
    float* __restrict__ boxes, float* __restrict__ scores){
  int row = blockIdx.x * 4 + (threadIdx.x >> 6);
  int lane = threadIdx.x & 63;
  float zb0 = bf1(z2bb[(size_t)row*128 + 2*lane]);
  float zb1 = bf1(z2bb[(size_t)row*128 + 2*lane + 1]);
  float zc0 = bf1(z2ch[(size_t)row*128 + 2*lane]);
  float zc1 = bf1(z2ch[(size_t)row*128 + 2*lane + 1]);
  float acc[5];
  #pragma unroll
  for (int o = 0; o < 4; o++)
    acc[o] = bb3_w[o*128 + 2*lane]*zb0 + bb3_w[o*128 + 2*lane + 1]*zb1;
  acc[4] = ch3_w[2*lane]*zc0 + ch3_w[2*lane + 1]*zc1;
  #pragma unroll
  for (int o = 0; o < 5; o++){
    float v = acc[o];
    #pragma unroll
    for (int off = 32; off >= 1; off >>= 1) v += __shfl_xor(v, off);
    acc[o] = v;
  }
  if (lane == 0){
    #pragma unroll
    for (int o = 0; o < 4; o++)
      boxes[(size_t)row*4 + o] = acc[o] + bb3_b[o];
    float sv = acc[4] + ch3_b[0];
    scores[row] = 1.f / (1.f + __expf(-sv));
  }
}

// diversity: sum_m (sum_n attn[n,m]/||attn_n||)^2  (norms holds SUM OF SQUARES)
__global__ __launch_bounds__(256) void simdiv_kernel(const unsigned short* __restrict__ attn16,
    const float* __restrict__ norms, float* __restrict__ acc){
  int b = blockIdx.y;
  int m = blockIdx.x * 256 + threadIdx.x;
  __shared__ float inv_s[NQ];
  __shared__ float red[4];
  for (int i = threadIdx.x; i < NQ; i += 256)
    inv_s[i] = 1.f / fmaxf(sqrtf(norms[(size_t)b * NQ + i]), 1e-12f);
  __syncthreads();
  const unsigned short* ab = attn16 + (size_t)b * NQ * MM;
  float S = 0.f;
  for (int n = 0; n < NQ; n++)
    S += bf1(ab[(size_t)n * MM + m]) * inv_s[n];
  float p = S * S;
  #pragma unroll
  for (int off = 32; off >= 1; off >>= 1) p += __shfl_xor(p, off);
  int w = threadIdx.x >> 6, lane = threadIdx.x & 63;
  if (lane == 0) red[w] = p;
  __syncthreads();
  if (threadIdx.x == 0) atomicAdd(acc, red[0] + red[1] + red[2] + red[3]);
}

__global__ void finalize_kernel(const float* __restrict__ acc, float* __restrict__ out_div){
  out_div[0] = (acc[0] - (float)(BB * NQ)) / (float)(NQ * (NQ - 1)) * 0.1f;
}

extern "C" void kernel_launch(void* const* d_in, const int* in_sizes, int n_in,
                              void* d_out, int out_size, void* d_ws, size_t ws_size,
                              hipStream_t stream){
  const float* x      = (const float*)d_in[0];
  const float* ss     = (const float*)d_in[1];
  const float* pos_w  = (const float*)d_in[2];
  const float* pos_b  = (const float*)d_in[3];
  const float* fp_w   = (const float*)d_in[4];
  const float* fp_b   = (const float*)d_in[5];
  const float* bn_g   = (const float*)d_in[6];
  const float* bn_b   = (const float*)d_in[7];
  const float* bn_m   = (const float*)d_in[8];
  const float* bn_v   = (const float*)d_in[9];
  const float* key_w  = (const float*)d_in[10];
  const float* key_b  = (const float*)d_in[11];
  const float* val_w  = (const float*)d_in[12];
  const float* val_b  = (const float*)d_in[13];
  const float* ctp_w  = (const float*)d_in[14];
  const float* ctp_b  = (const float*)d_in[15];
  const float* bb1_w  = (const float*)d_in[16];
  const float* bb1_b  = (const float*)d_in[17];
  const float* bbln_g = (const float*)d_in[18];
  const float* bbln_b = (const float*)d_in[19];
  const float* bb2_w  = (const float*)d_in[20];
  const float* bb2_b  = (const float*)d_in[21];
  const float* bb3_w  = (const float*)d_in[22];
  const float* bb3_b  = (const float*)d_in[23];
  const float* ch1_w  = (const float*)d_in[24];
  const float* ch1_b  = (const float*)d_in[25];
  const float* chln_g = (const float*)d_in[26];
  const float* chln_b = (const float*)d_in[27];
  const float* ch2_w  = (const float*)d_in[28];
  const float* ch2_b  = (const float*)d_in[29];
  const float* ch3_w  = (const float*)d_in[30];
  const float* ch3_b  = (const float*)d_in[31];

  float* out    = (float*)d_out;
  float* boxes  = out + OFF_BOXES;
  float* scores = out + OFF_SCORES;
  float* cls    = out + OFF_CLS;
  float* maps   = out + OFF_MAPS;
  float* divp   = out + OFF_DIV;
  float* sfout  = out + OFF_SF;

  float* ws = (float*)d_ws;
  unsigned short* comb16 = (unsigned short*)(ws + WS_COMB16);
  unsigned short* keysT  = (unsigned short*)(ws + WS_KEYS16);
  unsigned short* attn16 = (unsigned short*)(ws + WS_ATTN16);
  unsigned short* t16    = (unsigned short*)(ws + WS_T16);
  unsigned short* valw16 = (unsigned short*)(ws + WS_VALW16);
  float* sums  = ws + WS_SUMS;
  float* norms = ws + WS_NORM;
  float* dacc  = ws + WS_ACC;
  unsigned short* sf16   = (unsigned short*)(ws + HP_SF16);
  unsigned short* z2bb16 = (unsigned short*)(ws + HP_Z2BB);
  unsigned short* z2ch16 = (unsigned short*)(ws + HP_Z2CH);
  unsigned short* hw16   = (unsigned short*)(ws + HP_HW);
  float*          b2ws   = ws + WS_B2;
  unsigned short* q16    = (unsigned short*)(ws + WS_Q16);
  unsigned short* xT16   = (unsigned short*)(ws + WS_XT);
  float*          tpart  = ws + WS_XT;        // aliases xT16+combT (both dead by then)
  unsigned short* combT  = (unsigned short*)(ws + WS_COMBT);
  unsigned short* fpw16  = (unsigned short*)(ws + WS_FPW16);
  unsigned short* keyw16 = (unsigned short*)(ws + WS_KEYW16);
  float*          z1pre2 = ws + WS_Z1PRE2;
  unsigned short* z1b16  = (unsigned short*)(ws + WS_Z1B16);

  // sums + norms + dacc are contiguous -> one zeroing pass (covers dacc)
  zero4_kernel<<<24, 256, 0, stream>>>((float4*)sums, 6002);
  init_kernel<<<128, 256, 0, stream>>>(ss, fp_w, key_w, q16, fpw16, keyw16);

  // x (b,256,4096) fp32 -> xT16 (b,4096,256) bf16
  transpose_x_kernel<<<dim3(64,4,16), 256, 0, stream>>>(x, xT16);
  // pos encoding into comb16 rows 128..255 AND combT cols 128..255
  pos_kernel<<<8704, 256, 0, stream>>>(pos_w, pos_b, comb16, combT);
  // comb rows 0..127 = relu(bn(fp_w @ x)) via MFMA, dual-layout store
  comb_mfma_kernel<<<dim3(64,2,16), 64, 0, stream>>>(
      fpw16, xT16, fp_b, bn_g, bn_b, bn_m, bn_v, comb16, combT);
  // keysT[m][d] = combT @ key_w^T + key_b (D-layout = m-major)
  mfma_nt_kernel<false><<<dim3(1,64,16), 64, 0, stream>>>(
      combT, (size_t)MM*CIN, keyw16, 0, key_b, 0,
      nullptr, keysT, (size_t)MM*64, 64, MM, 64, CIN);

  // fused no-P attention: swapped-operand MFMA logits, 2 passes
  attn_sums_kernel<<<dim3(32,5,16), 256, 0, stream>>>(q16, keysT, sums);
  attn_emit_kernel<<<dim3(32,5,16), 256, 0, stream>>>(q16, keysT, sums, maps, attn16, norms);

  // tpart[b*8+kz] = attn @ comb^T  (8-way split-K, 1-wave blocks, plain stores;
  // xT16+combT region is dead -> partial slab)
  mfma_nt_splitk_kernel<<<dim3(4,5,BB*8), 64, 0, stream>>>(
      attn16, (size_t)NQ*MM, comb16, (size_t)HIDC*MM,
      tpart, (size_t)NQ*HIDC, HIDC, NQ, MM, MM/8);
  cast_sum8_kernel<<<1200, 256, 0, stream>>>(tpart, t16, 307200);
  cast_heads_kernel<<<256, 256, 0, stream>>>(val_w, bb1_w, ch1_w, bb2_w, ch2_w, ctp_w,
                                             bb2_b, ch2_b, valw16, hw16, b2ws);
  // sf = t @ val_w^T + val_b  (fp32 into d_out, bf16 into sf16)
  mfma_nt_kernel<false><<<dim3(4,5,BB), 64, 0, stream>>>(
      t16, (size_t)NQ*HIDC, valw16, 0, val_b, 0,
      sfout, sf16, (size_t)NQ*HIDC, HIDC, NQ, HIDC, HIDC);

  // ---- both heads, merged (z=0 boxes, z=1 scores) ----
  mfma_nt_kernel<false><<<dim3(4,75,2), 64, 0, stream>>>(
      sf16, 0, hw16 + HW_BB1, (size_t)(HW_CH1 - HW_BB1), nullptr, 0,
      z1pre2, nullptr, (size_t)4800*256, 256, 4800, 256, 256);
  ln_relu2_kernel<<<dim3(1200,2), 256, 0, stream>>>(
      z1pre2, bb1_b, ch1_b, bbln_g, bbln_b, chln_g, chln_b, z1b16);
  mfma_nt_kernel<true><<<dim3(2,75,2), 64, 0, stream>>>(
      z1b16, (size_t)4800*256, hw16 + HW_BB2, (size_t)(HW_CH2 - HW_BB2), b2ws, 128,
      nullptr, z2bb16, (size_t)4800*128, 128, 4800, 128, 256);
  // ---- finals + cls ----
  head3_kernel<<<1200, 256, 0, stream>>>(z2bb16, z2ch16, bb3_w, bb3_b, ch3_w, ch3_b, boxes, scores);
  mfma_nt_kernel<false><<<dim3(2,75,1), 64, 0, stream>>>(
      sf16, 0, hw16 + HW_CTP, 0, ctp_b, 0, cls, nullptr, 0, 80, 4800, 80, 256);

  simdiv_kernel<<<dim3(16,16), 256, 0, stream>>>(attn16, norms, dacc);
  finalize_kernel<<<1, 1, 0, stream>>>(dacc, divp);
}

// Round 10
// 469.430 us; speedup vs baseline: 1.1042x; 1.0252x over previous
//
#include <hip/hip_runtime.h>
#include <math.h>

// ---- problem constants ----
#define BB 16
#define CIN 256
#define MM 4096      // H*W
#define HIDC 256
#define NQ 300
#define NHH 4
#define HDD 16

// ---- output offsets (floats) ----
#define OFF_BOXES  0
#define OFF_SCORES 19200
#define OFF_CLS    24000
#define OFF_MAPS   408000
#define OFF_DIV    20068800
#define OFF_SF     20068801

// ---- workspace offsets (in floats) ----
#define WS_COMB16  0            // 16*256*4096 ushort  (comb, c-major: [c][m])
#define WS_KEYS16  8388608      // keysT: (b, m=4096, d=64) bf16
#define WS_ATTN16  10485760     // 16*300*4096 ushort
#define WS_T16     21544960     // 16*300*256 ushort
#define WS_VALW16  22159360     // 65536 ushort
#define WS_SUMS    22192128     // 16*4*300 fp32 (exp-sum; atomically accumulated)
#define WS_NORM    22211328     // 4800 floats: SUM OF SQUARES per (b,n)
#define WS_ACC     22216128     // 1 float (+pad) -- contiguous after norms (one zero pass)
#define WS_P       22216192     // head scratch base

// head scratch
#define HP_SF16   (WS_P + 0)         // 4800x256 bf16  (614400 fl)
#define HP_Z2BB   (WS_P + 2457600)   // 4800x128 bf16  (307200 fl)
#define HP_Z2CH   (WS_P + 2764800)   // 4800x128 bf16  (307200 fl) -- contiguous after Z2BB
#define HP_HW     (WS_P + 3072000)   // head weights bf16 (~108.6k fl)
#define WS_B2     (WS_P + 3180544)   // 256 fp32: [bb2_b | ch2_b] contiguous
#define WS_Q16    (WS_P + 3200000)   // 320x64 bf16 q (0.25-scaled, rows 300..319 zero)
// MFMA-path buffers
#define WS_XT     25426432      // xT16: (b,4096,256) bf16 (dead after comb_mfma)
                                // -> reused as splitk partials: 128 x 76800 fp32 = 9830400 fl
#define WS_COMBT  33815040      // combT: (b, m=4096, c=256) bf16 = 8388608 fl
#define WS_FPW16  42203648      // fp_w rows 0..127 bf16
#define WS_KEYW16 42220032      // key_w bf16
#define WS_Z1PRE2 42228224      // 2 x 4800x256 fp32 = 2457600 fl (boxes|scores z1 pre-LN)
#define WS_Z1B16  44685824      // 2 x 4800x256 bf16 = 1228800 fl
// total ≈ 45914624 fl ≈ 184 MB (harness provides ≥246 MB)

// ushort offsets within HP_HW:
#define HW_BB1 0
#define HW_CH1 65536
#define HW_BB2 131072
#define HW_CH2 163840
#define HW_CTP 196608

typedef short short8 __attribute__((ext_vector_type(8)));
typedef float floatx4 __attribute__((ext_vector_type(4)));

__device__ __forceinline__ unsigned short f2bf(float f){
  unsigned int u = __float_as_uint(f);
  u = (u + 0x7FFFu + ((u >> 16) & 1u)) >> 16;
  return (unsigned short)u;
}
__device__ __forceinline__ float bf1(unsigned short u){
  return __uint_as_float((unsigned int)u << 16);
}

__global__ __launch_bounds__(256) void zero4_kernel(float4* __restrict__ p, int n4){
  int i = blockIdx.x * 256 + threadIdx.x;
  if (i < n4) p[i] = make_float4(0.f, 0.f, 0.f, 0.f);
}

// fused init: q16 (0.25-scaled, 320-row pad), fp_w rows 0..127 bf16, key_w bf16
__global__ __launch_bounds__(256) void init_kernel(const float* __restrict__ ss,
    const float* __restrict__ fp_w, const float* __restrict__ key_w,
    unsigned short* __restrict__ q16, unsigned short* __restrict__ fpw16,
    unsigned short* __restrict__ keyw16){
  int i = blockIdx.x * 256 + threadIdx.x;
  int T = gridDim.x * 256;
  for (int j = i; j < 320*64; j += T)
    q16[j] = (j < NQ*64) ? f2bf(ss[j] * 0.25f) : (unsigned short)0;
  for (int j = i; j < 128*256; j += T) fpw16[j] = f2bf(fp_w[j]);
  for (int j = i; j < 64*256; j += T)  keyw16[j] = f2bf(key_w[j]);
}

// one fused cast of all bf16 weight copies + contiguous gemm2 biases
__global__ __launch_bounds__(256) void cast_heads_kernel(
    const float* __restrict__ val_w, const float* __restrict__ bb1_w,
    const float* __restrict__ ch1_w, const float* __restrict__ bb2_w,
    const float* __restrict__ ch2_w, const float* __restrict__ ctp_w,
    const float* __restrict__ bb2_b, const float* __restrict__ ch2_b,
    unsigned short* __restrict__ valw16, unsigned short* __restrict__ hw16,
    float* __restrict__ b2){
  int i = blockIdx.x * 256 + threadIdx.x;
  int T = gridDim.x * 256;
  for (int j = i; j < 65536; j += T) valw16[j] = f2bf(val_w[j]);
  for (int j = i; j < 65536; j += T) hw16[HW_BB1 + j] = f2bf(bb1_w[j]);
  for (int j = i; j < 65536; j += T) hw16[HW_CH1 + j] = f2bf(ch1_w[j]);
  for (int j = i; j < 32768; j += T) hw16[HW_BB2 + j] = f2bf(bb2_w[j]);
  for (int j = i; j < 32768; j += T) hw16[HW_CH2 + j] = f2bf(ch2_w[j]);
  for (int j = i; j < 20480; j += T) hw16[HW_CTP + j] = f2bf(ctp_w[j]);
  for (int j = i; j < 128; j += T){ b2[j] = bb2_b[j]; b2[128 + j] = ch2_b[j]; }
}

// pos encoding into BOTH layouts: comb16[c][m] rows 128..255 (ushort4 over m)
// and combT[m][128+c] (ushort4 over c). One kernel, linear id split.
__global__ __launch_bounds__(256) void pos_kernel(const float* __restrict__ pos_w,
                                                  const float* __restrict__ pos_b,
                                                  unsigned short* __restrict__ comb16,
                                                  unsigned short* __restrict__ combT){
  int lin = blockIdx.x * 256 + threadIdx.x;
  if (lin < 2097152){                     // part A: comb16, thread -> (b, c, m4)
    int m  = (lin & 1023) * 4;
    int c  = (lin >> 10) & 127;
    int b  = lin >> 17;
    int row = m >> 6, col = m & 63;
    float y  = -1.f + 2.f * (float)row / 63.f;
    float wy = pos_w[c*2], wx = pos_w[c*2+1], pb = pos_b[c];
    float base = wy * y + pb;
    ushort4 u;
    u.x = f2bf(base + wx * (-1.f + 2.f * (float)(col+0) / 63.f));
    u.y = f2bf(base + wx * (-1.f + 2.f * (float)(col+1) / 63.f));
    u.z = f2bf(base + wx * (-1.f + 2.f * (float)(col+2) / 63.f));
    u.w = f2bf(base + wx * (-1.f + 2.f * (float)(col+3) / 63.f));
    *(ushort4*)&comb16[((size_t)(b*HIDC + 128 + c))*MM + m] = u;
  } else if (lin < 2097152 + 131072){     // part B: combT, thread -> (m, c4)
    int l2 = lin - 2097152;
    int c4 = (l2 & 31) * 4;
    int m  = l2 >> 5;
    int row = m >> 6, col = m & 63;
    float y = -1.f + 2.f * (float)row / 63.f;
    float x = -1.f + 2.f * (float)col / 63.f;
    ushort4 u;
    u.x = f2bf(pos_w[(c4+0)*2] * y + pos_w[(c4+0)*2+1] * x + pos_b[c4+0]);
    u.y = f2bf(pos_w[(c4+1)*2] * y + pos_w[(c4+1)*2+1] * x + pos_b[c4+1]);
    u.z = f2bf(pos_w[(c4+2)*2] * y + pos_w[(c4+2)*2+1] * x + pos_b[c4+2]);
    u.w = f2bf(pos_w[(c4+3)*2] * y + pos_w[(c4+3)*2+1] * x + pos_b[c4+3]);
    #pragma unroll
    for (int b = 0; b < BB; b++)
      *(ushort4*)&combT[((size_t)b*MM + m)*CIN + 128 + c4] = u;
  }
}

// x (b, 256, 4096) fp32 -> xT16 (b, 4096, 256) bf16; one 64x64 tile per block.
__global__ __launch_bounds__(256) void transpose_x_kernel(
    const float* __restrict__ in, unsigned short* __restrict__ outp){
  int b = blockIdx.z;
  int m0 = blockIdx.x * 64;
  int r0 = blockIdx.y * 64;
  __shared__ unsigned short lds[64][68];
  int t = threadIdx.x;
  const float* ib = in + (size_t)b * CIN * MM;
  #pragma unroll
  for (int j = 0; j < 4; j++){
    int lin = j*256 + t;
    int rr = lin >> 4;
    int m4 = (lin & 15) * 4;
    float4 v = *(const float4*)&ib[(size_t)(r0 + rr)*MM + m0 + m4];
    lds[m4+0][rr] = f2bf(v.x);
    lds[m4+1][rr] = f2bf(v.y);
    lds[m4+2][rr] = f2bf(v.z);
    lds[m4+3][rr] = f2bf(v.w);
  }
  __syncthreads();
  unsigned short* ob = outp + (size_t)b * MM * CIN;
  #pragma unroll
  for (int j = 0; j < 4; j++){
    int lin = j*256 + t;
    int mm = lin >> 4;
    int c4 = (lin & 15) * 4;
    ushort4 u;
    u.x = lds[mm][c4+0]; u.y = lds[mm][c4+1];
    u.z = lds[mm][c4+2]; u.w = lds[mm][c4+3];
    *(ushort4*)&ob[(size_t)(m0 + mm)*CIN + r0 + c4] = u;
  }
}

// comb rows 0..127 via MFMA with DUAL-layout store:
//   comb16[c][m] (scalar, c-major) AND combT[m][c] (ushort4: reg axis = 4 consecutive c).
__global__ __launch_bounds__(64) void comb_mfma_kernel(
    const unsigned short* __restrict__ fpw16, const unsigned short* __restrict__ xT16,
    const float* __restrict__ fp_b, const float* __restrict__ bn_g,
    const float* __restrict__ bn_b, const float* __restrict__ bn_m,
    const float* __restrict__ bn_v, unsigned short* __restrict__ comb16,
    unsigned short* __restrict__ combT){
  int b = blockIdx.z;
  const unsigned short* Bb = xT16 + (size_t)b * MM * CIN;
  unsigned short* cb  = comb16 + (size_t)b * HIDC * MM;
  unsigned short* cTb = combT + (size_t)b * MM * CIN;
  int lane = threadIdx.x;
  int r16 = lane & 15;
  int ko  = (lane >> 4) * 8;
  const unsigned short* arow[4];
  const unsigned short* brow[4];
  #pragma unroll
  for (int i = 0; i < 4; i++){
    arow[i] = fpw16 + (size_t)(blockIdx.y*64 + i*16 + r16) * CIN + ko;
    brow[i] = Bb + (size_t)(blockIdx.x*64 + i*16 + r16) * CIN + ko;
  }
  floatx4 acc[4][4];
  #pragma unroll
  for (int i = 0; i < 4; i++)
    #pragma unroll
    for (int j = 0; j < 4; j++)
      acc[i][j] = (floatx4){0.f, 0.f, 0.f, 0.f};
  short8 a[4], bv[4], a2[4], b2[4];
  #pragma unroll
  for (int i = 0; i < 4; i++){
    a[i]  = *(const short8*)(arow[i]);
    bv[i] = *(const short8*)(brow[i]);
  }
  for (int k = 32; k < CIN; k += 32){
    #pragma unroll
    for (int i = 0; i < 4; i++){
      a2[i] = *(const short8*)(arow[i] + k);
      b2[i] = *(const short8*)(brow[i] + k);
    }
    #pragma unroll
    for (int i = 0; i < 4; i++)
      #pragma unroll
      for (int j = 0; j < 4; j++)
        acc[i][j] = __builtin_amdgcn_mfma_f32_16x16x32_bf16(a[i], bv[j], acc[i][j], 0, 0, 0);
    #pragma unroll
    for (int i = 0; i < 4; i++){ a[i] = a2[i]; bv[i] = b2[i]; }
  }
  #pragma unroll
  for (int i = 0; i < 4; i++)
    #pragma unroll
    for (int j = 0; j < 4; j++)
      acc[i][j] = __builtin_amdgcn_mfma_f32_16x16x32_bf16(a[i], bv[j], acc[i][j], 0, 0, 0);
  int cq = lane & 15, rq = (lane >> 4) * 4;
  #pragma unroll
  for (int i = 0; i < 4; i++){
    int rbase = blockIdx.y*64 + i*16 + rq;
    float mul[4], ofs[4];
    #pragma unroll
    for (int reg = 0; reg < 4; reg++){
      int rr = rbase + reg;
      float sc = rsqrtf(bn_v[rr] + 1e-5f);
      mul[reg] = sc * bn_g[rr];
      ofs[reg] = (fp_b[rr] - bn_m[rr]) * mul[reg] + bn_b[rr];
    }
    #pragma unroll
    for (int j = 0; j < 4; j++){
      int cc = blockIdx.x*64 + j*16 + cq;
      ushort4 u;
      float v0 = fmaxf(acc[i][j][0] * mul[0] + ofs[0], 0.f); u.x = f2bf(v0);
      float v1 = fmaxf(acc[i][j][1] * mul[1] + ofs[1], 0.f); u.y = f2bf(v1);
      float v2 = fmaxf(acc[i][j][2] * mul[2] + ofs[2], 0.f); u.z = f2bf(v2);
      float v3 = fmaxf(acc[i][j][3] * mul[3] + ofs[3], 0.f); u.w = f2bf(v3);
      cb[(size_t)(rbase+0) * MM + cc] = u.x;
      cb[(size_t)(rbase+1) * MM + cc] = u.y;
      cb[(size_t)(rbase+2) * MM + cc] = u.z;
      cb[(size_t)(rbase+3) * MM + cc] = u.w;
      *(ushort4*)&cTb[(size_t)cc * CIN + rbase] = u;
    }
  }
}

// ======== fused no-P attention: SWAPPED-operand MFMA logits, 2 passes ========
// mfma(a=k, b=q): D col = n (lane&15), D row = m ((lane>>4)*4 + reg).

// pass 1: sums[b][h][n] = sum_m exp(q.k/4). grid (32 m-chunks, 5 n-tiles, 16 b), 256 thr.
__global__ __launch_bounds__(256) void attn_sums_kernel(
    const unsigned short* __restrict__ q16, const unsigned short* __restrict__ keysT,
    float* __restrict__ sums){
  int b = blockIdx.z, ny = blockIdx.y, mx = blockIdx.x;
  int tid = threadIdx.x, w = tid >> 6, lane = tid & 63;
  int n0 = ny * 64;
  int l15 = lane & 15, qh = lane >> 4;
  int ko = (qh & 1) * 8;
  bool lo = lane < 32;
  const unsigned short* kT = keysT + (size_t)b * MM * 64;
  int mwb = mx*128 + w*32;
  __shared__ unsigned short qlds[64][72];
  __shared__ float spart[4][NHH][64];
  for (int c = tid; c < 512; c += 256){
    int r = c >> 3, d8 = (c & 7) * 8;
    *(short8*)&qlds[r][d8] = *(const short8*)&q16[(size_t)(n0 + r)*64 + d8];
  }
  __syncthreads();
  short8 zz = {0,0,0,0,0,0,0,0};
  #pragma unroll 1
  for (int h = 0; h < NHH; h++){
    short8 bq[4];
    #pragma unroll
    for (int ni = 0; ni < 4; ni++)
      bq[ni] = lo ? *(const short8*)&qlds[ni*16 + l15][h*16 + ko] : zz;
    float sacc[4] = {0.f, 0.f, 0.f, 0.f};
    #pragma unroll
    for (int ms = 0; ms < 2; ms++){
      int m = mwb + ms*16 + l15;
      short8 a = lo ? *(const short8*)&kT[(size_t)m*64 + h*16 + ko] : zz;
      #pragma unroll
      for (int ni = 0; ni < 4; ni++){
        floatx4 l = __builtin_amdgcn_mfma_f32_16x16x32_bf16(a, bq[ni],
                        (floatx4){0.f,0.f,0.f,0.f}, 0, 0, 0);
        sacc[ni] += __expf(l[0]) + __expf(l[1]) + __expf(l[2]) + __expf(l[3]);
      }
    }
    #pragma unroll
    for (int ni = 0; ni < 4; ni++){
      float v = sacc[ni];
      v += __shfl_xor(v, 16); v += __shfl_xor(v, 32);
      if (lane < 16) spart[w][h][ni*16 + lane] = v;
    }
  }
  __syncthreads();
  if (tid < NHH*64){
    int h = tid >> 6, r = tid & 63, n = n0 + r;
    if (n < NQ){
      float v = spart[0][h][r] + spart[1][h][r] + spart[2][h][r] + spart[3][h][r];
      atomicAdd(&sums[((size_t)b*NHH + h)*NQ + n], v);
    }
  }
}

// pass 2: attn[b][n][m] = sum_h exp(q.k/4) * (0.25/S_bhn); vectorized float4/ushort4 stores.
__global__ __launch_bounds__(256) void attn_emit_kernel(
    const unsigned short* __restrict__ q16, const unsigned short* __restrict__ keysT,
    const float* __restrict__ sums, float* __restrict__ maps,
    unsigned short* __restrict__ attn16, float* __restrict__ norms){
  int b = blockIdx.z, ny = blockIdx.y, mx = blockIdx.x;
  int tid = threadIdx.x, w = tid >> 6, lane = tid & 63;
  int n0 = ny * 64;
  int l15 = lane & 15, qh = lane >> 4;
  int ko = (qh & 1) * 8;
  bool lo = lane < 32;
  __shared__ unsigned short qlds[64][72];
  __shared__ float inv_s[NHH][64];
  __shared__ float npart[4][64];
  for (int c = tid; c < 512; c += 256){
    int r = c >> 3, d8 = (c & 7) * 8;
    *(short8*)&qlds[r][d8] = *(const short8*)&q16[(size_t)(n0 + r)*64 + d8];
  }
  if (tid < NHH*64){
    int h = tid >> 6, r = tid & 63, n = n0 + r;
    inv_s[h][r] = (n < NQ) ? 0.25f / sums[((size_t)b*NHH + h)*NQ + n] : 0.f;
  }
  __syncthreads();
  const unsigned short* kT = keysT + (size_t)b * MM * 64;
  int mwb = mx*128 + w*32;
  short8 zz = {0,0,0,0,0,0,0,0};
  float nacc[4] = {0.f, 0.f, 0.f, 0.f};
  float* mb = maps + (size_t)b * NQ * MM;
  unsigned short* ab = attn16 + (size_t)b * NQ * MM;
  #pragma unroll 1
  for (int ms = 0; ms < 2; ms++){
    asm volatile("" ::: "memory");   // defeat LICM: q frags re-read from LDS each iter
    int mbase = mwb + ms*16;
    int mk = mbase + l15;
    floatx4 o[4];
    #pragma unroll
    for (int ni = 0; ni < 4; ni++) o[ni] = (floatx4){0.f,0.f,0.f,0.f};
    #pragma unroll
    for (int h = 0; h < NHH; h++){
      short8 a = lo ? *(const short8*)&kT[(size_t)mk*64 + h*16 + ko] : zz;
      #pragma unroll
      for (int ni = 0; ni < 4; ni++){
        short8 bq = lo ? *(const short8*)&qlds[ni*16 + l15][h*16 + ko] : zz;
        floatx4 l = __builtin_amdgcn_mfma_f32_16x16x32_bf16(a, bq,
                        (floatx4){0.f,0.f,0.f,0.f}, 0, 0, 0);
        float iv = inv_s[h][ni*16 + l15];
        o[ni][0] += __expf(l[0]) * iv;
        o[ni][1] += __expf(l[1]) * iv;
        o[ni][2] += __expf(l[2]) * iv;
        o[ni][3] += __expf(l[3]) * iv;
      }
    }
    #pragma unroll
    for (int ni = 0; ni < 4; ni++){
      nacc[ni] += o[ni][0]*o[ni][0] + o[ni][1]*o[ni][1]
                + o[ni][2]*o[ni][2] + o[ni][3]*o[ni][3];
      int n = n0 + ni*16 + l15;
      if (n < NQ){
        size_t off = (size_t)n*MM + mbase + qh*4;
        float4 v; v.x = o[ni][0]; v.y = o[ni][1]; v.z = o[ni][2]; v.w = o[ni][3];
        *(float4*)&mb[off] = v;
        ushort4 u;
        u.x = f2bf(v.x); u.y = f2bf(v.y); u.z = f2bf(v.z); u.w = f2bf(v.w);
        *(ushort4*)&ab[off] = u;
      }
    }
  }
  #pragma unroll
  for (int ni = 0; ni < 4; ni++){
    float v = nacc[ni];
    v += __shfl_xor(v, 16); v += __shfl_xor(v, 32);
    if (lane < 16) npart[w][ni*16 + lane] = v;
  }
  __syncthreads();
  if (tid < 64){
    int n = n0 + tid;
    if (n < NQ){
      float v = npart[0][tid] + npart[1][tid] + npart[2][tid] + npart[3][tid];
      atomicAdd(&norms[(size_t)b*NQ + n], v);
    }
  }
}

// C = A @ B^T (+bias). bf16 NT MFMA, wave per 64x64 tile. Row clamp Mr, col clamp Nc.
// bias index = bz*bstride + cc (bstride=0 -> shared bias across batch/z).
template<bool RELU>
__global__ __launch_bounds__(64) void mfma_nt_kernel(
    const unsigned short* __restrict__ A, size_t sA,
    const unsigned short* __restrict__ B, size_t sB,
    const float* __restrict__ bias, int bstride,
    float* __restrict__ C, unsigned short* __restrict__ C16,
    size_t sC, int ldc, int Mr, int Nc, int K){
  int bz = blockIdx.z;
  const unsigned short* Ab = A + (size_t)bz * sA;
  const unsigned short* Bb = B + (size_t)bz * sB;
  int lane = threadIdx.x;
  int r16 = lane & 15;
  int ko  = (lane >> 4) * 8;
  const unsigned short* arow[4];
  const unsigned short* brow[4];
  #pragma unroll
  for (int i = 0; i < 4; i++){
    int m = blockIdx.y*64 + i*16 + r16;
    if (m > Mr - 1) m = Mr - 1;
    arow[i] = Ab + (size_t)m * K + ko;
    int n = blockIdx.x*64 + i*16 + r16;
    if (n > Nc - 1) n = Nc - 1;
    brow[i] = Bb + (size_t)n * K + ko;
  }
  floatx4 acc[4][4];
  #pragma unroll
  for (int i = 0; i < 4; i++)
    #pragma unroll
    for (int j = 0; j < 4; j++)
      acc[i][j] = (floatx4){0.f, 0.f, 0.f, 0.f};
  short8 a[4], bv[4], a2[4], b2[4];
  #pragma unroll
  for (int i = 0; i < 4; i++){
    a[i]  = *(const short8*)(arow[i]);
    bv[i] = *(const short8*)(brow[i]);
  }
  for (int k = 32; k < K; k += 32){
    #pragma unroll
    for (int i = 0; i < 4; i++){
      a2[i] = *(const short8*)(arow[i] + k);
      b2[i] = *(const short8*)(brow[i] + k);
    }
    #pragma unroll
    for (int i = 0; i < 4; i++)
      #pragma unroll
      for (int j = 0; j < 4; j++)
        acc[i][j] = __builtin_amdgcn_mfma_f32_16x16x32_bf16(a[i], bv[j], acc[i][j], 0, 0, 0);
    #pragma unroll
    for (int i = 0; i < 4; i++){ a[i] = a2[i]; bv[i] = b2[i]; }
  }
  #pragma unroll
  for (int i = 0; i < 4; i++)
    #pragma unroll
    for (int j = 0; j < 4; j++)
      acc[i][j] = __builtin_amdgcn_mfma_f32_16x16x32_bf16(a[i], bv[j], acc[i][j], 0, 0, 0);
  int cq = lane & 15, rq = (lane >> 4) * 4;
  #pragma unroll
  for (int j = 0; j < 4; j++){
    int cc = blockIdx.x*64 + j*16 + cq;
    if (cc >= Nc) continue;
    float bv_ = bias ? bias[bz*bstride + cc] : 0.f;
    #pragma unroll
    for (int i = 0; i < 4; i++){
      int rbase = blockIdx.y*64 + i*16 + rq;
      #pragma unroll
      for (int reg = 0; reg < 4; reg++){
        int rr = rbase + reg;
        if (rr < Mr){
          float v = acc[i][j][reg] + bv_;
          if (RELU) v = fmaxf(v, 0.f);
          size_t o = (size_t)bz * sC + (size_t)rr * ldc + cc;
          if (C)   C[o] = v;
          if (C16) C16[o] = f2bf(v);
        }
      }
    }
  }
}

// split-K, 1-wave blocks, plain stores into per-(b,kz) fp32 partials.
// Linear grid 2560 with XCD-grouped swizzle: each XCD owns 320 consecutive work
// items = 16 (b,kz) panel-pairs x 20 tiles -> panels (~569 KB) stay in its L2.
// Hard-coded geometry: 4 x-tiles, 5 y-tiles, 8 kz, 16 b; K=4096, kchunk=512.
__global__ __launch_bounds__(64) void mfma_nt_splitk_kernel(
    const unsigned short* __restrict__ A, size_t sA,
    const unsigned short* __restrict__ B, size_t sB,
    float* __restrict__ C, size_t sC, int ldc, int Mr, int K, int kchunk){
  int lin = blockIdx.x;
  int swz = (lin & 7) * 320 + (lin >> 3);   // XCD-grouped work id (2560 total)
  int pair = swz / 20;                      // (b,kz) pair, 0..127
  int rem  = swz - pair * 20;
  int tx = rem & 3;                         // N tile (HIDC/64 = 4)
  int ty = rem >> 2;                        // M tile (5)
  int bz = pair >> 3;                       // batch
  int kz = pair & 7;                        // K chunk
  const unsigned short* Ab = A + (size_t)bz * sA + (size_t)kz * kchunk;
  const unsigned short* Bb = B + (size_t)bz * sB + (size_t)kz * kchunk;
  int lane = threadIdx.x;
  int r16 = lane & 15;
  int ko  = (lane >> 4) * 8;
  const unsigned short* arow[4];
  const unsigned short* brow[4];
  #pragma unroll
  for (int i = 0; i < 4; i++){
    int m = ty*64 + i*16 + r16;
    if (m > Mr - 1) m = Mr - 1;
    arow[i] = Ab + (size_t)m * K + ko;
    int n = tx*64 + i*16 + r16;
    brow[i] = Bb + (size_t)n * K + ko;
  }
  floatx4 acc[4][4];
  #pragma unroll
  for (int i = 0; i < 4; i++)
    #pragma unroll
    for (int j = 0; j < 4; j++)
      acc[i][j] = (floatx4){0.f, 0.f, 0.f, 0.f};
  short8 a[4], bv[4], a2[4], b2[4];
  #pragma unroll
  for (int i = 0; i < 4; i++){
    a[i]  = *(const short8*)(arow[i]);
    bv[i] = *(const short8*)(brow[i]);
  }
  for (int k = 32; k < kchunk; k += 32){
    #pragma unroll
    for (int i = 0; i < 4; i++){
      a2[i] = *(const short8*)(arow[i] + k);
      b2[i] = *(const short8*)(brow[i] + k);
    }
    #pragma unroll
    for (int i = 0; i < 4; i++)
      #pragma unroll
      for (int j = 0; j < 4; j++)
        acc[i][j] = __builtin_amdgcn_mfma_f32_16x16x32_bf16(a[i], bv[j], acc[i][j], 0, 0, 0);
    #pragma unroll
    for (int i = 0; i < 4; i++){ a[i] = a2[i]; bv[i] = b2[i]; }
  }
  #pragma unroll
  for (int i = 0; i < 4; i++)
    #pragma unroll
    for (int j = 0; j < 4; j++)
      acc[i][j] = __builtin_amdgcn_mfma_f32_16x16x32_bf16(a[i], bv[j], acc[i][j], 0, 0, 0);
  int cq = lane & 15, rq = (lane >> 4) * 4;
  float* Cb = C + (size_t)pair * sC;
  #pragma unroll
  for (int j = 0; j < 4; j++){
    int cc = tx*64 + j*16 + cq;
    #pragma unroll
    for (int i = 0; i < 4; i++){
      int rbase = ty*64 + i*16 + rq;
      #pragma unroll
      for (int reg = 0; reg < 4; reg++){
        int rr = rbase + reg;
        if (rr < Mr)
          Cb[(size_t)rr * ldc + cc] = acc[i][j][reg];
      }
    }
  }
}

// t16 = bf16( sum over 8 split-K partials )
__global__ __launch_bounds__(256) void cast_sum8_kernel(const float* __restrict__ part,
                                                        unsigned short* __restrict__ dst, int n4){
  int i = blockIdx.x * 256 + threadIdx.x;   // float4 index within (b, n, c)
  if (i < n4){
    int b = i / 19200, r = i - b * 19200;   // 19200 = NQ*HIDC/4
    const float4* p = (const float4*)part + (size_t)b * 8 * 19200 + r;
    float4 s = p[0];
    #pragma unroll
    for (int k = 1; k < 8; k++){
      float4 v = p[(size_t)k * 19200];
      s.x += v.x; s.y += v.y; s.z += v.z; s.w += v.w;
    }
    ushort4 u;
    u.x = f2bf(s.x); u.y = f2bf(s.y); u.z = f2bf(s.z); u.w = f2bf(s.w);
    ((ushort4*)dst)[i] = u;
  }
}

// LayerNorm(x + bias) + ReLU over 256-wide rows for BOTH heads (z = blockIdx.y).
__global__ __launch_bounds__(256) void ln_relu2_kernel(const float* __restrict__ zin,
    const float* __restrict__ bias_b, const float* __restrict__ bias_c,
    const float* __restrict__ g_b, const float* __restrict__ be_b,
    const float* __restrict__ g_c, const float* __restrict__ be_c,
    unsigned short* __restrict__ zout){
  int z = blockIdx.y;
  const float* bias = z ? bias_c : bias_b;
  const float* g    = z ? g_c : g_b;
  const float* be   = z ? be_c : be_b;
  const float* zi = zin + (size_t)z * 1228800;
  unsigned short* zo = zout + (size_t)z * 1228800;
  int row = blockIdx.x * 4 + (threadIdx.x >> 6);
  int lane = threadIdx.x & 63;
  float4 v = *(const float4*)&zi[(size_t)row * 256 + lane * 4];
  float4 bi = *(const float4*)&bias[lane * 4];
  v.x += bi.x; v.y += bi.y; v.z += bi.z; v.w += bi.w;
  float s = v.x + v.y + v.z + v.w;
  #pragma unroll
  for (int off = 32; off >= 1; off >>= 1) s += __shfl_xor(s, off);
  float mean = s * (1.f/256.f);
  float dx = v.x - mean, dy = v.y - mean, dz = v.z - mean, dw = v.w - mean;
  float sq = dx*dx + dy*dy + dz*dz + dw*dw;
  #pragma unroll
  for (int off = 32; off >= 1; off >>= 1) sq += __shfl_xor(sq, off);
  float inv = rsqrtf(sq * (1.f/256.f) + 1e-5f);
  float4 gv = *(const float4*)&g[lane * 4];
  float4 bb = *(const float4*)&be[lane * 4];
  ushort4 u;
  u.x = f2bf(fmaxf(dx*inv*gv.x + bb.x, 0.f));
  u.y = f2bf(fmaxf(dy*inv*gv.y + bb.y, 0.f));
  u.z = f2bf(fmaxf(dz*inv*gv.z + bb.z, 0.f));
  u.w = f2bf(fmaxf(dw*inv*gv.w + bb.w, 0.f));
  *(ushort4*)&zo[(size_t)row * 256 + lane * 4] = u;
}

// final tiny projections: boxes = z2bb @ bb3^T + b; scores = sigmoid(z2ch @ ch3^T + b)
__global__ __launch_bounds__(256) void head3_kernel(
    const unsigned short* __restrict__ z2bb, const unsigned short* __restrict__ z2ch,
    const float* __restrict__ bb3_w, const float* __restrict__ bb3_b,
    const float* __restrict__ ch3_w, const float* __restrict__ ch3_b,
    float* __restrict__ boxes, float* __restrict__ scores){
  int row = blockIdx.x * 4 + (threadIdx.x >> 6);
  int lane = threadIdx.x & 63;
  float zb0 = bf1(z2bb[(size_t)row*128 + 2*lane]);
  float zb1 = bf1(z2bb[(size_t)row*128 + 2*lane + 1]);
  float zc0 = bf1(z2ch[(size_t)row*128 + 2*lane]);
  float zc1 = bf1(z2ch[(size_t)row*128 + 2*lane + 1]);
  float acc[5];
  #pragma unroll
  for (int o = 0; o < 4; o++)
    acc[o] = bb3_w[o*128 + 2*lane]*zb0 + bb3_w[o*128 + 2*lane + 1]*zb1;
  acc[4] = ch3_w[2*lane]*zc0 + ch3_w[2*lane + 1]*zc1;
  #pragma unroll
  for (int o = 0; o < 5; o++){
    float v = acc[o];
    #pragma unroll
    for (int off = 32; off >= 1; off >>= 1) v += __shfl_xor(v, off);
    acc[o] = v;
  }
  if (lane == 0){
    #pragma unroll
    for (int o = 0; o < 4; o++)
      boxes[(size_t)row*4 + o] = acc[o] + bb3_b[o];
    float sv = acc[4] + ch3_b[0];
    scores[row] = 1.f / (1.f + __expf(-sv));
  }
}

// diversity: sum_m (sum_n attn[n,m]/||attn_n||)^2  (norms holds SUM OF SQUARES)
__global__ __launch_bounds__(256) void simdiv_kernel(const unsigned short* __restrict__ attn16,
    const float* __restrict__ norms, float* __restrict__ acc){
  int b = blockIdx.y;
  int m = blockIdx.x * 256 + threadIdx.x;
  __shared__ float inv_s[NQ];
  __shared__ float red[4];
  for (int i = threadIdx.x; i < NQ; i += 256)
    inv_s[i] = 1.f / fmaxf(sqrtf(norms[(size_t)b * NQ + i]), 1e-12f);
  __syncthreads();
  const unsigned short* ab = attn16 + (size_t)b * NQ * MM;
  float S = 0.f;
  for (int n = 0; n < NQ; n++)
    S += bf1(ab[(size_t)n * MM + m]) * inv_s[n];
  float p = S * S;
  #pragma unroll
  for (int off = 32; off >= 1; off >>= 1) p += __shfl_xor(p, off);
  int w = threadIdx.x >> 6, lane = threadIdx.x & 63;
  if (lane == 0) red[w] = p;
  __syncthreads();
  if (threadIdx.x == 0) atomicAdd(acc, red[0] + red[1] + red[2] + red[3]);
}

__global__ void finalize_kernel(const float* __restrict__ acc, float* __restrict__ out_div){
  out_div[0] = (acc[0] - (float)(BB * NQ)) / (float)(NQ * (NQ - 1)) * 0.1f;
}

extern "C" void kernel_launch(void* const* d_in, const int* in_sizes, int n_in,
                              void* d_out, int out_size, void* d_ws, size_t ws_size,
                              hipStream_t stream){
  const float* x      = (const float*)d_in[0];
  const float* ss     = (const float*)d_in[1];
  const float* pos_w  = (const float*)d_in[2];
  const float* pos_b  = (const float*)d_in[3];
  const float* fp_w   = (const float*)d_in[4];
  const float* fp_b   = (const float*)d_in[5];
  const float* bn_g   = (const float*)d_in[6];
  const float* bn_b   = (const float*)d_in[7];
  const float* bn_m   = (const float*)d_in[8];
  const float* bn_v   = (const float*)d_in[9];
  const float* key_w  = (const float*)d_in[10];
  const float* key_b  = (const float*)d_in[11];
  const float* val_w  = (const float*)d_in[12];
  const float* val_b  = (const float*)d_in[13];
  const float* ctp_w  = (const float*)d_in[14];
  const float* ctp_b  = (const float*)d_in[15];
  const float* bb1_w  = (const float*)d_in[16];
  const float* bb1_b  = (const float*)d_in[17];
  const float* bbln_g = (const float*)d_in[18];
  const float* bbln_b = (const float*)d_in[19];
  const float* bb2_w  = (const float*)d_in[20];
  const float* bb2_b  = (const float*)d_in[21];
  const float* bb3_w  = (const float*)d_in[22];
  const float* bb3_b  = (const float*)d_in[23];
  const float* ch1_w  = (const float*)d_in[24];
  const float* ch1_b  = (const float*)d_in[25];
  const float* chln_g = (const float*)d_in[26];
  const float* chln_b = (const float*)d_in[27];
  const float* ch2_w  = (const float*)d_in[28];
  const float* ch2_b  = (const float*)d_in[29];
  const float* ch3_w  = (const float*)d_in[30];
  const float* ch3_b  = (const float*)d_in[31];

  float* out    = (float*)d_out;
  float* boxes  = out + OFF_BOXES;
  float* scores = out + OFF_SCORES;
  float* cls    = out + OFF_CLS;
  float* maps   = out + OFF_MAPS;
  float* divp   = out + OFF_DIV;
  float* sfout  = out + OFF_SF;

  float* ws = (float*)d_ws;
  unsigned short* comb16 = (unsigned short*)(ws + WS_COMB16);
  unsigned short* keysT  = (unsigned short*)(ws + WS_KEYS16);
  unsigned short* attn16 = (unsigned short*)(ws + WS_ATTN16);
  unsigned short* t16    = (unsigned short*)(ws + WS_T16);
  unsigned short* valw16 = (unsigned short*)(ws + WS_VALW16);
  float* sums  = ws + WS_SUMS;
  float* norms = ws + WS_NORM;
  float* dacc  = ws + WS_ACC;
  unsigned short* sf16   = (unsigned short*)(ws + HP_SF16);
  unsigned short* z2bb16 = (unsigned short*)(ws + HP_Z2BB);
  unsigned short* z2ch16 = (unsigned short*)(ws + HP_Z2CH);
  unsigned short* hw16   = (unsigned short*)(ws + HP_HW);
  float*          b2ws   = ws + WS_B2;
  unsigned short* q16    = (unsigned short*)(ws + WS_Q16);
  unsigned short* xT16   = (unsigned short*)(ws + WS_XT);
  float*          tpart  = ws + WS_XT;        // aliases xT16+combT (both dead by then)
  unsigned short* combT  = (unsigned short*)(ws + WS_COMBT);
  unsigned short* fpw16  = (unsigned short*)(ws + WS_FPW16);
  unsigned short* keyw16 = (unsigned short*)(ws + WS_KEYW16);
  float*          z1pre2 = ws + WS_Z1PRE2;
  unsigned short* z1b16  = (unsigned short*)(ws + WS_Z1B16);

  // sums + norms + dacc are contiguous -> one zeroing pass (covers dacc)
  zero4_kernel<<<24, 256, 0, stream>>>((float4*)sums, 6002);
  init_kernel<<<128, 256, 0, stream>>>(ss, fp_w, key_w, q16, fpw16, keyw16);

  // x (b,256,4096) fp32 -> xT16 (b,4096,256) bf16
  transpose_x_kernel<<<dim3(64,4,16), 256, 0, stream>>>(x, xT16);
  // pos encoding into comb16 rows 128..255 AND combT cols 128..255
  pos_kernel<<<8704, 256, 0, stream>>>(pos_w, pos_b, comb16, combT);
  // comb rows 0..127 = relu(bn(fp_w @ x)) via MFMA, dual-layout store
  comb_mfma_kernel<<<dim3(64,2,16), 64, 0, stream>>>(
      fpw16, xT16, fp_b, bn_g, bn_b, bn_m, bn_v, comb16, combT);
  // keysT[m][d] = combT @ key_w^T + key_b (D-layout = m-major)
  mfma_nt_kernel<false><<<dim3(1,64,16), 64, 0, stream>>>(
      combT, (size_t)MM*CIN, keyw16, 0, key_b, 0,
      nullptr, keysT, (size_t)MM*64, 64, MM, 64, CIN);

  // fused no-P attention: swapped-operand MFMA logits, 2 passes
  attn_sums_kernel<<<dim3(32,5,16), 256, 0, stream>>>(q16, keysT, sums);
  attn_emit_kernel<<<dim3(32,5,16), 256, 0, stream>>>(q16, keysT, sums, maps, attn16, norms);

  // tpart[(b,kz)] = attn @ comb^T  (8-way split-K, 1-wave blocks, XCD-grouped swizzle)
  mfma_nt_splitk_kernel<<<2560, 64, 0, stream>>>(
      attn16, (size_t)NQ*MM, comb16, (size_t)HIDC*MM,
      tpart, (size_t)NQ*HIDC, HIDC, NQ, MM, MM/8);
  cast_sum8_kernel<<<1200, 256, 0, stream>>>(tpart, t16, 307200);
  cast_heads_kernel<<<256, 256, 0, stream>>>(val_w, bb1_w, ch1_w, bb2_w, ch2_w, ctp_w,
                                             bb2_b, ch2_b, valw16, hw16, b2ws);
  // sf = t @ val_w^T + val_b  (fp32 into d_out, bf16 into sf16)
  mfma_nt_kernel<false><<<dim3(4,5,BB), 64, 0, stream>>>(
      t16, (size_t)NQ*HIDC, valw16, 0, val_b, 0,
      sfout, sf16, (size_t)NQ*HIDC, HIDC, NQ, HIDC, HIDC);

  // ---- both heads, merged (z=0 boxes, z=1 scores) ----
  mfma_nt_kernel<false><<<dim3(4,75,2), 64, 0, stream>>>(
      sf16, 0, hw16 + HW_BB1, (size_t)(HW_CH1 - HW_BB1), nullptr, 0,
      z1pre2, nullptr, (size_t)4800*256, 256, 4800, 256, 256);
  ln_relu2_kernel<<<dim3(1200,2), 256, 0, stream>>>(
      z1pre2, bb1_b, ch1_b, bbln_g, bbln_b, chln_g, chln_b, z1b16);
  mfma_nt_kernel<true><<<dim3(2,75,2), 64, 0, stream>>>(
      z1b16, (size_t)4800*256, hw16 + HW_BB2, (size_t)(HW_CH2 - HW_BB2), b2ws, 128,
      nullptr, z2bb16, (size_t)4800*128, 128, 4800, 128, 256);
  // ---- finals + cls ----
  head3_kernel<<<1200, 256, 0, stream>>>(z2bb16, z2ch16, bb3_w, bb3_b, ch3_w, ch3_b, boxes, scores);
  mfma_nt_kernel<false><<<dim3(2,75,1), 64, 0, stream>>>(
      sf16, 0, hw16 + HW_CTP, 0, ctp_b, 0, cls, nullptr, 0, 80, 4800, 80, 256);

  simdiv_kernel<<<dim3(16,16), 256, 0, stream>>>(attn16, norms, dacc);
  finalize_kernel<<<1, 1, 0, stream>>>(dacc, divp);
}

// Round 11
// 458.259 us; speedup vs baseline: 1.1311x; 1.0244x over previous
//
#include <hip/hip_runtime.h>
#include <math.h>

// ---- problem constants ----
#define BB 16
#define CIN 256
#define MM 4096      // H*W
#define HIDC 256
#define NQ 300
#define NHH 4
#define HDD 16

// ---- output offsets (floats) ----
#define OFF_BOXES  0
#define OFF_SCORES 19200
#define OFF_CLS    24000
#define OFF_MAPS   408000
#define OFF_DIV    20068800
#define OFF_SF     20068801

// ---- workspace offsets (in floats) ----
#define WS_COMB16  0            // 16*256*4096 ushort  (comb, c-major: [c][m])
#define WS_KEYS16  8388608      // keysT: (b, m=4096, d=64) bf16
#define WS_ATTN16  10485760     // 16*300*4096 ushort
#define WS_T16     21544960     // 16*300*256 ushort
#define WS_VALW16  22159360     // 65536 ushort
#define WS_SUMS    22192128     // 16*4*300 fp32 (exp-sum; atomically accumulated)
#define WS_NORM    22211328     // 4800 floats: SUM OF SQUARES per (b,n)
#define WS_ACC     22216128     // 1 float (+pad) -- contiguous after norms (one zero pass)
#define WS_P       22216192     // head scratch base

// head scratch
#define HP_SF16   (WS_P + 0)         // 4800x256 bf16  (614400 fl)
#define HP_Z2BB   (WS_P + 2457600)   // 4800x128 bf16  (307200 fl)
#define HP_Z2CH   (WS_P + 2764800)   // 4800x128 bf16  (307200 fl) -- contiguous after Z2BB
#define HP_HW     (WS_P + 3072000)   // head weights bf16 (~108.6k fl)
#define WS_B2     (WS_P + 3180544)   // 256 fp32: [bb2_b | ch2_b] contiguous
#define WS_Q16    (WS_P + 3200000)   // 320x64 bf16 q (0.25-scaled, rows 300..319 zero)
// MFMA-path buffers
#define WS_XT     25426432      // xT16: (b,4096,256) bf16 (dead after comb_mfma)
                                // -> reused as splitk partials: 128 x 76800 fp32 = 9830400 fl
#define WS_COMBT  33815040      // combT: (b, m=4096, c=256) bf16 = 8388608 fl
#define WS_FPW16  42203648      // fp_w rows 0..127 bf16
#define WS_KEYW16 42220032      // key_w bf16
#define WS_Z1PRE2 42228224      // 2 x 4800x256 fp32 = 2457600 fl (boxes|scores z1 pre-LN)
#define WS_Z1B16  44685824      // 2 x 4800x256 bf16 = 1228800 fl
// total ≈ 45914624 fl ≈ 184 MB (harness provides ≥246 MB)

// ushort offsets within HP_HW:
#define HW_BB1 0
#define HW_CH1 65536
#define HW_BB2 131072
#define HW_CH2 163840
#define HW_CTP 196608

typedef short short8 __attribute__((ext_vector_type(8)));
typedef float floatx4 __attribute__((ext_vector_type(4)));

__device__ __forceinline__ unsigned short f2bf(float f){
  unsigned int u = __float_as_uint(f);
  u = (u + 0x7FFFu + ((u >> 16) & 1u)) >> 16;
  return (unsigned short)u;
}
__device__ __forceinline__ float bf1(unsigned short u){
  return __uint_as_float((unsigned int)u << 16);
}

__global__ __launch_bounds__(256) void zero4_kernel(float4* __restrict__ p, int n4){
  int i = blockIdx.x * 256 + threadIdx.x;
  if (i < n4) p[i] = make_float4(0.f, 0.f, 0.f, 0.f);
}

// fused init: q16 (0.25-scaled, 320-row pad), fp_w rows 0..127 bf16, key_w bf16
__global__ __launch_bounds__(256) void init_kernel(const float* __restrict__ ss,
    const float* __restrict__ fp_w, const float* __restrict__ key_w,
    unsigned short* __restrict__ q16, unsigned short* __restrict__ fpw16,
    unsigned short* __restrict__ keyw16){
  int i = blockIdx.x * 256 + threadIdx.x;
  int T = gridDim.x * 256;
  for (int j = i; j < 320*64; j += T)
    q16[j] = (j < NQ*64) ? f2bf(ss[j] * 0.25f) : (unsigned short)0;
  for (int j = i; j < 128*256; j += T) fpw16[j] = f2bf(fp_w[j]);
  for (int j = i; j < 64*256; j += T)  keyw16[j] = f2bf(key_w[j]);
}

// one fused cast of all bf16 weight copies + contiguous gemm2 biases
__global__ __launch_bounds__(256) void cast_heads_kernel(
    const float* __restrict__ val_w, const float* __restrict__ bb1_w,
    const float* __restrict__ ch1_w, const float* __restrict__ bb2_w,
    const float* __restrict__ ch2_w, const float* __restrict__ ctp_w,
    const float* __restrict__ bb2_b, const float* __restrict__ ch2_b,
    unsigned short* __restrict__ valw16, unsigned short* __restrict__ hw16,
    float* __restrict__ b2){
  int i = blockIdx.x * 256 + threadIdx.x;
  int T = gridDim.x * 256;
  for (int j = i; j < 65536; j += T) valw16[j] = f2bf(val_w[j]);
  for (int j = i; j < 65536; j += T) hw16[HW_BB1 + j] = f2bf(bb1_w[j]);
  for (int j = i; j < 65536; j += T) hw16[HW_CH1 + j] = f2bf(ch1_w[j]);
  for (int j = i; j < 32768; j += T) hw16[HW_BB2 + j] = f2bf(bb2_w[j]);
  for (int j = i; j < 32768; j += T) hw16[HW_CH2 + j] = f2bf(ch2_w[j]);
  for (int j = i; j < 20480; j += T) hw16[HW_CTP + j] = f2bf(ctp_w[j]);
  for (int j = i; j < 128; j += T){ b2[j] = bb2_b[j]; b2[128 + j] = ch2_b[j]; }
}

// pos encoding into BOTH layouts: comb16[c][m] rows 128..255 (ushort4 over m)
// and combT[m][128+c] (ushort4 over c). One kernel, linear id split.
__global__ __launch_bounds__(256) void pos_kernel(const float* __restrict__ pos_w,
                                                  const float* __restrict__ pos_b,
                                                  unsigned short* __restrict__ comb16,
                                                  unsigned short* __restrict__ combT){
  int lin = blockIdx.x * 256 + threadIdx.x;
  if (lin < 2097152){                     // part A: comb16, thread -> (b, c, m4)
    int m  = (lin & 1023) * 4;
    int c  = (lin >> 10) & 127;
    int b  = lin >> 17;
    int row = m >> 6, col = m & 63;
    float y  = -1.f + 2.f * (float)row / 63.f;
    float wy = pos_w[c*2], wx = pos_w[c*2+1], pb = pos_b[c];
    float base = wy * y + pb;
    ushort4 u;
    u.x = f2bf(base + wx * (-1.f + 2.f * (float)(col+0) / 63.f));
    u.y = f2bf(base + wx * (-1.f + 2.f * (float)(col+1) / 63.f));
    u.z = f2bf(base + wx * (-1.f + 2.f * (float)(col+2) / 63.f));
    u.w = f2bf(base + wx * (-1.f + 2.f * (float)(col+3) / 63.f));
    *(ushort4*)&comb16[((size_t)(b*HIDC + 128 + c))*MM + m] = u;
  } else if (lin < 2097152 + 131072){     // part B: combT, thread -> (m, c4)
    int l2 = lin - 2097152;
    int c4 = (l2 & 31) * 4;
    int m  = l2 >> 5;
    int row = m >> 6, col = m & 63;
    float y = -1.f + 2.f * (float)row / 63.f;
    float x = -1.f + 2.f * (float)col / 63.f;
    ushort4 u;
    u.x = f2bf(pos_w[(c4+0)*2] * y + pos_w[(c4+0)*2+1] * x + pos_b[c4+0]);
    u.y = f2bf(pos_w[(c4+1)*2] * y + pos_w[(c4+1)*2+1] * x + pos_b[c4+1]);
    u.z = f2bf(pos_w[(c4+2)*2] * y + pos_w[(c4+2)*2+1] * x + pos_b[c4+2]);
    u.w = f2bf(pos_w[(c4+3)*2] * y + pos_w[(c4+3)*2+1] * x + pos_b[c4+3]);
    #pragma unroll
    for (int b = 0; b < BB; b++)
      *(ushort4*)&combT[((size_t)b*MM + m)*CIN + 128 + c4] = u;
  }
}

// x (b, 256, 4096) fp32 -> xT16 (b, 4096, 256) bf16; one 64x64 tile per block.
__global__ __launch_bounds__(256) void transpose_x_kernel(
    const float* __restrict__ in, unsigned short* __restrict__ outp){
  int b = blockIdx.z;
  int m0 = blockIdx.x * 64;
  int r0 = blockIdx.y * 64;
  __shared__ unsigned short lds[64][68];
  int t = threadIdx.x;
  const float* ib = in + (size_t)b * CIN * MM;
  #pragma unroll
  for (int j = 0; j < 4; j++){
    int lin = j*256 + t;
    int rr = lin >> 4;
    int m4 = (lin & 15) * 4;
    float4 v = *(const float4*)&ib[(size_t)(r0 + rr)*MM + m0 + m4];
    lds[m4+0][rr] = f2bf(v.x);
    lds[m4+1][rr] = f2bf(v.y);
    lds[m4+2][rr] = f2bf(v.z);
    lds[m4+3][rr] = f2bf(v.w);
  }
  __syncthreads();
  unsigned short* ob = outp + (size_t)b * MM * CIN;
  #pragma unroll
  for (int j = 0; j < 4; j++){
    int lin = j*256 + t;
    int mm = lin >> 4;
    int c4 = (lin & 15) * 4;
    ushort4 u;
    u.x = lds[mm][c4+0]; u.y = lds[mm][c4+1];
    u.z = lds[mm][c4+2]; u.w = lds[mm][c4+3];
    *(ushort4*)&ob[(size_t)(m0 + mm)*CIN + r0 + c4] = u;
  }
}

// comb rows 0..127 via MFMA with DUAL-layout store:
//   comb16[c][m] (scalar, c-major) AND combT[m][c] (ushort4: reg axis = 4 consecutive c).
__global__ __launch_bounds__(64) void comb_mfma_kernel(
    const unsigned short* __restrict__ fpw16, const unsigned short* __restrict__ xT16,
    const float* __restrict__ fp_b, const float* __restrict__ bn_g,
    const float* __restrict__ bn_b, const float* __restrict__ bn_m,
    const float* __restrict__ bn_v, unsigned short* __restrict__ comb16,
    unsigned short* __restrict__ combT){
  int b = blockIdx.z;
  const unsigned short* Bb = xT16 + (size_t)b * MM * CIN;
  unsigned short* cb  = comb16 + (size_t)b * HIDC * MM;
  unsigned short* cTb = combT + (size_t)b * MM * CIN;
  int lane = threadIdx.x;
  int r16 = lane & 15;
  int ko  = (lane >> 4) * 8;
  const unsigned short* arow[4];
  const unsigned short* brow[4];
  #pragma unroll
  for (int i = 0; i < 4; i++){
    arow[i] = fpw16 + (size_t)(blockIdx.y*64 + i*16 + r16) * CIN + ko;
    brow[i] = Bb + (size_t)(blockIdx.x*64 + i*16 + r16) * CIN + ko;
  }
  floatx4 acc[4][4];
  #pragma unroll
  for (int i = 0; i < 4; i++)
    #pragma unroll
    for (int j = 0; j < 4; j++)
      acc[i][j] = (floatx4){0.f, 0.f, 0.f, 0.f};
  short8 a[4], bv[4], a2[4], b2[4];
  #pragma unroll
  for (int i = 0; i < 4; i++){
    a[i]  = *(const short8*)(arow[i]);
    bv[i] = *(const short8*)(brow[i]);
  }
  for (int k = 32; k < CIN; k += 32){
    #pragma unroll
    for (int i = 0; i < 4; i++){
      a2[i] = *(const short8*)(arow[i] + k);
      b2[i] = *(const short8*)(brow[i] + k);
    }
    #pragma unroll
    for (int i = 0; i < 4; i++)
      #pragma unroll
      for (int j = 0; j < 4; j++)
        acc[i][j] = __builtin_amdgcn_mfma_f32_16x16x32_bf16(a[i], bv[j], acc[i][j], 0, 0, 0);
    #pragma unroll
    for (int i = 0; i < 4; i++){ a[i] = a2[i]; bv[i] = b2[i]; }
  }
  #pragma unroll
  for (int i = 0; i < 4; i++)
    #pragma unroll
    for (int j = 0; j < 4; j++)
      acc[i][j] = __builtin_amdgcn_mfma_f32_16x16x32_bf16(a[i], bv[j], acc[i][j], 0, 0, 0);
  int cq = lane & 15, rq = (lane >> 4) * 4;
  #pragma unroll
  for (int i = 0; i < 4; i++){
    int rbase = blockIdx.y*64 + i*16 + rq;
    float mul[4], ofs[4];
    #pragma unroll
    for (int reg = 0; reg < 4; reg++){
      int rr = rbase + reg;
      float sc = rsqrtf(bn_v[rr] + 1e-5f);
      mul[reg] = sc * bn_g[rr];
      ofs[reg] = (fp_b[rr] - bn_m[rr]) * mul[reg] + bn_b[rr];
    }
    #pragma unroll
    for (int j = 0; j < 4; j++){
      int cc = blockIdx.x*64 + j*16 + cq;
      ushort4 u;
      float v0 = fmaxf(acc[i][j][0] * mul[0] + ofs[0], 0.f); u.x = f2bf(v0);
      float v1 = fmaxf(acc[i][j][1] * mul[1] + ofs[1], 0.f); u.y = f2bf(v1);
      float v2 = fmaxf(acc[i][j][2] * mul[2] + ofs[2], 0.f); u.z = f2bf(v2);
      float v3 = fmaxf(acc[i][j][3] * mul[3] + ofs[3], 0.f); u.w = f2bf(v3);
      cb[(size_t)(rbase+0) * MM + cc] = u.x;
      cb[(size_t)(rbase+1) * MM + cc] = u.y;
      cb[(size_t)(rbase+2) * MM + cc] = u.z;
      cb[(size_t)(rbase+3) * MM + cc] = u.w;
      *(ushort4*)&cTb[(size_t)cc * CIN + rbase] = u;
    }
  }
}

// ======== fused no-P attention: SWAPPED-operand MFMA logits, 2 passes ========
// mfma(a=k, b=q): D col = n (lane&15), D row = m ((lane>>4)*4 + reg).

// pass 1: sums[b][h][n] = sum_m exp(q.k/4). grid (32 m-chunks, 5 n-tiles, 16 b), 256 thr.
__global__ __launch_bounds__(256) void attn_sums_kernel(
    const unsigned short* __restrict__ q16, const unsigned short* __restrict__ keysT,
    float* __restrict__ sums){
  int b = blockIdx.z, ny = blockIdx.y, mx = blockIdx.x;
  int tid = threadIdx.x, w = tid >> 6, lane = tid & 63;
  int n0 = ny * 64;
  int l15 = lane & 15, qh = lane >> 4;
  int ko = (qh & 1) * 8;
  bool lo = lane < 32;
  const unsigned short* kT = keysT + (size_t)b * MM * 64;
  int mwb = mx*128 + w*32;
  __shared__ unsigned short qlds[64][72];
  __shared__ float spart[4][NHH][64];
  for (int c = tid; c < 512; c += 256){
    int r = c >> 3, d8 = (c & 7) * 8;
    *(short8*)&qlds[r][d8] = *(const short8*)&q16[(size_t)(n0 + r)*64 + d8];
  }
  __syncthreads();
  short8 zz = {0,0,0,0,0,0,0,0};
  #pragma unroll 1
  for (int h = 0; h < NHH; h++){
    short8 bq[4];
    #pragma unroll
    for (int ni = 0; ni < 4; ni++)
      bq[ni] = lo ? *(const short8*)&qlds[ni*16 + l15][h*16 + ko] : zz;
    float sacc[4] = {0.f, 0.f, 0.f, 0.f};
    #pragma unroll
    for (int ms = 0; ms < 2; ms++){
      int m = mwb + ms*16 + l15;
      short8 a = lo ? *(const short8*)&kT[(size_t)m*64 + h*16 + ko] : zz;
      #pragma unroll
      for (int ni = 0; ni < 4; ni++){
        floatx4 l = __builtin_amdgcn_mfma_f32_16x16x32_bf16(a, bq[ni],
                        (floatx4){0.f,0.f,0.f,0.f}, 0, 0, 0);
        sacc[ni] += __expf(l[0]) + __expf(l[1]) + __expf(l[2]) + __expf(l[3]);
      }
    }
    #pragma unroll
    for (int ni = 0; ni < 4; ni++){
      float v = sacc[ni];
      v += __shfl_xor(v, 16); v += __shfl_xor(v, 32);
      if (lane < 16) spart[w][h][ni*16 + lane] = v;
    }
  }
  __syncthreads();
  if (tid < NHH*64){
    int h = tid >> 6, r = tid & 63, n = n0 + r;
    if (n < NQ){
      float v = spart[0][h][r] + spart[1][h][r] + spart[2][h][r] + spart[3][h][r];
      atomicAdd(&sums[((size_t)b*NHH + h)*NQ + n], v);
    }
  }
}

// pass 2: attn[b][n][m] = sum_h exp(q.k/4) * (0.25/S_bhn).
// Both 16-m subtiles computed together (o[2][4]); store phase writes each row's
// maps (2x float4, 128B contiguous) and attn16 (2x ushort4 = full 64B line)
// back-to-back -> single L2 writeback per line.
__global__ __launch_bounds__(256) void attn_emit_kernel(
    const unsigned short* __restrict__ q16, const unsigned short* __restrict__ keysT,
    const float* __restrict__ sums, float* __restrict__ maps,
    unsigned short* __restrict__ attn16, float* __restrict__ norms){
  int b = blockIdx.z, ny = blockIdx.y, mx = blockIdx.x;
  int tid = threadIdx.x, w = tid >> 6, lane = tid & 63;
  int n0 = ny * 64;
  int l15 = lane & 15, qh = lane >> 4;
  int ko = (qh & 1) * 8;
  bool lo = lane < 32;
  __shared__ unsigned short qlds[64][72];
  __shared__ float inv_s[NHH][64];
  __shared__ float npart[4][64];
  for (int c = tid; c < 512; c += 256){
    int r = c >> 3, d8 = (c & 7) * 8;
    *(short8*)&qlds[r][d8] = *(const short8*)&q16[(size_t)(n0 + r)*64 + d8];
  }
  if (tid < NHH*64){
    int h = tid >> 6, r = tid & 63, n = n0 + r;
    inv_s[h][r] = (n < NQ) ? 0.25f / sums[((size_t)b*NHH + h)*NQ + n] : 0.f;
  }
  __syncthreads();
  const unsigned short* kT = keysT + (size_t)b * MM * 64;
  int mwb = mx*128 + w*32;
  short8 zz = {0,0,0,0,0,0,0,0};
  floatx4 o[2][4];
  #pragma unroll
  for (int ms = 0; ms < 2; ms++)
    #pragma unroll
    for (int ni = 0; ni < 4; ni++)
      o[ms][ni] = (floatx4){0.f,0.f,0.f,0.f};
  #pragma unroll
  for (int h = 0; h < NHH; h++){
    short8 a0 = lo ? *(const short8*)&kT[(size_t)(mwb + l15)*64 + h*16 + ko] : zz;
    short8 a1 = lo ? *(const short8*)&kT[(size_t)(mwb + 16 + l15)*64 + h*16 + ko] : zz;
    #pragma unroll
    for (int ni = 0; ni < 4; ni++){
      short8 bq = lo ? *(const short8*)&qlds[ni*16 + l15][h*16 + ko] : zz;
      floatx4 l0 = __builtin_amdgcn_mfma_f32_16x16x32_bf16(a0, bq,
                      (floatx4){0.f,0.f,0.f,0.f}, 0, 0, 0);
      floatx4 l1 = __builtin_amdgcn_mfma_f32_16x16x32_bf16(a1, bq,
                      (floatx4){0.f,0.f,0.f,0.f}, 0, 0, 0);
      float iv = inv_s[h][ni*16 + l15];
      o[0][ni][0] += __expf(l0[0]) * iv;
      o[0][ni][1] += __expf(l0[1]) * iv;
      o[0][ni][2] += __expf(l0[2]) * iv;
      o[0][ni][3] += __expf(l0[3]) * iv;
      o[1][ni][0] += __expf(l1[0]) * iv;
      o[1][ni][1] += __expf(l1[1]) * iv;
      o[1][ni][2] += __expf(l1[2]) * iv;
      o[1][ni][3] += __expf(l1[3]) * iv;
    }
  }
  float* mb = maps + (size_t)b * NQ * MM;
  unsigned short* ab = attn16 + (size_t)b * NQ * MM;
  float nacc[4];
  #pragma unroll
  for (int ni = 0; ni < 4; ni++){
    nacc[ni] = o[0][ni][0]*o[0][ni][0] + o[0][ni][1]*o[0][ni][1]
             + o[0][ni][2]*o[0][ni][2] + o[0][ni][3]*o[0][ni][3]
             + o[1][ni][0]*o[1][ni][0] + o[1][ni][1]*o[1][ni][1]
             + o[1][ni][2]*o[1][ni][2] + o[1][ni][3]*o[1][ni][3];
    int n = n0 + ni*16 + l15;
    if (n < NQ){
      size_t base = (size_t)n*MM + mwb + qh*4;
      float4 v0; v0.x = o[0][ni][0]; v0.y = o[0][ni][1]; v0.z = o[0][ni][2]; v0.w = o[0][ni][3];
      float4 v1; v1.x = o[1][ni][0]; v1.y = o[1][ni][1]; v1.z = o[1][ni][2]; v1.w = o[1][ni][3];
      *(float4*)&mb[base]      = v0;
      *(float4*)&mb[base + 16] = v1;
      ushort4 u0, u1;
      u0.x = f2bf(v0.x); u0.y = f2bf(v0.y); u0.z = f2bf(v0.z); u0.w = f2bf(v0.w);
      u1.x = f2bf(v1.x); u1.y = f2bf(v1.y); u1.z = f2bf(v1.z); u1.w = f2bf(v1.w);
      *(ushort4*)&ab[base]      = u0;
      *(ushort4*)&ab[base + 16] = u1;
    }
  }
  #pragma unroll
  for (int ni = 0; ni < 4; ni++){
    float v = nacc[ni];
    v += __shfl_xor(v, 16); v += __shfl_xor(v, 32);
    if (lane < 16) npart[w][ni*16 + lane] = v;
  }
  __syncthreads();
  if (tid < 64){
    int n = n0 + tid;
    if (n < NQ){
      float v = npart[0][tid] + npart[1][tid] + npart[2][tid] + npart[3][tid];
      atomicAdd(&norms[(size_t)b*NQ + n], v);
    }
  }
}

// C = A @ B^T (+bias). bf16 NT MFMA, wave per 64x64 tile. Row clamp Mr, col clamp Nc.
// bias index = bz*bstride + cc (bstride=0 -> shared bias across batch/z).
template<bool RELU>
__global__ __launch_bounds__(64) void mfma_nt_kernel(
    const unsigned short* __restrict__ A, size_t sA,
    const unsigned short* __restrict__ B, size_t sB,
    const float* __restrict__ bias, int bstride,
    float* __restrict__ C, unsigned short* __restrict__ C16,
    size_t sC, int ldc, int Mr, int Nc, int K){
  int bz = blockIdx.z;
  const unsigned short* Ab = A + (size_t)bz * sA;
  const unsigned short* Bb = B + (size_t)bz * sB;
  int lane = threadIdx.x;
  int r16 = lane & 15;
  int ko  = (lane >> 4) * 8;
  const unsigned short* arow[4];
  const unsigned short* brow[4];
  #pragma unroll
  for (int i = 0; i < 4; i++){
    int m = blockIdx.y*64 + i*16 + r16;
    if (m > Mr - 1) m = Mr - 1;
    arow[i] = Ab + (size_t)m * K + ko;
    int n = blockIdx.x*64 + i*16 + r16;
    if (n > Nc - 1) n = Nc - 1;
    brow[i] = Bb + (size_t)n * K + ko;
  }
  floatx4 acc[4][4];
  #pragma unroll
  for (int i = 0; i < 4; i++)
    #pragma unroll
    for (int j = 0; j < 4; j++)
      acc[i][j] = (floatx4){0.f, 0.f, 0.f, 0.f};
  short8 a[4], bv[4], a2[4], b2[4];
  #pragma unroll
  for (int i = 0; i < 4; i++){
    a[i]  = *(const short8*)(arow[i]);
    bv[i] = *(const short8*)(brow[i]);
  }
  for (int k = 32; k < K; k += 32){
    #pragma unroll
    for (int i = 0; i < 4; i++){
      a2[i] = *(const short8*)(arow[i] + k);
      b2[i] = *(const short8*)(brow[i] + k);
    }
    #pragma unroll
    for (int i = 0; i < 4; i++)
      #pragma unroll
      for (int j = 0; j < 4; j++)
        acc[i][j] = __builtin_amdgcn_mfma_f32_16x16x32_bf16(a[i], bv[j], acc[i][j], 0, 0, 0);
    #pragma unroll
    for (int i = 0; i < 4; i++){ a[i] = a2[i]; bv[i] = b2[i]; }
  }
  #pragma unroll
  for (int i = 0; i < 4; i++)
    #pragma unroll
    for (int j = 0; j < 4; j++)
      acc[i][j] = __builtin_amdgcn_mfma_f32_16x16x32_bf16(a[i], bv[j], acc[i][j], 0, 0, 0);
  int cq = lane & 15, rq = (lane >> 4) * 4;
  #pragma unroll
  for (int j = 0; j < 4; j++){
    int cc = blockIdx.x*64 + j*16 + cq;
    if (cc >= Nc) continue;
    float bv_ = bias ? bias[bz*bstride + cc] : 0.f;
    #pragma unroll
    for (int i = 0; i < 4; i++){
      int rbase = blockIdx.y*64 + i*16 + rq;
      #pragma unroll
      for (int reg = 0; reg < 4; reg++){
        int rr = rbase + reg;
        if (rr < Mr){
          float v = acc[i][j][reg] + bv_;
          if (RELU) v = fmaxf(v, 0.f);
          size_t o = (size_t)bz * sC + (size_t)rr * ldc + cc;
          if (C)   C[o] = v;
          if (C16) C16[o] = f2bf(v);
        }
      }
    }
  }
}

// split-K, 1-wave blocks, plain stores into per-(b,kz) fp32 partials.
// Linear grid 2560 with XCD-grouped swizzle: each XCD owns 320 consecutive work
// items = 16 (b,kz) panel-pairs x 20 tiles -> panels (~569 KB) stay in its L2.
// Hard-coded geometry: 4 x-tiles, 5 y-tiles, 8 kz, 16 b; K=4096, kchunk=512.
__global__ __launch_bounds__(64) void mfma_nt_splitk_kernel(
    const unsigned short* __restrict__ A, size_t sA,
    const unsigned short* __restrict__ B, size_t sB,
    float* __restrict__ C, size_t sC, int ldc, int Mr, int K, int kchunk){
  int lin = blockIdx.x;
  int swz = (lin & 7) * 320 + (lin >> 3);   // XCD-grouped work id (2560 total)
  int pair = swz / 20;                      // (b,kz) pair, 0..127
  int rem  = swz - pair * 20;
  int tx = rem & 3;                         // N tile (HIDC/64 = 4)
  int ty = rem >> 2;                        // M tile (5)
  int bz = pair >> 3;                       // batch
  int kz = pair & 7;                        // K chunk
  const unsigned short* Ab = A + (size_t)bz * sA + (size_t)kz * kchunk;
  const unsigned short* Bb = B + (size_t)bz * sB + (size_t)kz * kchunk;
  int lane = threadIdx.x;
  int r16 = lane & 15;
  int ko  = (lane >> 4) * 8;
  const unsigned short* arow[4];
  const unsigned short* brow[4];
  #pragma unroll
  for (int i = 0; i < 4; i++){
    int m = ty*64 + i*16 + r16;
    if (m > Mr - 1) m = Mr - 1;
    arow[i] = Ab + (size_t)m * K + ko;
    int n = tx*64 + i*16 + r16;
    brow[i] = Bb + (size_t)n * K + ko;
  }
  floatx4 acc[4][4];
  #pragma unroll
  for (int i = 0; i < 4; i++)
    #pragma unroll
    for (int j = 0; j < 4; j++)
      acc[i][j] = (floatx4){0.f, 0.f, 0.f, 0.f};
  short8 a[4], bv[4], a2[4], b2[4];
  #pragma unroll
  for (int i = 0; i < 4; i++){
    a[i]  = *(const short8*)(arow[i]);
    bv[i] = *(const short8*)(brow[i]);
  }
  for (int k = 32; k < kchunk; k += 32){
    #pragma unroll
    for (int i = 0; i < 4; i++){
      a2[i] = *(const short8*)(arow[i] + k);
      b2[i] = *(const short8*)(brow[i] + k);
    }
    #pragma unroll
    for (int i = 0; i < 4; i++)
      #pragma unroll
      for (int j = 0; j < 4; j++)
        acc[i][j] = __builtin_amdgcn_mfma_f32_16x16x32_bf16(a[i], bv[j], acc[i][j], 0, 0, 0);
    #pragma unroll
    for (int i = 0; i < 4; i++){ a[i] = a2[i]; bv[i] = b2[i]; }
  }
  #pragma unroll
  for (int i = 0; i < 4; i++)
    #pragma unroll
    for (int j = 0; j < 4; j++)
      acc[i][j] = __builtin_amdgcn_mfma_f32_16x16x32_bf16(a[i], bv[j], acc[i][j], 0, 0, 0);
  int cq = lane & 15, rq = (lane >> 4) * 4;
  float* Cb = C + (size_t)pair * sC;
  #pragma unroll
  for (int j = 0; j < 4; j++){
    int cc = tx*64 + j*16 + cq;
    #pragma unroll
    for (int i = 0; i < 4; i++){
      int rbase = ty*64 + i*16 + rq;
      #pragma unroll
      for (int reg = 0; reg < 4; reg++){
        int rr = rbase + reg;
        if (rr < Mr)
          Cb[(size_t)rr * ldc + cc] = acc[i][j][reg];
      }
    }
  }
}

// t16 = bf16( sum over 8 split-K partials )
__global__ __launch_bounds__(256) void cast_sum8_kernel(const float* __restrict__ part,
                                                        unsigned short* __restrict__ dst, int n4){
  int i = blockIdx.x * 256 + threadIdx.x;   // float4 index within (b, n, c)
  if (i < n4){
    int b = i / 19200, r = i - b * 19200;   // 19200 = NQ*HIDC/4
    const float4* p = (const float4*)part + (size_t)b * 8 * 19200 + r;
    float4 s = p[0];
    #pragma unroll
    for (int k = 1; k < 8; k++){
      float4 v = p[(size_t)k * 19200];
      s.x += v.x; s.y += v.y; s.z += v.z; s.w += v.w;
    }
    ushort4 u;
    u.x = f2bf(s.x); u.y = f2bf(s.y); u.z = f2bf(s.z); u.w = f2bf(s.w);
    ((ushort4*)dst)[i] = u;
  }
}

// LayerNorm(x + bias) + ReLU over 256-wide rows for BOTH heads (z = blockIdx.y).
__global__ __launch_bounds__(256) void ln_relu2_kernel(const float* __restrict__ zin,
    const float* __restrict__ bias_b, const float* __restrict__ bias_c,
    const float* __restrict__ g_b, const float* __restrict__ be_b,
    const float* __restrict__ g_c, const float* __restrict__ be_c,
    unsigned short* __restrict__ zout){
  int z = blockIdx.y;
  const float* bias = z ? bias_c : bias_b;
  const float* g    = z ? g_c : g_b;
  const float* be   = z ? be_c : be_b;
  const float* zi = zin + (size_t)z * 1228800;
  unsigned short* zo = zout + (size_t)z * 1228800;
  int row = blockIdx.x * 4 + (threadIdx.x >> 6);
  int lane = threadIdx.x & 63;
  float4 v = *(const float4*)&zi[(size_t)row * 256 + lane * 4];
  float4 bi = *(const float4*)&bias[lane * 4];
  v.x += bi.x; v.y += bi.y; v.z += bi.z; v.w += bi.w;
  float s = v.x + v.y + v.z + v.w;
  #pragma unroll
  for (int off = 32; off >= 1; off >>= 1) s += __shfl_xor(s, off);
  float mean = s * (1.f/256.f);
  float dx = v.x - mean, dy = v.y - mean, dz = v.z - mean, dw = v.w - mean;
  float sq = dx*dx + dy*dy + dz*dz + dw*dw;
  #pragma unroll
  for (int off = 32; off >= 1; off >>= 1) sq += __shfl_xor(sq, off);
  float inv = rsqrtf(sq * (1.f/256.f) + 1e-5f);
  float4 gv = *(const float4*)&g[lane * 4];
  float4 bb = *(const float4*)&be[lane * 4];
  ushort4 u;
  u.x = f2bf(fmaxf(dx*inv*gv.x + bb.x, 0.f));
  u.y = f2bf(fmaxf(dy*inv*gv.y + bb.y, 0.f));
  u.z = f2bf(fmaxf(dz*inv*gv.z + bb.z, 0.f));
  u.w = f2bf(fmaxf(dw*inv*gv.w + bb.w, 0.f));
  *(ushort4*)&zo[(size_t)row * 256 + lane * 4] = u;
}

// final tiny projections: boxes = z2bb @ bb3^T + b; scores = sigmoid(z2ch @ ch3^T + b)
__global__ __launch_bounds__(256) void head3_kernel(
    const unsigned short* __restrict__ z2bb, const unsigned short* __restrict__ z2ch,
    const float* __restrict__ bb3_w, const float* __restrict__ bb3_b,
    const float* __restrict__ ch3_w, const float* __restrict__ ch3_b,
    float* __restrict__ boxes, float* __restrict__ scores){
  int row = blockIdx.x * 4 + (threadIdx.x >> 6);
  int lane = threadIdx.x & 63;
  float zb0 = bf1(z2bb[(size_t)row*128 + 2*lane]);
  float zb1 = bf1(z2bb[(size_t)row*128 + 2*lane + 1]);
  float zc0 = bf1(z2ch[(size_t)row*128 + 2*lane]);
  float zc1 = bf1(z2ch[(size_t)row*128 + 2*lane + 1]);
  float acc[5];
  #pragma unroll
  for (int o = 0; o < 4; o++)
    acc[o] = bb3_w[o*128 + 2*lane]*zb0 + bb3_w[o*128 + 2*lane + 1]*zb1;
  acc[4] = ch3_w[2*lane]*zc0 + ch3_w[2*lane + 1]*zc1;
  #pragma unroll
  for (int o = 0; o < 5; o++){
    float v = acc[o];
    #pragma unroll
    for (int off = 32; off >= 1; off >>= 1) v += __shfl_xor(v, off);
    acc[o] = v;
  }
  if (lane == 0){
    #pragma unroll
    for (int o = 0; o < 4; o++)
      boxes[(size_t)row*4 + o] = acc[o] + bb3_b[o];
    float sv = acc[4] + ch3_b[0];
    scores[row] = 1.f / (1.f + __expf(-sv));
  }
}

// diversity: sum_m (sum_n attn[n,m]/||attn_n||)^2  (norms holds SUM OF SQUARES)
// vectorized: each thread owns 4 consecutive m (ushort4 loads). grid (4, 16).
__global__ __launch_bounds__(256) void simdiv_kernel(const unsigned short* __restrict__ attn16,
    const float* __restrict__ norms, float* __restrict__ acc){
  int b = blockIdx.y;
  int m4 = (blockIdx.x * 256 + threadIdx.x) * 4;
  __shared__ float inv_s[NQ];
  __shared__ float red[4];
  for (int i = threadIdx.x; i < NQ; i += 256)
    inv_s[i] = 1.f / fmaxf(sqrtf(norms[(size_t)b * NQ + i]), 1e-12f);
  __syncthreads();
  const unsigned short* ab = attn16 + (size_t)b * NQ * MM;
  float S0 = 0.f, S1 = 0.f, S2 = 0.f, S3 = 0.f;
  for (int n = 0; n < NQ; n++){
    ushort4 u = *(const ushort4*)&ab[(size_t)n * MM + m4];
    float iv = inv_s[n];
    S0 += bf1(u.x) * iv; S1 += bf1(u.y) * iv;
    S2 += bf1(u.z) * iv; S3 += bf1(u.w) * iv;
  }
  float p = S0*S0 + S1*S1 + S2*S2 + S3*S3;
  #pragma unroll
  for (int off = 32; off >= 1; off >>= 1) p += __shfl_xor(p, off);
  int w = threadIdx.x >> 6, lane = threadIdx.x & 63;
  if (lane == 0) red[w] = p;
  __syncthreads();
  if (threadIdx.x == 0) atomicAdd(acc, red[0] + red[1] + red[2] + red[3]);
}

__global__ void finalize_kernel(const float* __restrict__ acc, float* __restrict__ out_div){
  out_div[0] = (acc[0] - (float)(BB * NQ)) / (float)(NQ * (NQ - 1)) * 0.1f;
}

extern "C" void kernel_launch(void* const* d_in, const int* in_sizes, int n_in,
                              void* d_out, int out_size, void* d_ws, size_t ws_size,
                              hipStream_t stream){
  const float* x      = (const float*)d_in[0];
  const float* ss     = (const float*)d_in[1];
  const float* pos_w  = (const float*)d_in[2];
  const float* pos_b  = (const float*)d_in[3];
  const float* fp_w   = (const float*)d_in[4];
  const float* fp_b   = (const float*)d_in[5];
  const float* bn_g   = (const float*)d_in[6];
  const float* bn_b   = (const float*)d_in[7];
  const float* bn_m   = (const float*)d_in[8];
  const float* bn_v   = (const float*)d_in[9];
  const float* key_w  = (const float*)d_in[10];
  const float* key_b  = (const float*)d_in[11];
  const float* val_w  = (const float*)d_in[12];
  const float* val_b  = (const float*)d_in[13];
  const float* ctp_w  = (const float*)d_in[14];
  const float* ctp_b  = (const float*)d_in[15];
  const float* bb1_w  = (const float*)d_in[16];
  const float* bb1_b  = (const float*)d_in[17];
  const float* bbln_g = (const float*)d_in[18];
  const float* bbln_b = (const float*)d_in[19];
  const float* bb2_w  = (const float*)d_in[20];
  const float* bb2_b  = (const float*)d_in[21];
  const float* bb3_w  = (const float*)d_in[22];
  const float* bb3_b  = (const float*)d_in[23];
  const float* ch1_w  = (const float*)d_in[24];
  const float* ch1_b  = (const float*)d_in[25];
  const float* chln_g = (const float*)d_in[26];
  const float* chln_b = (const float*)d_in[27];
  const float* ch2_w  = (const float*)d_in[28];
  const float* ch2_b  = (const float*)d_in[29];
  const float* ch3_w  = (const float*)d_in[30];
  const float* ch3_b  = (const float*)d_in[31];

  float* out    = (float*)d_out;
  float* boxes  = out + OFF_BOXES;
  float* scores = out + OFF_SCORES;
  float* cls    = out + OFF_CLS;
  float* maps   = out + OFF_MAPS;
  float* divp   = out + OFF_DIV;
  float* sfout  = out + OFF_SF;

  float* ws = (float*)d_ws;
  unsigned short* comb16 = (unsigned short*)(ws + WS_COMB16);
  unsigned short* keysT  = (unsigned short*)(ws + WS_KEYS16);
  unsigned short* attn16 = (unsigned short*)(ws + WS_ATTN16);
  unsigned short* t16    = (unsigned short*)(ws + WS_T16);
  unsigned short* valw16 = (unsigned short*)(ws + WS_VALW16);
  float* sums  = ws + WS_SUMS;
  float* norms = ws + WS_NORM;
  float* dacc  = ws + WS_ACC;
  unsigned short* sf16   = (unsigned short*)(ws + HP_SF16);
  unsigned short* z2bb16 = (unsigned short*)(ws + HP_Z2BB);
  unsigned short* z2ch16 = (unsigned short*)(ws + HP_Z2CH);
  unsigned short* hw16   = (unsigned short*)(ws + HP_HW);
  float*          b2ws   = ws + WS_B2;
  unsigned short* q16    = (unsigned short*)(ws + WS_Q16);
  unsigned short* xT16   = (unsigned short*)(ws + WS_XT);
  float*          tpart  = ws + WS_XT;        // aliases xT16+combT (both dead by then)
  unsigned short* combT  = (unsigned short*)(ws + WS_COMBT);
  unsigned short* fpw16  = (unsigned short*)(ws + WS_FPW16);
  unsigned short* keyw16 = (unsigned short*)(ws + WS_KEYW16);
  float*          z1pre2 = ws + WS_Z1PRE2;
  unsigned short* z1b16  = (unsigned short*)(ws + WS_Z1B16);

  // sums + norms + dacc are contiguous -> one zeroing pass (covers dacc)
  zero4_kernel<<<24, 256, 0, stream>>>((float4*)sums, 6002);
  init_kernel<<<128, 256, 0, stream>>>(ss, fp_w, key_w, q16, fpw16, keyw16);

  // x (b,256,4096) fp32 -> xT16 (b,4096,256) bf16
  transpose_x_kernel<<<dim3(64,4,16), 256, 0, stream>>>(x, xT16);
  // pos encoding into comb16 rows 128..255 AND combT cols 128..255
  pos_kernel<<<8704, 256, 0, stream>>>(pos_w, pos_b, comb16, combT);
  // comb rows 0..127 = relu(bn(fp_w @ x)) via MFMA, dual-layout store
  comb_mfma_kernel<<<dim3(64,2,16), 64, 0, stream>>>(
      fpw16, xT16, fp_b, bn_g, bn_b, bn_m, bn_v, comb16, combT);
  // keysT[m][d] = combT @ key_w^T + key_b (D-layout = m-major)
  mfma_nt_kernel<false><<<dim3(1,64,16), 64, 0, stream>>>(
      combT, (size_t)MM*CIN, keyw16, 0, key_b, 0,
      nullptr, keysT, (size_t)MM*64, 64, MM, 64, CIN);

  // fused no-P attention: swapped-operand MFMA logits, 2 passes
  attn_sums_kernel<<<dim3(32,5,16), 256, 0, stream>>>(q16, keysT, sums);
  attn_emit_kernel<<<dim3(32,5,16), 256, 0, stream>>>(q16, keysT, sums, maps, attn16, norms);

  // tpart[(b,kz)] = attn @ comb^T  (8-way split-K, 1-wave blocks, XCD-grouped swizzle)
  mfma_nt_splitk_kernel<<<2560, 64, 0, stream>>>(
      attn16, (size_t)NQ*MM, comb16, (size_t)HIDC*MM,
      tpart, (size_t)NQ*HIDC, HIDC, NQ, MM, MM/8);
  cast_sum8_kernel<<<1200, 256, 0, stream>>>(tpart, t16, 307200);
  cast_heads_kernel<<<256, 256, 0, stream>>>(val_w, bb1_w, ch1_w, bb2_w, ch2_w, ctp_w,
                                             bb2_b, ch2_b, valw16, hw16, b2ws);
  // sf = t @ val_w^T + val_b  (fp32 into d_out, bf16 into sf16)
  mfma_nt_kernel<false><<<dim3(4,5,BB), 64, 0, stream>>>(
      t16, (size_t)NQ*HIDC, valw16, 0, val_b, 0,
      sfout, sf16, (size_t)NQ*HIDC, HIDC, NQ, HIDC, HIDC);

  // ---- both heads, merged (z=0 boxes, z=1 scores) ----
  mfma_nt_kernel<false><<<dim3(4,75,2), 64, 0, stream>>>(
      sf16, 0, hw16 + HW_BB1, (size_t)(HW_CH1 - HW_BB1), nullptr, 0,
      z1pre2, nullptr, (size_t)4800*256, 256, 4800, 256, 256);
  ln_relu2_kernel<<<dim3(1200,2), 256, 0, stream>>>(
      z1pre2, bb1_b, ch1_b, bbln_g, bbln_b, chln_g, chln_b, z1b16);
  mfma_nt_kernel<true><<<dim3(2,75,2), 64, 0, stream>>>(
      z1b16, (size_t)4800*256, hw16 + HW_BB2, (size_t)(HW_CH2 - HW_BB2), b2ws, 128,
      nullptr, z2bb16, (size_t)4800*128, 128, 4800, 128, 256);
  // ---- finals + cls ----
  head3_kernel<<<1200, 256, 0, stream>>>(z2bb16, z2ch16, bb3_w, bb3_b, ch3_w, ch3_b, boxes, scores);
  mfma_nt_kernel<false><<<dim3(2,75,1), 64, 0, stream>>>(
      sf16, 0, hw16 + HW_CTP, 0, ctp_b, 0, cls, nullptr, 0, 80, 4800, 80, 256);

  simdiv_kernel<<<dim3(4,16), 256, 0, stream>>>(attn16, norms, dacc);
  finalize_kernel<<<1, 1, 0, stream>>>(dacc, divp);
}